// Round 2
// baseline (2590.898 us; speedup 1.0000x reference)
//
#include <hip/hip_runtime.h>
#include <hip/hip_bf16.h>
#include <cstddef>

#define D_MODEL   384
#define D_IN_PROJ 1676
#define D_INNER   768
#define D_CONV_IN 896
#define ZXLD      1664          // z(768) + xBC(896), dt columns stored separately in f32
#define NHEADS    12
#define HEADDIM   64
#define D_STATE   64
#define SEQLEN    4096
#define BATCH     8
#define NTOK      (BATCH * SEQLEN)   // 32768
#define EPSV      1e-5f

typedef __hip_bfloat16 bf16;

__device__ __forceinline__ float b2f(bf16 v) { return __bfloat162float(v); }
__device__ __forceinline__ bf16  f2b(float v) { return __float2bfloat16(v); }

// ---------------------------------------------------------------------------
// K1: zxbcdt = u @ in_proj_w^T.  A f32 (M x K), B f32 (N x K).
// cols < 1664 -> bf16 zx (stride 1664); cols 1664..1675 -> f32 dtraw (stride 12)
// ---------------------------------------------------------------------------
__global__ __launch_bounds__(256)
void gemm_in(const float* __restrict__ A, const float* __restrict__ Bm,
             bf16* __restrict__ zx, float* __restrict__ dtraw,
             int M, int N, int K) {
    const int BM = 64, BN = 64, BK = 16;
    __shared__ float As[16][68];
    __shared__ float Bs[16][68];
    const int tid = threadIdx.x;
    const int bm = blockIdx.y * BM;
    const int bn = blockIdx.x * BN;
    const int ty = tid >> 4;
    const int tx = tid & 15;
    const int lr = tid >> 2;
    const int lc = (tid & 3) * 4;
    float acc[4][4] = {{0.f}};

    const int brow = bn + lr;
    const float* Aptr = A + (size_t)(bm + lr) * K + lc;
    const float* Bptr = Bm + (size_t)(brow < N ? brow : 0) * K + lc;
    const bool bvalid = (brow < N);

    for (int k0 = 0; k0 < K; k0 += BK) {
        float4 av = *(const float4*)(Aptr + k0);
        float4 bv = bvalid ? *(const float4*)(Bptr + k0)
                           : make_float4(0.f, 0.f, 0.f, 0.f);
        __syncthreads();
        As[lc + 0][lr] = av.x; As[lc + 1][lr] = av.y;
        As[lc + 2][lr] = av.z; As[lc + 3][lr] = av.w;
        Bs[lc + 0][lr] = bv.x; Bs[lc + 1][lr] = bv.y;
        Bs[lc + 2][lr] = bv.z; Bs[lc + 3][lr] = bv.w;
        __syncthreads();
#pragma unroll
        for (int k = 0; k < BK; ++k) {
            float a0 = As[k][ty * 4 + 0], a1 = As[k][ty * 4 + 1];
            float a2 = As[k][ty * 4 + 2], a3 = As[k][ty * 4 + 3];
            float b0 = Bs[k][tx * 4 + 0], b1 = Bs[k][tx * 4 + 1];
            float b2 = Bs[k][tx * 4 + 2], b3 = Bs[k][tx * 4 + 3];
            acc[0][0] += a0 * b0; acc[0][1] += a0 * b1; acc[0][2] += a0 * b2; acc[0][3] += a0 * b3;
            acc[1][0] += a1 * b0; acc[1][1] += a1 * b1; acc[1][2] += a1 * b2; acc[1][3] += a1 * b3;
            acc[2][0] += a2 * b0; acc[2][1] += a2 * b1; acc[2][2] += a2 * b2; acc[2][3] += a2 * b3;
            acc[3][0] += a3 * b0; acc[3][1] += a3 * b1; acc[3][2] += a3 * b2; acc[3][3] += a3 * b3;
        }
    }
#pragma unroll
    for (int i = 0; i < 4; ++i) {
        int row = bm + ty * 4 + i;
#pragma unroll
        for (int j = 0; j < 4; ++j) {
            int col = bn + tx * 4 + j;
            if (col < ZXLD)
                zx[(size_t)row * ZXLD + col] = f2b(acc[i][j]);
            else if (col < N)
                dtraw[(size_t)row * NHEADS + (col - ZXLD)] = acc[i][j];
        }
    }
}

// ---------------------------------------------------------------------------
// K2: causal depthwise conv(4) + bias + SiLU + split + RMSNorm(x) + softplus(dt)
// ---------------------------------------------------------------------------
__global__ __launch_bounds__(256)
void conv_norm_kernel(const bf16* __restrict__ zx, const float* __restrict__ dtraw,
                      const float* __restrict__ conv_w, const float* __restrict__ conv_b,
                      const float* __restrict__ norm_w, const float* __restrict__ dt_bias,
                      bf16* __restrict__ xn, bf16* __restrict__ Bb,
                      bf16* __restrict__ Cb, float* __restrict__ dtb) {
    const int token = blockIdx.x;
    const int l = token & (SEQLEN - 1);
    __shared__ float sval[D_CONV_IN];
    __shared__ float ssum[4];
    float partial = 0.f;

    for (int c = threadIdx.x; c < D_CONV_IN; c += 256) {
        float acc = conv_b[c];
#pragma unroll
        for (int j = 0; j < 4; ++j) {
            int lt = l - 3 + j;
            if (lt >= 0)
                acc += b2f(zx[(size_t)(token - 3 + j) * ZXLD + D_INNER + c]) * conv_w[c * 4 + j];
        }
        float s = acc / (1.f + expf(-acc));     // silu
        sval[c] = s;
        if (c < D_INNER) partial += s * s;
    }
    for (int off = 32; off > 0; off >>= 1) partial += __shfl_down(partial, off, 64);
    if ((threadIdx.x & 63) == 0) ssum[threadIdx.x >> 6] = partial;
    __syncthreads();
    float total = ssum[0] + ssum[1] + ssum[2] + ssum[3];
    float scale = rsqrtf(total / (float)D_INNER + EPSV);

    for (int c = threadIdx.x; c < D_CONV_IN; c += 256) {
        float s = sval[c];
        if (c < D_INNER)
            xn[(size_t)token * D_INNER + c] = f2b(s * scale * norm_w[c]);
        else if (c < D_INNER + D_STATE)
            Bb[(size_t)token * D_STATE + (c - D_INNER)] = f2b(s);
        else
            Cb[(size_t)token * D_STATE + (c - D_INNER - D_STATE)] = f2b(s);
    }
    if (threadIdx.x < NHEADS) {
        float v = dtraw[(size_t)token * NHEADS + threadIdx.x] + dt_bias[threadIdx.x];
        float sp = (v > 20.f) ? v : log1pf(expf(v));
        dtb[(size_t)token * NHEADS + threadIdx.x] = sp;
    }
}

// ---------------------------------------------------------------------------
// K3: sequential SSD scan, one block per (b, h). 256 threads.
// thread (p = tid&63, g = tid>>6) owns h[n = g*16+i][p], i = 0..15.
// y (gated) written bf16 in-place over xn.
// ---------------------------------------------------------------------------
#define SCHUNK 8
__global__ __launch_bounds__(256)
void scan_kernel(const bf16* __restrict__ zx, bf16* __restrict__ xy,
                 const bf16* __restrict__ Bb, const bf16* __restrict__ Cb,
                 const float* __restrict__ dtb, const float* __restrict__ A_log,
                 const float* __restrict__ Dpa) {
    const int blk = blockIdx.x;
    const int b = blk / NHEADS;
    const int h = blk % NHEADS;
    const int tid = threadIdx.x;
    const int p = tid & 63;
    const int g = tid >> 6;
    const float Acoef = -expf(A_log[h]);
    const float Dh = Dpa[h];

    float hstate[16];
#pragma unroll
    for (int i = 0; i < 16; ++i) hstate[i] = 0.f;

    __shared__ float sx[SCHUNK][64];
    __shared__ float sB[SCHUNK][64];
    __shared__ float sC[SCHUNK][64];
    __shared__ float sdA[SCHUNK];
    __shared__ float sdt[SCHUNK];
    __shared__ float sred[SCHUNK][4][64];

    const size_t tok0 = (size_t)b * SEQLEN;

    for (int t0 = 0; t0 < SEQLEN; t0 += SCHUNK) {
        for (int q = tid; q < SCHUNK * 64; q += 256) {
            int s = q >> 6, pp = q & 63;
            sx[s][pp] = b2f(xy[(tok0 + t0 + s) * D_INNER + h * HEADDIM + pp]);
            (&sB[0][0])[q] = b2f(Bb[(tok0 + t0) * D_STATE + q]);
            (&sC[0][0])[q] = b2f(Cb[(tok0 + t0) * D_STATE + q]);
        }
        if (tid < SCHUNK) {
            float dtv = dtb[(tok0 + t0 + tid) * NHEADS + h];
            sdt[tid] = dtv;
            sdA[tid] = expf(dtv * Acoef);
        }
        __syncthreads();

        float part[SCHUNK];
#pragma unroll
        for (int s = 0; s < SCHUNK; ++s) {
            float xv = sx[s][p];
            float dAv = sdA[s];
            float bx = sdt[s] * xv;
            float accy = 0.f;
            const float* Bp = &sB[s][g * 16];
            const float* Cp = &sC[s][g * 16];
#pragma unroll
            for (int i = 0; i < 16; ++i) {
                float hv = hstate[i] * dAv + Bp[i] * bx;
                hstate[i] = hv;
                accy += Cp[i] * hv;
            }
            part[s] = accy;
        }
#pragma unroll
        for (int s = 0; s < SCHUNK; ++s) sred[s][g][p] = part[s];
        __syncthreads();

        if (g == 0) {
#pragma unroll
            for (int s = 0; s < SCHUNK; ++s) {
                float y = sred[s][0][p] + sred[s][1][p] + sred[s][2][p] + sred[s][3][p]
                        + sx[s][p] * Dh;
                float zv = b2f(zx[(tok0 + t0 + s) * ZXLD + h * HEADDIM + p]);
                float sz = zv / (1.f + expf(-zv));
                xy[(tok0 + t0 + s) * D_INNER + h * HEADDIM + p] = f2b(y * sz);
            }
        }
        __syncthreads();
    }
}

// ---------------------------------------------------------------------------
// K4: out = y @ out_proj_w^T.  A bf16 (M x K), B f32 (N x K), C f32.
// ---------------------------------------------------------------------------
__global__ __launch_bounds__(256)
void gemm_out(const bf16* __restrict__ A, const float* __restrict__ Bm,
              float* __restrict__ C, int M, int N, int K) {
    const int BM = 64, BN = 64, BK = 16;
    __shared__ float As[16][68];
    __shared__ float Bs[16][68];
    const int tid = threadIdx.x;
    const int bm = blockIdx.y * BM;
    const int bn = blockIdx.x * BN;
    const int ty = tid >> 4;
    const int tx = tid & 15;
    const int lr = tid >> 2;
    const int lc = (tid & 3) * 4;
    float acc[4][4] = {{0.f}};

    const int brow = bn + lr;
    const bf16* Aptr = A + (size_t)(bm + lr) * K + lc;
    const float* Bptr = Bm + (size_t)(brow < N ? brow : 0) * K + lc;
    const bool bvalid = (brow < N);

    for (int k0 = 0; k0 < K; k0 += BK) {
        ushort4 au = *(const ushort4*)(Aptr + k0);
        float4 bv = bvalid ? *(const float4*)(Bptr + k0)
                           : make_float4(0.f, 0.f, 0.f, 0.f);
        __syncthreads();
        As[lc + 0][lr] = b2f(__ushort_as_bfloat16(au.x));
        As[lc + 1][lr] = b2f(__ushort_as_bfloat16(au.y));
        As[lc + 2][lr] = b2f(__ushort_as_bfloat16(au.z));
        As[lc + 3][lr] = b2f(__ushort_as_bfloat16(au.w));
        Bs[lc + 0][lr] = bv.x; Bs[lc + 1][lr] = bv.y;
        Bs[lc + 2][lr] = bv.z; Bs[lc + 3][lr] = bv.w;
        __syncthreads();
#pragma unroll
        for (int k = 0; k < BK; ++k) {
            float a0 = As[k][ty * 4 + 0], a1 = As[k][ty * 4 + 1];
            float a2 = As[k][ty * 4 + 2], a3 = As[k][ty * 4 + 3];
            float b0 = Bs[k][tx * 4 + 0], b1 = Bs[k][tx * 4 + 1];
            float b2 = Bs[k][tx * 4 + 2], b3 = Bs[k][tx * 4 + 3];
            acc[0][0] += a0 * b0; acc[0][1] += a0 * b1; acc[0][2] += a0 * b2; acc[0][3] += a0 * b3;
            acc[1][0] += a1 * b0; acc[1][1] += a1 * b1; acc[1][2] += a1 * b2; acc[1][3] += a1 * b3;
            acc[2][0] += a2 * b0; acc[2][1] += a2 * b1; acc[2][2] += a2 * b2; acc[2][3] += a2 * b3;
            acc[3][0] += a3 * b0; acc[3][1] += a3 * b1; acc[3][2] += a3 * b2; acc[3][3] += a3 * b3;
        }
    }
#pragma unroll
    for (int i = 0; i < 4; ++i) {
        int row = bm + ty * 4 + i;
#pragma unroll
        for (int j = 0; j < 4; ++j) {
            int col = bn + tx * 4 + j;
            if (col < N) C[(size_t)row * N + col] = acc[i][j];
        }
    }
}

// ---------------------------------------------------------------------------
extern "C" void kernel_launch(void* const* d_in, const int* in_sizes, int n_in,
                              void* d_out, int out_size, void* d_ws, size_t ws_size,
                              hipStream_t stream) {
    (void)in_sizes; (void)n_in; (void)out_size; (void)ws_size;
    const float* u          = (const float*)d_in[0];
    const float* in_proj_w  = (const float*)d_in[1];
    const float* conv_w     = (const float*)d_in[2];
    const float* conv_b     = (const float*)d_in[3];
    const float* norm_w     = (const float*)d_in[4];
    const float* out_proj_w = (const float*)d_in[5];
    const float* A_log      = (const float*)d_in[6];
    const float* Dp         = (const float*)d_in[7];
    const float* dt_bias    = (const float*)d_in[8];

    // workspace layout (bytes), all 256B-aligned:
    //   zx_bf16 : NTOK*1664*2 = 109.05 MB
    //   xy_bf16 : NTOK* 768*2 =  50.33 MB
    //   Bb_bf16 : NTOK*  64*2 =   4.19 MB
    //   Cb_bf16 : NTOK*  64*2 =   4.19 MB
    //   dtraw   : NTOK*  12*4 =   1.57 MB
    //   dtb     : NTOK*  12*4 =   1.57 MB      total = 170.9 MB
    char* w = (char*)d_ws;
    bf16*  zx    = (bf16*)w;                 w += (size_t)NTOK * ZXLD * 2;
    bf16*  xy    = (bf16*)w;                 w += (size_t)NTOK * D_INNER * 2;
    bf16*  Bb    = (bf16*)w;                 w += (size_t)NTOK * D_STATE * 2;
    bf16*  Cb    = (bf16*)w;                 w += (size_t)NTOK * D_STATE * 2;
    float* dtraw = (float*)w;                w += (size_t)NTOK * NHEADS * 4;
    float* dtb   = (float*)w;

    dim3 g1((D_IN_PROJ + 63) / 64, NTOK / 64);
    gemm_in<<<g1, 256, 0, stream>>>(u, in_proj_w, zx, dtraw, NTOK, D_IN_PROJ, D_MODEL);

    conv_norm_kernel<<<NTOK, 256, 0, stream>>>(zx, dtraw, conv_w, conv_b, norm_w, dt_bias,
                                               xy, Bb, Cb, dtb);

    scan_kernel<<<BATCH * NHEADS, 256, 0, stream>>>(zx, xy, Bb, Cb, dtb, A_log, Dp);

    dim3 g4(D_MODEL / 64, NTOK / 64);
    gemm_out<<<g4, 256, 0, stream>>>(xy, out_proj_w, (float*)d_out, NTOK, D_MODEL, D_INNER);
}

// Round 3
// 1579.597 us; speedup vs baseline: 1.6402x; 1.6402x over previous
//
#include <hip/hip_runtime.h>
#include <hip/hip_bf16.h>
#include <cstddef>

#define D_MODEL   384
#define D_IN_PROJ 1676
#define D_INNER   768
#define D_CONV_IN 896
#define ZXLD      1664
#define NHEADS    12
#define HEADDIM   64
#define D_STATE   64
#define SEQLEN    4096
#define BATCH     8
#define NTOK      (BATCH * SEQLEN)
#define EPSV      1e-5f
#define Q         128
#define NCHUNK    (SEQLEN / Q)          // 32
#define NCHB      (BATCH * NHEADS * NCHUNK)  // 3072

typedef __hip_bfloat16 bf16;

__device__ __forceinline__ float b2f(bf16 v) { return __bfloat162float(v); }
__device__ __forceinline__ bf16  f2b(float v) { return __float2bfloat16(v); }
__device__ __forceinline__ float bl(unsigned u)  { return __uint_as_float(u << 16); }
__device__ __forceinline__ float bh(unsigned u)  { return __uint_as_float(u & 0xffff0000u); }
__device__ __forceinline__ float bu(unsigned short v) { return __uint_as_float(((unsigned)v) << 16); }
__device__ __forceinline__ unsigned pk2(float a, float b) {
    return ((unsigned)__bfloat16_as_ushort(f2b(b)) << 16) | (unsigned)__bfloat16_as_ushort(f2b(a));
}

// ---------------------------------------------------------------------------
// K1: zxbcdt = u @ in_proj_w^T -> Z (cols<768), XBC (768..1663), dtraw (>=1664)
// ---------------------------------------------------------------------------
__global__ __launch_bounds__(256)
void gemm_in(const float* __restrict__ A, const float* __restrict__ Bm,
             bf16* __restrict__ Z, bf16* __restrict__ XBC, float* __restrict__ dtraw,
             int M, int N, int K) {
    const int BK = 16;
    __shared__ float As[16][68];
    __shared__ float Bs[16][68];
    const int tid = threadIdx.x;
    const int bm = blockIdx.y * 64;
    const int bn = blockIdx.x * 64;
    const int ty = tid >> 4;
    const int tx = tid & 15;
    const int lr = tid >> 2;
    const int lc = (tid & 3) * 4;
    float acc[4][4] = {{0.f}};

    const int brow = bn + lr;
    const float* Aptr = A + (size_t)(bm + lr) * K + lc;
    const float* Bptr = Bm + (size_t)(brow < N ? brow : 0) * K + lc;
    const bool bvalid = (brow < N);

    for (int k0 = 0; k0 < K; k0 += BK) {
        float4 av = *(const float4*)(Aptr + k0);
        float4 bv = bvalid ? *(const float4*)(Bptr + k0) : make_float4(0.f, 0.f, 0.f, 0.f);
        __syncthreads();
        As[lc + 0][lr] = av.x; As[lc + 1][lr] = av.y;
        As[lc + 2][lr] = av.z; As[lc + 3][lr] = av.w;
        Bs[lc + 0][lr] = bv.x; Bs[lc + 1][lr] = bv.y;
        Bs[lc + 2][lr] = bv.z; Bs[lc + 3][lr] = bv.w;
        __syncthreads();
#pragma unroll
        for (int k = 0; k < BK; ++k) {
            float a0 = As[k][ty * 4 + 0], a1 = As[k][ty * 4 + 1];
            float a2 = As[k][ty * 4 + 2], a3 = As[k][ty * 4 + 3];
            float b0 = Bs[k][tx * 4 + 0], b1 = Bs[k][tx * 4 + 1];
            float b2 = Bs[k][tx * 4 + 2], b3 = Bs[k][tx * 4 + 3];
            acc[0][0] += a0 * b0; acc[0][1] += a0 * b1; acc[0][2] += a0 * b2; acc[0][3] += a0 * b3;
            acc[1][0] += a1 * b0; acc[1][1] += a1 * b1; acc[1][2] += a1 * b2; acc[1][3] += a1 * b3;
            acc[2][0] += a2 * b0; acc[2][1] += a2 * b1; acc[2][2] += a2 * b2; acc[2][3] += a2 * b3;
            acc[3][0] += a3 * b0; acc[3][1] += a3 * b1; acc[3][2] += a3 * b2; acc[3][3] += a3 * b3;
        }
    }
#pragma unroll
    for (int i = 0; i < 4; ++i) {
        int row = bm + ty * 4 + i;
#pragma unroll
        for (int j = 0; j < 4; ++j) {
            int col = bn + tx * 4 + j;
            if (col < D_INNER)      Z[(size_t)row * D_INNER + col] = f2b(acc[i][j]);
            else if (col < ZXLD)    XBC[(size_t)row * D_CONV_IN + (col - D_INNER)] = f2b(acc[i][j]);
            else if (col < N)       dtraw[(size_t)row * NHEADS + (col - ZXLD)] = acc[i][j];
        }
    }
}

// ---------------------------------------------------------------------------
// K2: causal conv(4) + bias + SiLU + split + RMSNorm(x) + softplus(dt)
// ---------------------------------------------------------------------------
__global__ __launch_bounds__(256)
void conv_norm_kernel(const bf16* __restrict__ XBC, const float* __restrict__ dtraw,
                      const float* __restrict__ conv_w, const float* __restrict__ conv_b,
                      const float* __restrict__ norm_w, const float* __restrict__ dt_bias,
                      bf16* __restrict__ xn, bf16* __restrict__ Bb,
                      bf16* __restrict__ Cb, float* __restrict__ dtb) {
    const int token = blockIdx.x;
    const int l = token & (SEQLEN - 1);
    __shared__ float sval[D_CONV_IN];
    __shared__ float ssum[4];
    float partial = 0.f;

    for (int c = threadIdx.x; c < D_CONV_IN; c += 256) {
        float acc = conv_b[c];
#pragma unroll
        for (int j = 0; j < 4; ++j) {
            int lt = l - 3 + j;
            if (lt >= 0)
                acc += b2f(XBC[(size_t)(token - 3 + j) * D_CONV_IN + c]) * conv_w[c * 4 + j];
        }
        float s = acc / (1.f + expf(-acc));
        sval[c] = s;
        if (c < D_INNER) partial += s * s;
    }
    for (int off = 32; off > 0; off >>= 1) partial += __shfl_down(partial, off, 64);
    if ((threadIdx.x & 63) == 0) ssum[threadIdx.x >> 6] = partial;
    __syncthreads();
    float total = ssum[0] + ssum[1] + ssum[2] + ssum[3];
    float scale = rsqrtf(total / (float)D_INNER + EPSV);

    for (int c = threadIdx.x; c < D_CONV_IN; c += 256) {
        float s = sval[c];
        if (c < D_INNER)
            xn[(size_t)token * D_INNER + c] = f2b(s * scale * norm_w[c]);
        else if (c < D_INNER + D_STATE)
            Bb[(size_t)token * D_STATE + (c - D_INNER)] = f2b(s);
        else
            Cb[(size_t)token * D_STATE + (c - D_INNER - D_STATE)] = f2b(s);
    }
    if (threadIdx.x < NHEADS) {
        float v = dtraw[(size_t)token * NHEADS + threadIdx.x] + dt_bias[threadIdx.x];
        float sp = (v > 20.f) ? v : log1pf(expf(v));
        dtb[(size_t)token * NHEADS + threadIdx.x] = sp;
    }
}

// ---------------------------------------------------------------------------
// K3a: per-chunk state S_c[n][p] = sum_t exp(ltot-lcum_t) * Bdt_t[n] * x_t[p]
// one block (256 thr) per (b,h,c). Also writes cdecay = exp(ltot).
// ---------------------------------------------------------------------------
__global__ __launch_bounds__(256)
void chunk_state_kernel(const bf16* __restrict__ xy, const bf16* __restrict__ Bb,
                        const float* __restrict__ dtb, const float* __restrict__ A_log,
                        float* __restrict__ states, float* __restrict__ cdecay) {
    const int sid = blockIdx.x;
    const int c = sid % NCHUNK;
    const int h = (sid / NCHUNK) % NHEADS;
    const int b = sid / (NCHUNK * NHEADS);
    const int tid = threadIdx.x;
    const size_t tok0 = (size_t)b * SEQLEN + (size_t)c * Q;
    const float Acoef = -expf(A_log[h]);

    __shared__ __align__(16) unsigned short sBdt[Q * 64];
    __shared__ __align__(16) unsigned short sx[Q * 64];
    __shared__ float slcum[Q];
    __shared__ float sdt[Q];
    __shared__ float wtot[2];

    float lx = 0.f;
    if (tid < Q) {
        float dtv = dtb[(tok0 + tid) * NHEADS + h];
        sdt[tid] = dtv;
        lx = dtv * Acoef;
        int lane = tid & 63;
        for (int off = 1; off < 64; off <<= 1) {
            float v = __shfl_up(lx, off, 64);
            if (lane >= off) lx += v;
        }
        if (lane == 63) wtot[tid >> 6] = lx;
    }
    __syncthreads();
    if (tid < Q) {
        if (tid >= 64) lx += wtot[0];
        slcum[tid] = lx;
    }
    __syncthreads();
    const float ltot = slcum[Q - 1];

    // stage Bdt (B * dt, bf16) and x
    for (int i4 = tid; i4 < Q * 64 / 8; i4 += 256) {
        uint4 bv = ((const uint4*)(Bb + tok0 * D_STATE))[i4];
        float dtv = sdt[i4 >> 3];
        uint4 ov;
        ov.x = pk2(bl(bv.x) * dtv, bh(bv.x) * dtv);
        ov.y = pk2(bl(bv.y) * dtv, bh(bv.y) * dtv);
        ov.z = pk2(bl(bv.z) * dtv, bh(bv.z) * dtv);
        ov.w = pk2(bl(bv.w) * dtv, bh(bv.w) * dtv);
        ((uint4*)sBdt)[i4] = ov;
        int t = i4 >> 3, k = i4 & 7;
        ((uint4*)sx)[i4] = *(const uint4*)(xy + (tok0 + t) * D_INNER + h * HEADDIM + k * 8);
    }
    __syncthreads();

    const int p = tid & 63, g = tid >> 6;
    float S[16];
#pragma unroll
    for (int i = 0; i < 16; ++i) S[i] = 0.f;

    for (int t = 0; t < Q; ++t) {
        float w = __expf(ltot - slcum[t]);
        float xv = bu(sx[t * 64 + p]);
        float wx = w * xv;
        const uint4* brow = (const uint4*)(sBdt + t * 64);
        uint4 b0 = brow[g * 2], b1 = brow[g * 2 + 1];
        S[0] += bl(b0.x) * wx; S[1] += bh(b0.x) * wx;
        S[2] += bl(b0.y) * wx; S[3] += bh(b0.y) * wx;
        S[4] += bl(b0.z) * wx; S[5] += bh(b0.z) * wx;
        S[6] += bl(b0.w) * wx; S[7] += bh(b0.w) * wx;
        S[8]  += bl(b1.x) * wx; S[9]  += bh(b1.x) * wx;
        S[10] += bl(b1.y) * wx; S[11] += bh(b1.y) * wx;
        S[12] += bl(b1.z) * wx; S[13] += bh(b1.z) * wx;
        S[14] += bl(b1.w) * wx; S[15] += bh(b1.w) * wx;
    }
    float* out = states + (size_t)sid * 4096;
#pragma unroll
    for (int i = 0; i < 16; ++i) out[(g * 16 + i) * 64 + p] = S[i];
    if (tid == 0) cdecay[sid] = expf(ltot);
}

// ---------------------------------------------------------------------------
// K3b: sequential inter-chunk recurrence (32 steps). states[c] is rewritten
// in-place with the state ENTERING chunk c.
// ---------------------------------------------------------------------------
__global__ __launch_bounds__(256)
void state_pass_kernel(float* __restrict__ states, const float* __restrict__ cdecay) {
    const int bh = blockIdx.x;      // 0..95
    const int tid = threadIdx.x;
    float run[16];
#pragma unroll
    for (int i = 0; i < 16; ++i) run[i] = 0.f;
    float* base = states + (size_t)bh * NCHUNK * 4096 + tid * 16;
    const float* cd = cdecay + bh * NCHUNK;
    for (int c = 0; c < NCHUNK; ++c) {
        float dec = cd[c];
        float* ptr = base + (size_t)c * 4096;
        float4 s0 = *(float4*)(ptr + 0);
        float4 s1 = *(float4*)(ptr + 4);
        float4 s2 = *(float4*)(ptr + 8);
        float4 s3 = *(float4*)(ptr + 12);
        float nr[16];
        nr[0] = dec * run[0] + s0.x;  nr[1] = dec * run[1] + s0.y;
        nr[2] = dec * run[2] + s0.z;  nr[3] = dec * run[3] + s0.w;
        nr[4] = dec * run[4] + s1.x;  nr[5] = dec * run[5] + s1.y;
        nr[6] = dec * run[6] + s1.z;  nr[7] = dec * run[7] + s1.w;
        nr[8] = dec * run[8] + s2.x;  nr[9] = dec * run[9] + s2.y;
        nr[10] = dec * run[10] + s2.z; nr[11] = dec * run[11] + s2.w;
        nr[12] = dec * run[12] + s3.x; nr[13] = dec * run[13] + s3.y;
        nr[14] = dec * run[14] + s3.z; nr[15] = dec * run[15] + s3.w;
        *(float4*)(ptr + 0)  = make_float4(run[0], run[1], run[2], run[3]);
        *(float4*)(ptr + 4)  = make_float4(run[4], run[5], run[6], run[7]);
        *(float4*)(ptr + 8)  = make_float4(run[8], run[9], run[10], run[11]);
        *(float4*)(ptr + 12) = make_float4(run[12], run[13], run[14], run[15]);
#pragma unroll
        for (int i = 0; i < 16; ++i) run[i] = nr[i];
    }
}

// ---------------------------------------------------------------------------
// K3c: per-token output. One block (128 thr) per (b,h,c); thread t owns row t.
// y_t = exp(lcum_t)*C_t.init + sum_{s<=t} (C_t.Bdt_s) exp(lcum_t-lcum_s) x_s
// then +Dp*x, *silu(z), written bf16 in-place over xy.
// ---------------------------------------------------------------------------
__global__ __launch_bounds__(128)
void chunk_output_kernel(const bf16* __restrict__ Zb, bf16* __restrict__ xy,
                         const bf16* __restrict__ Bb, const bf16* __restrict__ Cb,
                         const float* __restrict__ dtb, const float* __restrict__ A_log,
                         const float* __restrict__ Dpa, const float* __restrict__ states) {
    const int sid = blockIdx.x;
    const int c = sid % NCHUNK;
    const int h = (sid / NCHUNK) % NHEADS;
    const int b = sid / (NCHUNK * NHEADS);
    const int tid = threadIdx.x;        // == t
    const int t = tid;
    const size_t tok0 = (size_t)b * SEQLEN + (size_t)c * Q;
    const float Acoef = -expf(A_log[h]);

    __shared__ __align__(16) unsigned short sBdt[Q * 64];
    __shared__ __align__(16) unsigned short sx[Q * 64];
    __shared__ __align__(16) unsigned short sCt[64 * Q];   // [n][t]
    __shared__ float slcum[Q];
    __shared__ float sdt[Q];
    __shared__ float wtot[2];

    // --- cumulative log-decay scan ---
    float dtv = dtb[(tok0 + t) * NHEADS + h];
    float lx = dtv * Acoef;
    {
        int lane = t & 63;
        for (int off = 1; off < 64; off <<= 1) {
            float v = __shfl_up(lx, off, 64);
            if (lane >= off) lx += v;
        }
        if (lane == 63) wtot[t >> 6] = lx;
        sdt[t] = dtv;
    }
    __syncthreads();
    if (t >= 64) lx += wtot[0];
    slcum[t] = lx;
    __syncthreads();
    const float lct = slcum[t];

    // --- stage Bdt, x, C^T ---
    for (int i4 = tid; i4 < Q * 64 / 8; i4 += 128) {
        int tt = i4 >> 3, k = i4 & 7;
        uint4 bv = ((const uint4*)(Bb + tok0 * D_STATE))[i4];
        float dd = sdt[tt];
        uint4 ov;
        ov.x = pk2(bl(bv.x) * dd, bh(bv.x) * dd);
        ov.y = pk2(bl(bv.y) * dd, bh(bv.y) * dd);
        ov.z = pk2(bl(bv.z) * dd, bh(bv.z) * dd);
        ov.w = pk2(bl(bv.w) * dd, bh(bv.w) * dd);
        ((uint4*)sBdt)[i4] = ov;
        ((uint4*)sx)[i4] = *(const uint4*)(xy + (tok0 + tt) * D_INNER + h * HEADDIM + k * 8);
        uint4 cv = ((const uint4*)(Cb + tok0 * D_STATE))[i4];
        int n0 = k * 8;
        sCt[(n0 + 0) * Q + tt] = (unsigned short)(cv.x & 0xffff);
        sCt[(n0 + 1) * Q + tt] = (unsigned short)(cv.x >> 16);
        sCt[(n0 + 2) * Q + tt] = (unsigned short)(cv.y & 0xffff);
        sCt[(n0 + 3) * Q + tt] = (unsigned short)(cv.y >> 16);
        sCt[(n0 + 4) * Q + tt] = (unsigned short)(cv.z & 0xffff);
        sCt[(n0 + 5) * Q + tt] = (unsigned short)(cv.z >> 16);
        sCt[(n0 + 6) * Q + tt] = (unsigned short)(cv.w & 0xffff);
        sCt[(n0 + 7) * Q + tt] = (unsigned short)(cv.w >> 16);
    }
    __syncthreads();

    // --- C_t into registers ---
    float C[64];
    {
        const uint4* crow = (const uint4*)(Cb + (tok0 + t) * D_STATE);
#pragma unroll
        for (int k = 0; k < 8; ++k) {
            uint4 cv = crow[k];
            C[k * 8 + 0] = bl(cv.x); C[k * 8 + 1] = bh(cv.x);
            C[k * 8 + 2] = bl(cv.y); C[k * 8 + 3] = bh(cv.y);
            C[k * 8 + 4] = bl(cv.z); C[k * 8 + 5] = bh(cv.z);
            C[k * 8 + 6] = bl(cv.w); C[k * 8 + 7] = bh(cv.w);
        }
    }

    // --- state term: y = C_t . init (init from global, uniform broadcast) ---
    float y[64];
#pragma unroll
    for (int p = 0; p < 64; ++p) y[p] = 0.f;
    const float* init = states + (size_t)sid * 4096;
#pragma unroll 4
    for (int n = 0; n < 64; ++n) {
        float cn = bu(sCt[n * Q + t]);
#pragma unroll
        for (int p0 = 0; p0 < 64; p0 += 4) {
            float4 iv = *(const float4*)(init + n * 64 + p0);
            y[p0 + 0] += cn * iv.x; y[p0 + 1] += cn * iv.y;
            y[p0 + 2] += cn * iv.z; y[p0 + 3] += cn * iv.w;
        }
    }
    const float el = __expf(lct);
#pragma unroll
    for (int p = 0; p < 64; ++p) y[p] *= el;

    // --- intra-chunk causal accumulation ---
    const int smax = t | 63;
    for (int s = 0; s <= smax; ++s) {
        float gdot = 0.f;
        const uint4* brow = (const uint4*)(sBdt + s * 64);
#pragma unroll
        for (int k = 0; k < 8; ++k) {
            uint4 bv = brow[k];
            gdot += C[k * 8 + 0] * bl(bv.x) + C[k * 8 + 1] * bh(bv.x)
                  + C[k * 8 + 2] * bl(bv.y) + C[k * 8 + 3] * bh(bv.y)
                  + C[k * 8 + 4] * bl(bv.z) + C[k * 8 + 5] * bh(bv.z)
                  + C[k * 8 + 6] * bl(bv.w) + C[k * 8 + 7] * bh(bv.w);
        }
        float m = (s <= t) ? gdot * __expf(lct - slcum[s]) : 0.f;
        const uint4* xrow = (const uint4*)(sx + s * 64);
#pragma unroll
        for (int k = 0; k < 8; ++k) {
            uint4 xv = xrow[k];
            y[k * 8 + 0] += m * bl(xv.x); y[k * 8 + 1] += m * bh(xv.x);
            y[k * 8 + 2] += m * bl(xv.y); y[k * 8 + 3] += m * bh(xv.y);
            y[k * 8 + 4] += m * bl(xv.z); y[k * 8 + 5] += m * bh(xv.z);
            y[k * 8 + 6] += m * bl(xv.w); y[k * 8 + 7] += m * bh(xv.w);
        }
    }

    // --- epilogue: +Dp*x, gate with silu(z), store bf16 ---
    const float Dh = Dpa[h];
    const size_t rowoff = (tok0 + t) * D_INNER + h * HEADDIM;
    const uint4* xrow = (const uint4*)(xy + rowoff);
    const uint4* zrow = (const uint4*)(Zb + rowoff);
    uint4* orow = (uint4*)(xy + rowoff);
#pragma unroll
    for (int k = 0; k < 8; ++k) {
        uint4 xv = xrow[k];
        uint4 zv = zrow[k];
        float xs[8] = {bl(xv.x), bh(xv.x), bl(xv.y), bh(xv.y), bl(xv.z), bh(xv.z), bl(xv.w), bh(xv.w)};
        float zs[8] = {bl(zv.x), bh(zv.x), bl(zv.y), bh(zv.y), bl(zv.z), bh(zv.z), bl(zv.w), bh(zv.w)};
        unsigned o[4];
#pragma unroll
        for (int j = 0; j < 4; ++j) {
            float y0 = y[k * 8 + 2 * j]     + Dh * xs[2 * j];
            float y1 = y[k * 8 + 2 * j + 1] + Dh * xs[2 * j + 1];
            float z0 = zs[2 * j], z1 = zs[2 * j + 1];
            y0 *= z0 / (1.f + __expf(-z0));
            y1 *= z1 / (1.f + __expf(-z1));
            o[j] = pk2(y0, y1);
        }
        uint4 ov; ov.x = o[0]; ov.y = o[1]; ov.z = o[2]; ov.w = o[3];
        orow[k] = ov;
    }
}

// ---------------------------------------------------------------------------
// K4: out = y @ out_proj_w^T
// ---------------------------------------------------------------------------
__global__ __launch_bounds__(256)
void gemm_out(const bf16* __restrict__ A, const float* __restrict__ Bm,
              float* __restrict__ C, int M, int N, int K) {
    const int BK = 16;
    __shared__ float As[16][68];
    __shared__ float Bs[16][68];
    const int tid = threadIdx.x;
    const int bm = blockIdx.y * 64;
    const int bn = blockIdx.x * 64;
    const int ty = tid >> 4;
    const int tx = tid & 15;
    const int lr = tid >> 2;
    const int lc = (tid & 3) * 4;
    float acc[4][4] = {{0.f}};

    const int brow = bn + lr;
    const bf16* Aptr = A + (size_t)(bm + lr) * K + lc;
    const float* Bptr = Bm + (size_t)(brow < N ? brow : 0) * K + lc;
    const bool bvalid = (brow < N);

    for (int k0 = 0; k0 < K; k0 += BK) {
        ushort4 au = *(const ushort4*)(Aptr + k0);
        float4 bv = bvalid ? *(const float4*)(Bptr + k0) : make_float4(0.f, 0.f, 0.f, 0.f);
        __syncthreads();
        As[lc + 0][lr] = bu(au.x);
        As[lc + 1][lr] = bu(au.y);
        As[lc + 2][lr] = bu(au.z);
        As[lc + 3][lr] = bu(au.w);
        Bs[lc + 0][lr] = bv.x; Bs[lc + 1][lr] = bv.y;
        Bs[lc + 2][lr] = bv.z; Bs[lc + 3][lr] = bv.w;
        __syncthreads();
#pragma unroll
        for (int k = 0; k < BK; ++k) {
            float a0 = As[k][ty * 4 + 0], a1 = As[k][ty * 4 + 1];
            float a2 = As[k][ty * 4 + 2], a3 = As[k][ty * 4 + 3];
            float b0 = Bs[k][tx * 4 + 0], b1 = Bs[k][tx * 4 + 1];
            float b2 = Bs[k][tx * 4 + 2], b3 = Bs[k][tx * 4 + 3];
            acc[0][0] += a0 * b0; acc[0][1] += a0 * b1; acc[0][2] += a0 * b2; acc[0][3] += a0 * b3;
            acc[1][0] += a1 * b0; acc[1][1] += a1 * b1; acc[1][2] += a1 * b2; acc[1][3] += a1 * b3;
            acc[2][0] += a2 * b0; acc[2][1] += a2 * b1; acc[2][2] += a2 * b2; acc[2][3] += a2 * b3;
            acc[3][0] += a3 * b0; acc[3][1] += a3 * b1; acc[3][2] += a3 * b2; acc[3][3] += a3 * b3;
        }
    }
#pragma unroll
    for (int i = 0; i < 4; ++i) {
        int row = bm + ty * 4 + i;
#pragma unroll
        for (int j = 0; j < 4; ++j) {
            int col = bn + tx * 4 + j;
            if (col < N) C[(size_t)row * N + col] = acc[i][j];
        }
    }
}

// ---------------------------------------------------------------------------
extern "C" void kernel_launch(void* const* d_in, const int* in_sizes, int n_in,
                              void* d_out, int out_size, void* d_ws, size_t ws_size,
                              hipStream_t stream) {
    (void)in_sizes; (void)n_in; (void)out_size; (void)ws_size;
    const float* u          = (const float*)d_in[0];
    const float* in_proj_w  = (const float*)d_in[1];
    const float* conv_w     = (const float*)d_in[2];
    const float* conv_b     = (const float*)d_in[3];
    const float* norm_w     = (const float*)d_in[4];
    const float* out_proj_w = (const float*)d_in[5];
    const float* A_log      = (const float*)d_in[6];
    const float* Dp         = (const float*)d_in[7];
    const float* dt_bias    = (const float*)d_in[8];

    // workspace: Z 50.33MB | XBC 58.72MB (aliased by states f32 50.33MB after K2)
    //            xy 50.33MB | Bb 4.19 | Cb 4.19 | dtraw 1.57 | dtb 1.57 | cdecay 12KB
    char* w = (char*)d_ws;
    bf16*  Zb     = (bf16*)w;     w += (size_t)NTOK * D_INNER * 2;
    bf16*  XBC    = (bf16*)w;     w += (size_t)NTOK * D_CONV_IN * 2;
    bf16*  xy     = (bf16*)w;     w += (size_t)NTOK * D_INNER * 2;
    bf16*  Bb     = (bf16*)w;     w += (size_t)NTOK * D_STATE * 2;
    bf16*  Cb     = (bf16*)w;     w += (size_t)NTOK * D_STATE * 2;
    float* dtraw  = (float*)w;    w += (size_t)NTOK * NHEADS * 4;
    float* dtb    = (float*)w;    w += (size_t)NTOK * NHEADS * 4;
    float* cdecay = (float*)w;
    float* states = (float*)XBC;   // alias: XBC is dead after conv_norm

    dim3 g1((D_IN_PROJ + 63) / 64, NTOK / 64);
    gemm_in<<<g1, 256, 0, stream>>>(u, in_proj_w, Zb, XBC, dtraw, NTOK, D_IN_PROJ, D_MODEL);

    conv_norm_kernel<<<NTOK, 256, 0, stream>>>(XBC, dtraw, conv_w, conv_b, norm_w, dt_bias,
                                               xy, Bb, Cb, dtb);

    chunk_state_kernel<<<NCHB, 256, 0, stream>>>(xy, Bb, dtb, A_log, states, cdecay);
    state_pass_kernel<<<BATCH * NHEADS, 256, 0, stream>>>(states, cdecay);
    chunk_output_kernel<<<NCHB, 128, 0, stream>>>(Zb, xy, Bb, Cb, dtb, A_log, Dp, states);

    dim3 g4(D_MODEL / 64, NTOK / 64);
    gemm_out<<<g4, 256, 0, stream>>>(xy, out_proj_w, (float*)d_out, NTOK, D_MODEL, D_INNER);
}

// Round 4
// 972.084 us; speedup vs baseline: 2.6653x; 1.6250x over previous
//
#include <hip/hip_runtime.h>
#include <hip/hip_bf16.h>
#include <cstddef>

#define D_MODEL   384
#define D_IN_PROJ 1676
#define D_INNER   768
#define D_CONV_IN 896
#define ZXLD      1664
#define NHEADS    12
#define HEADDIM   64
#define D_STATE   64
#define SEQLEN    4096
#define BATCH     8
#define NTOK      (BATCH * SEQLEN)
#define EPSV      1e-5f
#define Q         128
#define NCHUNK    (SEQLEN / Q)
#define NCHB      (BATCH * NHEADS * NCHUNK)

typedef __hip_bfloat16 bf16;
typedef __attribute__((ext_vector_type(8))) short bf16x8v;
typedef __attribute__((ext_vector_type(4))) float f32x4v;

__device__ __forceinline__ float b2f(bf16 v) { return __bfloat162float(v); }
__device__ __forceinline__ bf16  f2b(float v) { return __float2bfloat16(v); }
__device__ __forceinline__ float bl(unsigned u)  { return __uint_as_float(u << 16); }
__device__ __forceinline__ float bh(unsigned u)  { return __uint_as_float(u & 0xffff0000u); }
__device__ __forceinline__ float bu(unsigned short v) { return __uint_as_float(((unsigned)v) << 16); }
__device__ __forceinline__ unsigned pk2(float a, float b) {
    return ((unsigned)__bfloat16_as_ushort(f2b(b)) << 16) | (unsigned)__bfloat16_as_ushort(f2b(a));
}
__device__ __forceinline__ int swzf(int r) { return (r ^ (r >> 2)) & 3; }

#define GL_LDS16(g, l) __builtin_amdgcn_global_load_lds( \
    (const __attribute__((address_space(1))) unsigned*)(g), \
    (__attribute__((address_space(3))) unsigned*)(l), 16, 0, 0)

// ---------------------------------------------------------------------------
// f32 -> bf16 conversion (vectorized, n divisible by 4)
// ---------------------------------------------------------------------------
__global__ __launch_bounds__(256)
void cvt_f32_bf16(const float* __restrict__ in, unsigned short* __restrict__ out, int n) {
    int i = (blockIdx.x * 256 + threadIdx.x) * 4;
    if (i + 3 < n) {
        float4 v = *(const float4*)(in + i);
        uint2 o; o.x = pk2(v.x, v.y); o.y = pk2(v.z, v.w);
        *(uint2*)(out + i) = o;
    }
}

// ---------------------------------------------------------------------------
// dt columns in exact f32: dtraw[row][h] = u[row][:] . in_proj_w[1664+h][:]
// ---------------------------------------------------------------------------
__global__ __launch_bounds__(256)
void dt_gemm(const float* __restrict__ u, const float* __restrict__ W,
             float* __restrict__ dtraw) {
    int g = blockIdx.x * 256 + threadIdx.x;
    int row = g / NHEADS, head = g % NHEADS;
    const float4* ur = (const float4*)(u + (size_t)row * D_MODEL);
    const float4* wr = (const float4*)(W + (size_t)(ZXLD + head) * D_MODEL);
    float acc = 0.f;
#pragma unroll 8
    for (int k = 0; k < D_MODEL / 4; ++k) {
        float4 a = ur[k], b = wr[k];
        acc += a.x * b.x + a.y * b.y + a.z * b.z + a.w * b.w;
    }
    dtraw[g] = acc;
}

// ---------------------------------------------------------------------------
// MFMA GEMM-NT: C[m][n] = sum_k A[m][k] * Bw[n][k], bf16 inputs, f32 acc.
// 128x128 tile, 4 waves x (64x64), BK=32, 16x16x32 bf16 MFMA.
// LDS linear dest for global_load_lds; XOR slot swizzle via pre-swizzled
// global source + swizzled ds_read (T2 both-sides rule).
// EPI 0: route cols <768 -> Z bf16, 768..1663 -> XBC bf16 (N=1664 exact)
// EPI 1: f32 out, stride D_MODEL (N=384 exact)
// ---------------------------------------------------------------------------
template<int EPI>
__global__ __launch_bounds__(256)
void gemm_mfma(const bf16* __restrict__ A, const bf16* __restrict__ Bw, int K,
               bf16* __restrict__ Zo, bf16* __restrict__ XBCo, float* __restrict__ Co) {
    __shared__ short As[128 * 32];
    __shared__ short Bs[128 * 32];
    const int tid = threadIdx.x;
    const int lane = tid & 63;
    const int w = tid >> 6;
    const int wr = w >> 1, wc = w & 1;
    const int bm = blockIdx.y * 128;
    const int bn = blockIdx.x * 128;

    f32x4v acc[4][4];
#pragma unroll
    for (int mi = 0; mi < 4; ++mi)
#pragma unroll
        for (int ni = 0; ni < 4; ++ni)
            acc[mi][ni] = (f32x4v){0.f, 0.f, 0.f, 0.f};

    // staging source offsets (pre-swizzled): chunk q -> LDS bytes q*4096 + tid*16
    size_t aoff[2]; size_t boff[2];
#pragma unroll
    for (int q = 0; q < 2; ++q) {
        int o = q * 4096 + tid * 16;
        int row = o >> 6;                 // 0..127
        int ps = (o >> 4) & 3;            // physical 16B slot
        int sl = ps ^ swzf(row);          // logical slot stored here
        aoff[q] = (size_t)(bm + row) * K + sl * 8;
        boff[q] = (size_t)(bn + row) * K + sl * 8;
    }
    short* adst0 = As + tid * 8;          short* adst1 = As + 2048 + tid * 8;
    short* bdst0 = Bs + tid * 8;          short* bdst1 = Bs + 2048 + tid * 8;

    // fragment read addresses (element idx into [128][32] LDS, swizzled)
    int aidx[4], bidx[4];
#pragma unroll
    for (int i = 0; i < 4; ++i) {
        int ra = wr * 64 + i * 16 + (lane & 15);
        int rb = wc * 64 + i * 16 + (lane & 15);
        aidx[i] = ra * 32 + (((lane >> 4) ^ swzf(ra)) * 8);
        bidx[i] = rb * 32 + (((lane >> 4) ^ swzf(rb)) * 8);
    }

    for (int k0 = 0; k0 < K; k0 += 32) {
        __syncthreads();   // previous iter's ds_reads done before overwrite
        GL_LDS16(A + aoff[0] + k0, adst0);
        GL_LDS16(A + aoff[1] + k0, adst1);
        GL_LDS16(Bw + boff[0] + k0, bdst0);
        GL_LDS16(Bw + boff[1] + k0, bdst1);
        __syncthreads();   // loads complete (compiler inserts vmcnt(0))

        bf16x8v af[4], bf[4];
#pragma unroll
        for (int i = 0; i < 4; ++i) {
            af[i] = *(const bf16x8v*)(As + aidx[i]);
            bf[i] = *(const bf16x8v*)(Bs + bidx[i]);
        }
#pragma unroll
        for (int mi = 0; mi < 4; ++mi)
#pragma unroll
            for (int ni = 0; ni < 4; ++ni)
                acc[mi][ni] = __builtin_amdgcn_mfma_f32_16x16x32_bf16(
                    af[mi], bf[ni], acc[mi][ni], 0, 0, 0);
    }

    const int l15 = lane & 15, l4 = lane >> 4;
#pragma unroll
    for (int mi = 0; mi < 4; ++mi) {
        int rbase = bm + wr * 64 + mi * 16 + l4 * 4;
#pragma unroll
        for (int ni = 0; ni < 4; ++ni) {
            int col = bn + wc * 64 + ni * 16 + l15;
            f32x4v v = acc[mi][ni];
            if (EPI == 0) {
                if (col < D_INNER) {
#pragma unroll
                    for (int j = 0; j < 4; ++j)
                        Zo[(size_t)(rbase + j) * D_INNER + col] = f2b(v[j]);
                } else {
#pragma unroll
                    for (int j = 0; j < 4; ++j)
                        XBCo[(size_t)(rbase + j) * D_CONV_IN + (col - D_INNER)] = f2b(v[j]);
                }
            } else {
#pragma unroll
                for (int j = 0; j < 4; ++j)
                    Co[(size_t)(rbase + j) * D_MODEL + col] = v[j];
            }
        }
    }
}

// ---------------------------------------------------------------------------
// K2: causal conv(4) + bias + SiLU + split + RMSNorm(x) + softplus(dt)
// ---------------------------------------------------------------------------
__global__ __launch_bounds__(256)
void conv_norm_kernel(const bf16* __restrict__ XBC, const float* __restrict__ dtraw,
                      const float* __restrict__ conv_w, const float* __restrict__ conv_b,
                      const float* __restrict__ norm_w, const float* __restrict__ dt_bias,
                      bf16* __restrict__ xn, bf16* __restrict__ Bb,
                      bf16* __restrict__ Cb, float* __restrict__ dtb) {
    const int token = blockIdx.x;
    const int l = token & (SEQLEN - 1);
    __shared__ float sval[D_CONV_IN];
    __shared__ float ssum[4];
    float partial = 0.f;

    for (int c = threadIdx.x; c < D_CONV_IN; c += 256) {
        float acc = conv_b[c];
#pragma unroll
        for (int j = 0; j < 4; ++j) {
            int lt = l - 3 + j;
            if (lt >= 0)
                acc += b2f(XBC[(size_t)(token - 3 + j) * D_CONV_IN + c]) * conv_w[c * 4 + j];
        }
        float s = acc / (1.f + expf(-acc));
        sval[c] = s;
        if (c < D_INNER) partial += s * s;
    }
    for (int off = 32; off > 0; off >>= 1) partial += __shfl_down(partial, off, 64);
    if ((threadIdx.x & 63) == 0) ssum[threadIdx.x >> 6] = partial;
    __syncthreads();
    float total = ssum[0] + ssum[1] + ssum[2] + ssum[3];
    float scale = rsqrtf(total / (float)D_INNER + EPSV);

    for (int c = threadIdx.x; c < D_CONV_IN; c += 256) {
        float s = sval[c];
        if (c < D_INNER)
            xn[(size_t)token * D_INNER + c] = f2b(s * scale * norm_w[c]);
        else if (c < D_INNER + D_STATE)
            Bb[(size_t)token * D_STATE + (c - D_INNER)] = f2b(s);
        else
            Cb[(size_t)token * D_STATE + (c - D_INNER - D_STATE)] = f2b(s);
    }
    if (threadIdx.x < NHEADS) {
        float v = dtraw[(size_t)token * NHEADS + threadIdx.x] + dt_bias[threadIdx.x];
        float sp = (v > 20.f) ? v : log1pf(expf(v));
        dtb[(size_t)token * NHEADS + threadIdx.x] = sp;
    }
}

// ---------------------------------------------------------------------------
// K3a: per-chunk state S_c[n][p]
// ---------------------------------------------------------------------------
__global__ __launch_bounds__(256)
void chunk_state_kernel(const bf16* __restrict__ xy, const bf16* __restrict__ Bb,
                        const float* __restrict__ dtb, const float* __restrict__ A_log,
                        float* __restrict__ states, float* __restrict__ cdecay) {
    const int sid = blockIdx.x;
    const int c = sid % NCHUNK;
    const int h = (sid / NCHUNK) % NHEADS;
    const int b = sid / (NCHUNK * NHEADS);
    const int tid = threadIdx.x;
    const size_t tok0 = (size_t)b * SEQLEN + (size_t)c * Q;
    const float Acoef = -expf(A_log[h]);

    __shared__ __align__(16) unsigned short sBdt[Q * 64];
    __shared__ __align__(16) unsigned short sx[Q * 64];
    __shared__ float slcum[Q];
    __shared__ float sdt[Q];
    __shared__ float wtot[2];

    float lx = 0.f;
    if (tid < Q) {
        float dtv = dtb[(tok0 + tid) * NHEADS + h];
        sdt[tid] = dtv;
        lx = dtv * Acoef;
        int lane = tid & 63;
        for (int off = 1; off < 64; off <<= 1) {
            float v = __shfl_up(lx, off, 64);
            if (lane >= off) lx += v;
        }
        if (lane == 63) wtot[tid >> 6] = lx;
    }
    __syncthreads();
    if (tid < Q) {
        if (tid >= 64) lx += wtot[0];
        slcum[tid] = lx;
    }
    __syncthreads();
    const float ltot = slcum[Q - 1];

    for (int i4 = tid; i4 < Q * 64 / 8; i4 += 256) {
        uint4 bv = ((const uint4*)(Bb + tok0 * D_STATE))[i4];
        float dtv = sdt[i4 >> 3];
        uint4 ov;
        ov.x = pk2(bl(bv.x) * dtv, bh(bv.x) * dtv);
        ov.y = pk2(bl(bv.y) * dtv, bh(bv.y) * dtv);
        ov.z = pk2(bl(bv.z) * dtv, bh(bv.z) * dtv);
        ov.w = pk2(bl(bv.w) * dtv, bh(bv.w) * dtv);
        ((uint4*)sBdt)[i4] = ov;
        int t = i4 >> 3, k = i4 & 7;
        ((uint4*)sx)[i4] = *(const uint4*)(xy + (tok0 + t) * D_INNER + h * HEADDIM + k * 8);
    }
    __syncthreads();

    const int p = tid & 63, g = tid >> 6;
    float S[16];
#pragma unroll
    for (int i = 0; i < 16; ++i) S[i] = 0.f;

    for (int t = 0; t < Q; ++t) {
        float w = __expf(ltot - slcum[t]);
        float xv = bu(sx[t * 64 + p]);
        float wx = w * xv;
        const uint4* brow = (const uint4*)(sBdt + t * 64);
        uint4 b0 = brow[g * 2], b1 = brow[g * 2 + 1];
        S[0] += bl(b0.x) * wx; S[1] += bh(b0.x) * wx;
        S[2] += bl(b0.y) * wx; S[3] += bh(b0.y) * wx;
        S[4] += bl(b0.z) * wx; S[5] += bh(b0.z) * wx;
        S[6] += bl(b0.w) * wx; S[7] += bh(b0.w) * wx;
        S[8]  += bl(b1.x) * wx; S[9]  += bh(b1.x) * wx;
        S[10] += bl(b1.y) * wx; S[11] += bh(b1.y) * wx;
        S[12] += bl(b1.z) * wx; S[13] += bh(b1.z) * wx;
        S[14] += bl(b1.w) * wx; S[15] += bh(b1.w) * wx;
    }
    float* out = states + (size_t)sid * 4096;
#pragma unroll
    for (int i = 0; i < 16; ++i) out[(g * 16 + i) * 64 + p] = S[i];
    if (tid == 0) cdecay[sid] = expf(ltot);
}

// ---------------------------------------------------------------------------
// K3b: sequential inter-chunk recurrence
// ---------------------------------------------------------------------------
__global__ __launch_bounds__(256)
void state_pass_kernel(float* __restrict__ states, const float* __restrict__ cdecay) {
    const int bh = blockIdx.x;
    const int tid = threadIdx.x;
    float run[16];
#pragma unroll
    for (int i = 0; i < 16; ++i) run[i] = 0.f;
    float* base = states + (size_t)bh * NCHUNK * 4096 + tid * 16;
    const float* cd = cdecay + bh * NCHUNK;
    for (int c = 0; c < NCHUNK; ++c) {
        float dec = cd[c];
        float* ptr = base + (size_t)c * 4096;
        float4 s0 = *(float4*)(ptr + 0);
        float4 s1 = *(float4*)(ptr + 4);
        float4 s2 = *(float4*)(ptr + 8);
        float4 s3 = *(float4*)(ptr + 12);
        float nr[16];
        nr[0] = dec * run[0] + s0.x;  nr[1] = dec * run[1] + s0.y;
        nr[2] = dec * run[2] + s0.z;  nr[3] = dec * run[3] + s0.w;
        nr[4] = dec * run[4] + s1.x;  nr[5] = dec * run[5] + s1.y;
        nr[6] = dec * run[6] + s1.z;  nr[7] = dec * run[7] + s1.w;
        nr[8] = dec * run[8] + s2.x;  nr[9] = dec * run[9] + s2.y;
        nr[10] = dec * run[10] + s2.z; nr[11] = dec * run[11] + s2.w;
        nr[12] = dec * run[12] + s3.x; nr[13] = dec * run[13] + s3.y;
        nr[14] = dec * run[14] + s3.z; nr[15] = dec * run[15] + s3.w;
        *(float4*)(ptr + 0)  = make_float4(run[0], run[1], run[2], run[3]);
        *(float4*)(ptr + 4)  = make_float4(run[4], run[5], run[6], run[7]);
        *(float4*)(ptr + 8)  = make_float4(run[8], run[9], run[10], run[11]);
        *(float4*)(ptr + 12) = make_float4(run[12], run[13], run[14], run[15]);
#pragma unroll
        for (int i = 0; i < 16; ++i) run[i] = nr[i];
    }
}

// ---------------------------------------------------------------------------
// K3c: per-token output
// ---------------------------------------------------------------------------
__global__ __launch_bounds__(128)
void chunk_output_kernel(const bf16* __restrict__ Zb, bf16* __restrict__ xy,
                         const bf16* __restrict__ Bb, const bf16* __restrict__ Cb,
                         const float* __restrict__ dtb, const float* __restrict__ A_log,
                         const float* __restrict__ Dpa, const float* __restrict__ states) {
    const int sid = blockIdx.x;
    const int c = sid % NCHUNK;
    const int h = (sid / NCHUNK) % NHEADS;
    const int b = sid / (NCHUNK * NHEADS);
    const int tid = threadIdx.x;
    const int t = tid;
    const size_t tok0 = (size_t)b * SEQLEN + (size_t)c * Q;
    const float Acoef = -expf(A_log[h]);

    __shared__ __align__(16) unsigned short sBdt[Q * 64];
    __shared__ __align__(16) unsigned short sx[Q * 64];
    __shared__ __align__(16) unsigned short sCt[64 * Q];
    __shared__ float slcum[Q];
    __shared__ float sdt[Q];
    __shared__ float wtot[2];

    float dtv = dtb[(tok0 + t) * NHEADS + h];
    float lx = dtv * Acoef;
    {
        int lane = t & 63;
        for (int off = 1; off < 64; off <<= 1) {
            float v = __shfl_up(lx, off, 64);
            if (lane >= off) lx += v;
        }
        if (lane == 63) wtot[t >> 6] = lx;
        sdt[t] = dtv;
    }
    __syncthreads();
    if (t >= 64) lx += wtot[0];
    slcum[t] = lx;
    __syncthreads();
    const float lct = slcum[t];

    for (int i4 = tid; i4 < Q * 64 / 8; i4 += 128) {
        int tt = i4 >> 3, k = i4 & 7;
        uint4 bv = ((const uint4*)(Bb + tok0 * D_STATE))[i4];
        float dd = sdt[tt];
        uint4 ov;
        ov.x = pk2(bl(bv.x) * dd, bh(bv.x) * dd);
        ov.y = pk2(bl(bv.y) * dd, bh(bv.y) * dd);
        ov.z = pk2(bl(bv.z) * dd, bh(bv.z) * dd);
        ov.w = pk2(bl(bv.w) * dd, bh(bv.w) * dd);
        ((uint4*)sBdt)[i4] = ov;
        ((uint4*)sx)[i4] = *(const uint4*)(xy + (tok0 + tt) * D_INNER + h * HEADDIM + k * 8);
        uint4 cv = ((const uint4*)(Cb + tok0 * D_STATE))[i4];
        int n0 = k * 8;
        sCt[(n0 + 0) * Q + tt] = (unsigned short)(cv.x & 0xffff);
        sCt[(n0 + 1) * Q + tt] = (unsigned short)(cv.x >> 16);
        sCt[(n0 + 2) * Q + tt] = (unsigned short)(cv.y & 0xffff);
        sCt[(n0 + 3) * Q + tt] = (unsigned short)(cv.y >> 16);
        sCt[(n0 + 4) * Q + tt] = (unsigned short)(cv.z & 0xffff);
        sCt[(n0 + 5) * Q + tt] = (unsigned short)(cv.z >> 16);
        sCt[(n0 + 6) * Q + tt] = (unsigned short)(cv.w & 0xffff);
        sCt[(n0 + 7) * Q + tt] = (unsigned short)(cv.w >> 16);
    }
    __syncthreads();

    float C[64];
    {
        const uint4* crow = (const uint4*)(Cb + (tok0 + t) * D_STATE);
#pragma unroll
        for (int k = 0; k < 8; ++k) {
            uint4 cv = crow[k];
            C[k * 8 + 0] = bl(cv.x); C[k * 8 + 1] = bh(cv.x);
            C[k * 8 + 2] = bl(cv.y); C[k * 8 + 3] = bh(cv.y);
            C[k * 8 + 4] = bl(cv.z); C[k * 8 + 5] = bh(cv.z);
            C[k * 8 + 6] = bl(cv.w); C[k * 8 + 7] = bh(cv.w);
        }
    }

    float y[64];
#pragma unroll
    for (int p = 0; p < 64; ++p) y[p] = 0.f;
    const float* init = states + (size_t)sid * 4096;
#pragma unroll 4
    for (int n = 0; n < 64; ++n) {
        float cn = bu(sCt[n * Q + t]);
#pragma unroll
        for (int p0 = 0; p0 < 64; p0 += 4) {
            float4 iv = *(const float4*)(init + n * 64 + p0);
            y[p0 + 0] += cn * iv.x; y[p0 + 1] += cn * iv.y;
            y[p0 + 2] += cn * iv.z; y[p0 + 3] += cn * iv.w;
        }
    }
    const float el = __expf(lct);
#pragma unroll
    for (int p = 0; p < 64; ++p) y[p] *= el;

    const int smax = t | 63;
    for (int s = 0; s <= smax; ++s) {
        float gdot = 0.f;
        const uint4* brow = (const uint4*)(sBdt + s * 64);
#pragma unroll
        for (int k = 0; k < 8; ++k) {
            uint4 bv = brow[k];
            gdot += C[k * 8 + 0] * bl(bv.x) + C[k * 8 + 1] * bh(bv.x)
                  + C[k * 8 + 2] * bl(bv.y) + C[k * 8 + 3] * bh(bv.y)
                  + C[k * 8 + 4] * bl(bv.z) + C[k * 8 + 5] * bh(bv.z)
                  + C[k * 8 + 6] * bl(bv.w) + C[k * 8 + 7] * bh(bv.w);
        }
        float m = (s <= t) ? gdot * __expf(lct - slcum[s]) : 0.f;
        const uint4* xrow = (const uint4*)(sx + s * 64);
#pragma unroll
        for (int k = 0; k < 8; ++k) {
            uint4 xv = xrow[k];
            y[k * 8 + 0] += m * bl(xv.x); y[k * 8 + 1] += m * bh(xv.x);
            y[k * 8 + 2] += m * bl(xv.y); y[k * 8 + 3] += m * bh(xv.y);
            y[k * 8 + 4] += m * bl(xv.z); y[k * 8 + 5] += m * bh(xv.z);
            y[k * 8 + 6] += m * bl(xv.w); y[k * 8 + 7] += m * bh(xv.w);
        }
    }

    const float Dh = Dpa[h];
    const size_t rowoff = (tok0 + t) * D_INNER + h * HEADDIM;
    const uint4* xrow = (const uint4*)(xy + rowoff);
    const uint4* zrow = (const uint4*)(Zb + rowoff);
    uint4* orow = (uint4*)(xy + rowoff);
#pragma unroll
    for (int k = 0; k < 8; ++k) {
        uint4 xv = xrow[k];
        uint4 zv = zrow[k];
        float xs[8] = {bl(xv.x), bh(xv.x), bl(xv.y), bh(xv.y), bl(xv.z), bh(xv.z), bl(xv.w), bh(xv.w)};
        float zs[8] = {bl(zv.x), bh(zv.x), bl(zv.y), bh(zv.y), bl(zv.z), bh(zv.z), bl(zv.w), bh(zv.w)};
        unsigned o[4];
#pragma unroll
        for (int j = 0; j < 4; ++j) {
            float y0 = y[k * 8 + 2 * j]     + Dh * xs[2 * j];
            float y1 = y[k * 8 + 2 * j + 1] + Dh * xs[2 * j + 1];
            float z0 = zs[2 * j], z1 = zs[2 * j + 1];
            y0 *= z0 / (1.f + __expf(-z0));
            y1 *= z1 / (1.f + __expf(-z1));
            o[j] = pk2(y0, y1);
        }
        uint4 ov; ov.x = o[0]; ov.y = o[1]; ov.z = o[2]; ov.w = o[3];
        orow[k] = ov;
    }
}

// ---------------------------------------------------------------------------
extern "C" void kernel_launch(void* const* d_in, const int* in_sizes, int n_in,
                              void* d_out, int out_size, void* d_ws, size_t ws_size,
                              hipStream_t stream) {
    (void)in_sizes; (void)n_in; (void)out_size; (void)ws_size;
    const float* u          = (const float*)d_in[0];
    const float* in_proj_w  = (const float*)d_in[1];
    const float* conv_w     = (const float*)d_in[2];
    const float* conv_b     = (const float*)d_in[3];
    const float* norm_w     = (const float*)d_in[4];
    const float* out_proj_w = (const float*)d_in[5];
    const float* A_log      = (const float*)d_in[6];
    const float* Dp         = (const float*)d_in[7];
    const float* dt_bias    = (const float*)d_in[8];

    // workspace: Zb 50.33 | XBC 58.72 (states aliases) | xy 50.33 (u_bf16 aliases
    // during K1) | Bb 4.19 | Cb 4.19 | dtraw 1.57 | dtb 1.57 | cdecay 12KB |
    // wA 1.28 | wO 0.59   total ~= 173 MB
    char* w = (char*)d_ws;
    bf16*  Zb     = (bf16*)w;     w += (size_t)NTOK * D_INNER * 2;
    bf16*  XBC    = (bf16*)w;     w += (size_t)NTOK * D_CONV_IN * 2;
    bf16*  xy     = (bf16*)w;     w += (size_t)NTOK * D_INNER * 2;
    bf16*  Bb     = (bf16*)w;     w += (size_t)NTOK * D_STATE * 2;
    bf16*  Cb     = (bf16*)w;     w += (size_t)NTOK * D_STATE * 2;
    float* dtraw  = (float*)w;    w += (size_t)NTOK * NHEADS * 4;
    float* dtb    = (float*)w;    w += (size_t)NTOK * NHEADS * 4;
    float* cdecay = (float*)w;    w += (size_t)NCHB * 4;
    bf16*  wA     = (bf16*)w;     w += (size_t)ZXLD * D_MODEL * 2;
    bf16*  wO     = (bf16*)w;
    float* states = (float*)XBC;   // alias: XBC dead after conv_norm
    bf16*  uB     = xy;            // alias: xy region free until conv_norm writes it

    // ---- bf16 conversions ----
    {
        int n = NTOK * D_MODEL;
        cvt_f32_bf16<<<(n / 4 + 255) / 256, 256, 0, stream>>>(u, (unsigned short*)uB, n);
    }
    {
        int n = ZXLD * D_MODEL;
        cvt_f32_bf16<<<(n / 4 + 255) / 256, 256, 0, stream>>>(in_proj_w, (unsigned short*)wA, n);
    }
    {
        int n = D_MODEL * D_INNER;
        cvt_f32_bf16<<<(n / 4 + 255) / 256, 256, 0, stream>>>(out_proj_w, (unsigned short*)wO, n);
    }

    // ---- exact f32 dt columns ----
    dt_gemm<<<NTOK * NHEADS / 256, 256, 0, stream>>>(u, in_proj_w, dtraw);

    // ---- K1: MFMA GEMM, N=1664 ----
    dim3 g1(ZXLD / 128, NTOK / 128);
    gemm_mfma<0><<<g1, 256, 0, stream>>>(uB, wA, D_MODEL, Zb, XBC, nullptr);

    conv_norm_kernel<<<NTOK, 256, 0, stream>>>(XBC, dtraw, conv_w, conv_b, norm_w, dt_bias,
                                               xy, Bb, Cb, dtb);

    chunk_state_kernel<<<NCHB, 256, 0, stream>>>(xy, Bb, dtb, A_log, states, cdecay);
    state_pass_kernel<<<BATCH * NHEADS, 256, 0, stream>>>(states, cdecay);
    chunk_output_kernel<<<NCHB, 128, 0, stream>>>(Zb, xy, Bb, Cb, dtb, A_log, Dp, states);

    // ---- K4: MFMA GEMM, N=384 ----
    dim3 g4(D_MODEL / 128, NTOK / 128);
    gemm_mfma<1><<<g4, 256, 0, stream>>>(xy, wO, D_INNER, nullptr, nullptr, (float*)d_out);
}

// Round 6
// 594.562 us; speedup vs baseline: 4.3577x; 1.6350x over previous
//
#include <hip/hip_runtime.h>
#include <hip/hip_bf16.h>
#include <cstddef>

#define D_MODEL   384
#define D_IN_PROJ 1676
#define D_INNER   768
#define D_CONV_IN 896
#define ZXLD      1664
#define NHEADS    12
#define HEADDIM   64
#define D_STATE   64
#define SEQLEN    4096
#define BATCH     8
#define NTOK      (BATCH * SEQLEN)
#define EPSV      1e-5f
#define Q         128
#define NCHUNK    (SEQLEN / Q)
#define NCHB      (BATCH * NHEADS * NCHUNK)
#define NBC       (BATCH * NCHUNK)          // 256 (b,chunk) pairs

typedef __hip_bfloat16 bf16;
typedef __attribute__((ext_vector_type(8))) short bf16x8v;
typedef __attribute__((ext_vector_type(4))) float f32x4v;

__device__ __forceinline__ float b2f(bf16 v) { return __bfloat162float(v); }
__device__ __forceinline__ bf16  f2b(float v) { return __float2bfloat16(v); }
__device__ __forceinline__ float bl(unsigned u)  { return __uint_as_float(u << 16); }
__device__ __forceinline__ float bh(unsigned u)  { return __uint_as_float(u & 0xffff0000u); }
__device__ __forceinline__ float bu(unsigned short v) { return __uint_as_float(((unsigned)v) << 16); }
__device__ __forceinline__ unsigned pk2(float a, float b) {
    return ((unsigned)__bfloat16_as_ushort(f2b(b)) << 16) | (unsigned)__bfloat16_as_ushort(f2b(a));
}
__device__ __forceinline__ int swzf(int r) { return (r ^ (r >> 2)) & 3; }

#define GL_LDS16(g, l) __builtin_amdgcn_global_load_lds( \
    (const __attribute__((address_space(1))) unsigned*)(g), \
    (__attribute__((address_space(3))) unsigned*)(l), 16, 0, 0)

// ---------------------------------------------------------------------------
__global__ __launch_bounds__(256)
void cvt_f32_bf16(const float* __restrict__ in, unsigned short* __restrict__ out, int n) {
    int i = (blockIdx.x * 256 + threadIdx.x) * 4;
    if (i + 3 < n) {
        float4 v = *(const float4*)(in + i);
        uint2 o; o.x = pk2(v.x, v.y); o.y = pk2(v.z, v.w);
        *(uint2*)(out + i) = o;
    }
}

// ---------------------------------------------------------------------------
__global__ __launch_bounds__(256)
void dt_gemm(const float* __restrict__ u, const float* __restrict__ W,
             float* __restrict__ dtraw) {
    int g = blockIdx.x * 256 + threadIdx.x;
    int row = g / NHEADS, head = g % NHEADS;
    const float4* ur = (const float4*)(u + (size_t)row * D_MODEL);
    const float4* wr = (const float4*)(W + (size_t)(ZXLD + head) * D_MODEL);
    float acc = 0.f;
#pragma unroll 8
    for (int k = 0; k < D_MODEL / 4; ++k) {
        float4 a = ur[k], b = wr[k];
        acc += a.x * b.x + a.y * b.y + a.z * b.z + a.w * b.w;
    }
    dtraw[g] = acc;
}

// ---------------------------------------------------------------------------
// MFMA GEMM-NT (unchanged)
// ---------------------------------------------------------------------------
template<int EPI>
__global__ __launch_bounds__(256)
void gemm_mfma(const bf16* __restrict__ A, const bf16* __restrict__ Bw, int K,
               bf16* __restrict__ Zo, bf16* __restrict__ XBCo, float* __restrict__ Co) {
    __shared__ short As[128 * 32];
    __shared__ short Bs[128 * 32];
    const int tid = threadIdx.x;
    const int lane = tid & 63;
    const int w = tid >> 6;
    const int wr = w >> 1, wc = w & 1;
    const int bm = blockIdx.y * 128;
    const int bn = blockIdx.x * 128;

    f32x4v acc[4][4];
#pragma unroll
    for (int mi = 0; mi < 4; ++mi)
#pragma unroll
        for (int ni = 0; ni < 4; ++ni)
            acc[mi][ni] = (f32x4v){0.f, 0.f, 0.f, 0.f};

    size_t aoff[2]; size_t boff[2];
#pragma unroll
    for (int q = 0; q < 2; ++q) {
        int o = q * 4096 + tid * 16;
        int row = o >> 6;
        int ps = (o >> 4) & 3;
        int sl = ps ^ swzf(row);
        aoff[q] = (size_t)(bm + row) * K + sl * 8;
        boff[q] = (size_t)(bn + row) * K + sl * 8;
    }
    short* adst0 = As + tid * 8;          short* adst1 = As + 2048 + tid * 8;
    short* bdst0 = Bs + tid * 8;          short* bdst1 = Bs + 2048 + tid * 8;

    int aidx[4], bidx[4];
#pragma unroll
    for (int i = 0; i < 4; ++i) {
        int ra = wr * 64 + i * 16 + (lane & 15);
        int rb = wc * 64 + i * 16 + (lane & 15);
        aidx[i] = ra * 32 + (((lane >> 4) ^ swzf(ra)) * 8);
        bidx[i] = rb * 32 + (((lane >> 4) ^ swzf(rb)) * 8);
    }

    for (int k0 = 0; k0 < K; k0 += 32) {
        __syncthreads();
        GL_LDS16(A + aoff[0] + k0, adst0);
        GL_LDS16(A + aoff[1] + k0, adst1);
        GL_LDS16(Bw + boff[0] + k0, bdst0);
        GL_LDS16(Bw + boff[1] + k0, bdst1);
        __syncthreads();

        bf16x8v af[4], bf[4];
#pragma unroll
        for (int i = 0; i < 4; ++i) {
            af[i] = *(const bf16x8v*)(As + aidx[i]);
            bf[i] = *(const bf16x8v*)(Bs + bidx[i]);
        }
#pragma unroll
        for (int mi = 0; mi < 4; ++mi)
#pragma unroll
            for (int ni = 0; ni < 4; ++ni)
                acc[mi][ni] = __builtin_amdgcn_mfma_f32_16x16x32_bf16(
                    af[mi], bf[ni], acc[mi][ni], 0, 0, 0);
    }

    const int l15 = lane & 15, l4 = lane >> 4;
#pragma unroll
    for (int mi = 0; mi < 4; ++mi) {
        int rbase = bm + wr * 64 + mi * 16 + l4 * 4;
#pragma unroll
        for (int ni = 0; ni < 4; ++ni) {
            int col = bn + wc * 64 + ni * 16 + l15;
            f32x4v v = acc[mi][ni];
            if (EPI == 0) {
                if (col < D_INNER) {
#pragma unroll
                    for (int j = 0; j < 4; ++j)
                        Zo[(size_t)(rbase + j) * D_INNER + col] = f2b(v[j]);
                } else {
#pragma unroll
                    for (int j = 0; j < 4; ++j)
                        XBCo[(size_t)(rbase + j) * D_CONV_IN + (col - D_INNER)] = f2b(v[j]);
                }
            } else {
#pragma unroll
                for (int j = 0; j < 4; ++j)
                    Co[(size_t)(rbase + j) * D_MODEL + col] = v[j];
            }
        }
    }
}

// ---------------------------------------------------------------------------
// K2: causal conv(4) + bias + SiLU + split + RMSNorm(x) + softplus(dt)
// ---------------------------------------------------------------------------
__global__ __launch_bounds__(256)
void conv_norm_kernel(const bf16* __restrict__ XBC, const float* __restrict__ dtraw,
                      const float* __restrict__ conv_w, const float* __restrict__ conv_b,
                      const float* __restrict__ norm_w, const float* __restrict__ dt_bias,
                      bf16* __restrict__ xn, bf16* __restrict__ Bb,
                      bf16* __restrict__ Cb, float* __restrict__ dtb) {
    const int token = blockIdx.x;
    const int l = token & (SEQLEN - 1);
    __shared__ float sval[D_CONV_IN];
    __shared__ float ssum[4];
    float partial = 0.f;

    for (int c = threadIdx.x; c < D_CONV_IN; c += 256) {
        float acc = conv_b[c];
#pragma unroll
        for (int j = 0; j < 4; ++j) {
            int lt = l - 3 + j;
            if (lt >= 0)
                acc += b2f(XBC[(size_t)(token - 3 + j) * D_CONV_IN + c]) * conv_w[c * 4 + j];
        }
        float s = acc / (1.f + expf(-acc));
        sval[c] = s;
        if (c < D_INNER) partial += s * s;
    }
    for (int off = 32; off > 0; off >>= 1) partial += __shfl_down(partial, off, 64);
    if ((threadIdx.x & 63) == 0) ssum[threadIdx.x >> 6] = partial;
    __syncthreads();
    float total = ssum[0] + ssum[1] + ssum[2] + ssum[3];
    float scale = rsqrtf(total / (float)D_INNER + EPSV);

    for (int c = threadIdx.x; c < D_CONV_IN; c += 256) {
        float s = sval[c];
        if (c < D_INNER)
            xn[(size_t)token * D_INNER + c] = f2b(s * scale * norm_w[c]);
        else if (c < D_INNER + D_STATE)
            Bb[(size_t)token * D_STATE + (c - D_INNER)] = f2b(s);
        else
            Cb[(size_t)token * D_STATE + (c - D_INNER - D_STATE)] = f2b(s);
    }
    if (threadIdx.x < NHEADS) {
        float v = dtraw[(size_t)token * NHEADS + threadIdx.x] + dt_bias[threadIdx.x];
        float sp = (v > 20.f) ? v : log1pf(expf(v));
        dtb[(size_t)token * NHEADS + threadIdx.x] = sp;
    }
}

// ---------------------------------------------------------------------------
// Score kernel: G_raw[bc][t][s] = sum_n C[t][n]*B[s][n]  (head-shared, NGROUPS=1)
// one block per (b,chunk); 128x128 out, K=64, 4 waves x 64x64.
// FIX r6: staging loop it<4 (was it<2 -> rows 64..127 uninitialized -> NaN)
// ---------------------------------------------------------------------------
__global__ __launch_bounds__(256)
void score_kernel(const bf16* __restrict__ Bb, const bf16* __restrict__ Cb,
                  bf16* __restrict__ Graw) {
    const int bc = blockIdx.x;
    const size_t tok0 = (size_t)bc * Q;
    const int tid = threadIdx.x;
    const int lane = tid & 63, w = tid >> 6;
    const int wr = w >> 1, wc = w & 1;
    __shared__ short sC[Q * 64];
    __shared__ short sB[Q * 64];

#pragma unroll
    for (int it = 0; it < 4; ++it) {
        int j = it * 256 + tid;
        int r = j >> 3, sp = j & 7;
        int sl = sp ^ (r & 7);
        GL_LDS16(Cb + tok0 * D_STATE + r * 64 + sl * 8, sC + j * 8);
        GL_LDS16(Bb + tok0 * D_STATE + r * 64 + sl * 8, sB + j * 8);
    }
    __syncthreads();

    const int l15 = lane & 15, qq = lane >> 4;
    f32x4v acc[4][4];
#pragma unroll
    for (int mi = 0; mi < 4; ++mi)
#pragma unroll
        for (int ni = 0; ni < 4; ++ni)
            acc[mi][ni] = (f32x4v){0.f, 0.f, 0.f, 0.f};

#pragma unroll
    for (int kb = 0; kb < 2; ++kb) {
        bf16x8v af[4], bf[4];
#pragma unroll
        for (int i = 0; i < 4; ++i) {
            int ra = wr * 64 + i * 16 + l15;
            int rb = wc * 64 + i * 16 + l15;
            af[i] = *(const bf16x8v*)(sC + ra * 64 + ((kb * 4 + qq) ^ (ra & 7)) * 8);
            bf[i] = *(const bf16x8v*)(sB + rb * 64 + ((kb * 4 + qq) ^ (rb & 7)) * 8);
        }
#pragma unroll
        for (int mi = 0; mi < 4; ++mi)
#pragma unroll
            for (int ni = 0; ni < 4; ++ni)
                acc[mi][ni] = __builtin_amdgcn_mfma_f32_16x16x32_bf16(
                    af[mi], bf[ni], acc[mi][ni], 0, 0, 0);
    }

    bf16* gout = Graw + (size_t)bc * (Q * Q);
#pragma unroll
    for (int mi = 0; mi < 4; ++mi) {
        int t0 = wr * 64 + mi * 16 + qq * 4;
#pragma unroll
        for (int ni = 0; ni < 4; ++ni) {
            int s = wc * 64 + ni * 16 + l15;
            f32x4v v = acc[mi][ni];
#pragma unroll
            for (int j = 0; j < 4; ++j)
                gout[(size_t)(t0 + j) * Q + s] = f2b(v[j]);
        }
    }
}

// ---------------------------------------------------------------------------
// K3a: per-chunk state (unchanged)
// ---------------------------------------------------------------------------
__global__ __launch_bounds__(256)
void chunk_state_kernel(const bf16* __restrict__ xy, const bf16* __restrict__ Bb,
                        const float* __restrict__ dtb, const float* __restrict__ A_log,
                        float* __restrict__ states, float* __restrict__ cdecay) {
    const int sid = blockIdx.x;
    const int c = sid % NCHUNK;
    const int h = (sid / NCHUNK) % NHEADS;
    const int b = sid / (NCHUNK * NHEADS);
    const int tid = threadIdx.x;
    const size_t tok0 = (size_t)b * SEQLEN + (size_t)c * Q;
    const float Acoef = -expf(A_log[h]);

    __shared__ __align__(16) unsigned short sBdt[Q * 64];
    __shared__ __align__(16) unsigned short sx[Q * 64];
    __shared__ float slcum[Q];
    __shared__ float sdt[Q];
    __shared__ float wtot[2];

    float lx = 0.f;
    if (tid < Q) {
        float dtv = dtb[(tok0 + tid) * NHEADS + h];
        sdt[tid] = dtv;
        lx = dtv * Acoef;
        int lane = tid & 63;
        for (int off = 1; off < 64; off <<= 1) {
            float v = __shfl_up(lx, off, 64);
            if (lane >= off) lx += v;
        }
        if (lane == 63) wtot[tid >> 6] = lx;
    }
    __syncthreads();
    if (tid < Q) {
        if (tid >= 64) lx += wtot[0];
        slcum[tid] = lx;
    }
    __syncthreads();
    const float ltot = slcum[Q - 1];

    for (int i4 = tid; i4 < Q * 64 / 8; i4 += 256) {
        uint4 bv = ((const uint4*)(Bb + tok0 * D_STATE))[i4];
        float dtv = sdt[i4 >> 3];
        uint4 ov;
        ov.x = pk2(bl(bv.x) * dtv, bh(bv.x) * dtv);
        ov.y = pk2(bl(bv.y) * dtv, bh(bv.y) * dtv);
        ov.z = pk2(bl(bv.z) * dtv, bh(bv.z) * dtv);
        ov.w = pk2(bl(bv.w) * dtv, bh(bv.w) * dtv);
        ((uint4*)sBdt)[i4] = ov;
        int t = i4 >> 3, k = i4 & 7;
        ((uint4*)sx)[i4] = *(const uint4*)(xy + (tok0 + t) * D_INNER + h * HEADDIM + k * 8);
    }
    __syncthreads();

    const int p = tid & 63, g = tid >> 6;
    float S[16];
#pragma unroll
    for (int i = 0; i < 16; ++i) S[i] = 0.f;

    for (int t = 0; t < Q; ++t) {
        float w = __expf(ltot - slcum[t]);
        float xv = bu(sx[t * 64 + p]);
        float wx = w * xv;
        const uint4* brow = (const uint4*)(sBdt + t * 64);
        uint4 b0 = brow[g * 2], b1 = brow[g * 2 + 1];
        S[0] += bl(b0.x) * wx; S[1] += bh(b0.x) * wx;
        S[2] += bl(b0.y) * wx; S[3] += bh(b0.y) * wx;
        S[4] += bl(b0.z) * wx; S[5] += bh(b0.z) * wx;
        S[6] += bl(b0.w) * wx; S[7] += bh(b0.w) * wx;
        S[8]  += bl(b1.x) * wx; S[9]  += bh(b1.x) * wx;
        S[10] += bl(b1.y) * wx; S[11] += bh(b1.y) * wx;
        S[12] += bl(b1.z) * wx; S[13] += bh(b1.z) * wx;
        S[14] += bl(b1.w) * wx; S[15] += bh(b1.w) * wx;
    }
    float* out = states + (size_t)sid * 4096;
#pragma unroll
    for (int i = 0; i < 16; ++i) out[(g * 16 + i) * 64 + p] = S[i];
    if (tid == 0) cdecay[sid] = expf(ltot);
}

// ---------------------------------------------------------------------------
// K3b: sequential inter-chunk recurrence (unchanged)
// ---------------------------------------------------------------------------
__global__ __launch_bounds__(256)
void state_pass_kernel(float* __restrict__ states, const float* __restrict__ cdecay) {
    const int bh = blockIdx.x;
    const int tid = threadIdx.x;
    float run[16];
#pragma unroll
    for (int i = 0; i < 16; ++i) run[i] = 0.f;
    float* base = states + (size_t)bh * NCHUNK * 4096 + tid * 16;
    const float* cd = cdecay + bh * NCHUNK;
    for (int c = 0; c < NCHUNK; ++c) {
        float dec = cd[c];
        float* ptr = base + (size_t)c * 4096;
        float4 s0 = *(float4*)(ptr + 0);
        float4 s1 = *(float4*)(ptr + 4);
        float4 s2 = *(float4*)(ptr + 8);
        float4 s3 = *(float4*)(ptr + 12);
        float nr[16];
        nr[0] = dec * run[0] + s0.x;  nr[1] = dec * run[1] + s0.y;
        nr[2] = dec * run[2] + s0.z;  nr[3] = dec * run[3] + s0.w;
        nr[4] = dec * run[4] + s1.x;  nr[5] = dec * run[5] + s1.y;
        nr[6] = dec * run[6] + s1.z;  nr[7] = dec * run[7] + s1.w;
        nr[8] = dec * run[8] + s2.x;  nr[9] = dec * run[9] + s2.y;
        nr[10] = dec * run[10] + s2.z; nr[11] = dec * run[11] + s2.w;
        nr[12] = dec * run[12] + s3.x; nr[13] = dec * run[13] + s3.y;
        nr[14] = dec * run[14] + s3.z; nr[15] = dec * run[15] + s3.w;
        *(float4*)(ptr + 0)  = make_float4(run[0], run[1], run[2], run[3]);
        *(float4*)(ptr + 4)  = make_float4(run[4], run[5], run[6], run[7]);
        *(float4*)(ptr + 8)  = make_float4(run[8], run[9], run[10], run[11]);
        *(float4*)(ptr + 12) = make_float4(run[12], run[13], run[14], run[15]);
#pragma unroll
        for (int i = 0; i < 16; ++i) run[i] = nr[i];
    }
}

// ---------------------------------------------------------------------------
// K3c (MFMA): per-token output (unchanged from round 5)
// ---------------------------------------------------------------------------
__global__ __launch_bounds__(256)
void chunk_output_mfma(const bf16* __restrict__ Zb, bf16* __restrict__ xy,
                       const bf16* __restrict__ Cb, const bf16* __restrict__ Graw,
                       const float* __restrict__ dtb, const float* __restrict__ A_log,
                       const float* __restrict__ Dpa, const float* __restrict__ states) {
    const int sid = blockIdx.x;
    const int c = sid % NCHUNK;
    const int h = (sid / NCHUNK) % NHEADS;
    const int b = sid / (NCHUNK * NHEADS);
    const int tid = threadIdx.x;
    const int lane = tid & 63, w = tid >> 6;
    const int wr = w >> 1, wc = w & 1;
    const size_t tok0 = (size_t)b * SEQLEN + (size_t)c * Q;
    const int bc = b * NCHUNK + c;
    const float Acoef = -expf(A_log[h]);

    __shared__ __align__(16) float slcum[Q];
    __shared__ __align__(16) float sdt[Q];
    __shared__ float wtot[2];
    __shared__ __align__(16) unsigned short sXt[64][136];   // X^T [p][s]
    __shared__ __align__(16) unsigned short sNh[64][72];    // init^T hi [p][n]
    __shared__ __align__(16) unsigned short sNl[64][72];    // init^T lo [p][n]

    float lx = 0.f;
    if (tid < Q) {
        float dtv = dtb[(tok0 + tid) * NHEADS + h];
        sdt[tid] = dtv;
        lx = dtv * Acoef;
        int ln = tid & 63;
        for (int off = 1; off < 64; off <<= 1) {
            float v = __shfl_up(lx, off, 64);
            if (ln >= off) lx += v;
        }
        if (ln == 63) wtot[tid >> 6] = lx;
    }
    __syncthreads();
    if (tid < Q) {
        if (tid >= 64) lx += wtot[0];
        slcum[tid] = lx;
    }

    {
        int t = tid >> 1, ph = (tid & 1) * 32;
        const unsigned short* xr = (const unsigned short*)(xy + (tok0 + t) * D_INNER + h * HEADDIM + ph);
#pragma unroll
        for (int i = 0; i < 32; ++i) sXt[ph + i][t] = xr[i];
    }
    {
        const float* init = states + (size_t)sid * 4096;
        for (int i = tid; i < 1024; i += 256) {
            float4 v = ((const float4*)init)[i];
            int n = i >> 4;
            int p = (i & 15) * 4;
#pragma unroll
            for (int j2 = 0; j2 < 4; ++j2) {
                float f = (&v.x)[j2];
                bf16 hi = f2b(f);
                float lo = f - b2f(hi);
                sNh[p + j2][n] = __bfloat16_as_ushort(hi);
                sNl[p + j2][n] = __bfloat16_as_ushort(f2b(lo));
            }
        }
    }
    __syncthreads();

    const int l15 = lane & 15, qq = lane >> 4;
    const int twr = wr * 64;

    float lct_mi[4], elct[4];
    int tcur[4];
#pragma unroll
    for (int mi = 0; mi < 4; ++mi) {
        tcur[mi] = twr + mi * 16 + l15;
        lct_mi[mi] = slcum[tcur[mi]];
        elct[mi] = __expf(lct_mi[mi]);
    }

    f32x4v acc[4][2];
#pragma unroll
    for (int mi = 0; mi < 4; ++mi)
#pragma unroll
        for (int ni = 0; ni < 2; ++ni)
            acc[mi][ni] = (f32x4v){0.f, 0.f, 0.f, 0.f};

    const bf16* grow = Graw + (size_t)bc * (Q * Q);

#pragma unroll
    for (int kb = 0; kb < 4; ++kb) {
        const int s0 = kb * 32 + qq * 8;
        float4 lcA = *(const float4*)(slcum + s0);
        float4 lcB = *(const float4*)(slcum + s0 + 4);
        float4 dtA = *(const float4*)(sdt + s0);
        float4 dtB = *(const float4*)(sdt + s0 + 4);
        bf16x8v af[4];
#pragma unroll
        for (int mi = 0; mi < 4; ++mi) {
            int t = tcur[mi];
            float lct = lct_mi[mi];
            uint4 gv = *(const uint4*)(grow + (size_t)t * Q + s0);
            float f0 = (s0 + 0 <= t) ? bl(gv.x) * dtA.x * __expf(lct - lcA.x) : 0.f;
            float f1 = (s0 + 1 <= t) ? bh(gv.x) * dtA.y * __expf(lct - lcA.y) : 0.f;
            float f2 = (s0 + 2 <= t) ? bl(gv.y) * dtA.z * __expf(lct - lcA.z) : 0.f;
            float f3 = (s0 + 3 <= t) ? bh(gv.y) * dtA.w * __expf(lct - lcA.w) : 0.f;
            float f4 = (s0 + 4 <= t) ? bl(gv.z) * dtB.x * __expf(lct - lcB.x) : 0.f;
            float f5 = (s0 + 5 <= t) ? bh(gv.z) * dtB.y * __expf(lct - lcB.y) : 0.f;
            float f6 = (s0 + 6 <= t) ? bl(gv.w) * dtB.z * __expf(lct - lcB.z) : 0.f;
            float f7 = (s0 + 7 <= t) ? bh(gv.w) * dtB.w * __expf(lct - lcB.w) : 0.f;
            union { bf16x8v v; unsigned u[4]; } r;
            r.u[0] = pk2(f0, f1); r.u[1] = pk2(f2, f3);
            r.u[2] = pk2(f4, f5); r.u[3] = pk2(f6, f7);
            af[mi] = r.v;
        }
        bf16x8v bfr[2];
#pragma unroll
        for (int ni = 0; ni < 2; ++ni) {
            int p = wc * 32 + ni * 16 + l15;
            bfr[ni] = *(const bf16x8v*)(&sXt[p][s0]);
        }
#pragma unroll
        for (int mi = 0; mi < 4; ++mi)
#pragma unroll
            for (int ni = 0; ni < 2; ++ni)
                acc[mi][ni] = __builtin_amdgcn_mfma_f32_16x16x32_bf16(
                    af[mi], bfr[ni], acc[mi][ni], 0, 0, 0);
    }

#pragma unroll
    for (int half = 0; half < 2; ++half) {
        const int n0 = half * 32 + qq * 8;
        bf16x8v af[4];
#pragma unroll
        for (int mi = 0; mi < 4; ++mi) {
            uint4 cv = *(const uint4*)(Cb + (tok0 + tcur[mi]) * D_STATE + n0);
            float el = elct[mi];
            union { bf16x8v v; unsigned u[4]; } r;
            r.u[0] = pk2(bl(cv.x) * el, bh(cv.x) * el);
            r.u[1] = pk2(bl(cv.y) * el, bh(cv.y) * el);
            r.u[2] = pk2(bl(cv.z) * el, bh(cv.z) * el);
            r.u[3] = pk2(bl(cv.w) * el, bh(cv.w) * el);
            af[mi] = r.v;
        }
        bf16x8v bh_[2], bl_[2];
#pragma unroll
        for (int ni = 0; ni < 2; ++ni) {
            int p = wc * 32 + ni * 16 + l15;
            bh_[ni] = *(const bf16x8v*)(&sNh[p][n0]);
            bl_[ni] = *(const bf16x8v*)(&sNl[p][n0]);
        }
#pragma unroll
        for (int mi = 0; mi < 4; ++mi)
#pragma unroll
            for (int ni = 0; ni < 2; ++ni) {
                acc[mi][ni] = __builtin_amdgcn_mfma_f32_16x16x32_bf16(
                    af[mi], bh_[ni], acc[mi][ni], 0, 0, 0);
                acc[mi][ni] = __builtin_amdgcn_mfma_f32_16x16x32_bf16(
                    af[mi], bl_[ni], acc[mi][ni], 0, 0, 0);
            }
    }

    const float Dh = Dpa[h];
#pragma unroll
    for (int mi = 0; mi < 4; ++mi) {
        int t0 = twr + mi * 16 + qq * 4;
#pragma unroll
        for (int ni = 0; ni < 2; ++ni) {
            int p = wc * 32 + ni * 16 + l15;
            f32x4v v = acc[mi][ni];
#pragma unroll
            for (int jj = 0; jj < 4; ++jj) {
                size_t off = (tok0 + t0 + jj) * D_INNER + h * HEADDIM + p;
                float xv = b2f(xy[off]);
                float zv = b2f(Zb[off]);
                float yv = v[jj] + Dh * xv;
                yv *= zv / (1.f + __expf(-zv));
                xy[off] = f2b(yv);
            }
        }
    }
}

// ---------------------------------------------------------------------------
extern "C" void kernel_launch(void* const* d_in, const int* in_sizes, int n_in,
                              void* d_out, int out_size, void* d_ws, size_t ws_size,
                              hipStream_t stream) {
    (void)in_sizes; (void)n_in; (void)out_size; (void)ws_size;
    const float* u          = (const float*)d_in[0];
    const float* in_proj_w  = (const float*)d_in[1];
    const float* conv_w     = (const float*)d_in[2];
    const float* conv_b     = (const float*)d_in[3];
    const float* norm_w     = (const float*)d_in[4];
    const float* out_proj_w = (const float*)d_in[5];
    const float* A_log      = (const float*)d_in[6];
    const float* Dp         = (const float*)d_in[7];
    const float* dt_bias    = (const float*)d_in[8];

    char* w = (char*)d_ws;
    bf16*  Zb     = (bf16*)w;     w += (size_t)NTOK * D_INNER * 2;
    bf16*  XBC    = (bf16*)w;     w += (size_t)NTOK * D_CONV_IN * 2;
    bf16*  xy     = (bf16*)w;     w += (size_t)NTOK * D_INNER * 2;
    bf16*  Bb     = (bf16*)w;     w += (size_t)NTOK * D_STATE * 2;
    bf16*  Cb     = (bf16*)w;     w += (size_t)NTOK * D_STATE * 2;
    float* dtraw  = (float*)w;    w += (size_t)NTOK * NHEADS * 4;
    float* dtb    = (float*)w;    w += (size_t)NTOK * NHEADS * 4;
    float* cdecay = (float*)w;    w += (size_t)NCHB * 4;
    bf16*  wA     = (bf16*)w;     w += (size_t)ZXLD * D_MODEL * 2;
    bf16*  wO     = (bf16*)w;
    float* states = (float*)XBC;                                   // XBC dead after conv
    bf16*  Graw   = (bf16*)((char*)XBC + (size_t)NCHB * 4096 * 4); // 8 MB tail of XBC region
    bf16*  uB     = xy;                                            // xy free until conv writes it

    { int n = NTOK * D_MODEL;
      cvt_f32_bf16<<<(n / 4 + 255) / 256, 256, 0, stream>>>(u, (unsigned short*)uB, n); }
    { int n = ZXLD * D_MODEL;
      cvt_f32_bf16<<<(n / 4 + 255) / 256, 256, 0, stream>>>(in_proj_w, (unsigned short*)wA, n); }
    { int n = D_MODEL * D_INNER;
      cvt_f32_bf16<<<(n / 4 + 255) / 256, 256, 0, stream>>>(out_proj_w, (unsigned short*)wO, n); }

    dt_gemm<<<NTOK * NHEADS / 256, 256, 0, stream>>>(u, in_proj_w, dtraw);

    dim3 g1(ZXLD / 128, NTOK / 128);
    gemm_mfma<0><<<g1, 256, 0, stream>>>(uB, wA, D_MODEL, Zb, XBC, nullptr);

    conv_norm_kernel<<<NTOK, 256, 0, stream>>>(XBC, dtraw, conv_w, conv_b, norm_w, dt_bias,
                                               xy, Bb, Cb, dtb);

    score_kernel<<<NBC, 256, 0, stream>>>(Bb, Cb, Graw);
    chunk_state_kernel<<<NCHB, 256, 0, stream>>>(xy, Bb, dtb, A_log, states, cdecay);
    state_pass_kernel<<<BATCH * NHEADS, 256, 0, stream>>>(states, cdecay);
    chunk_output_mfma<<<NCHB, 256, 0, stream>>>(Zb, xy, Cb, Graw, dtb, A_log, Dp, states);

    dim3 g4(D_MODEL / 128, NTOK / 128);
    gemm_mfma<1><<<g4, 256, 0, stream>>>(xy, wO, D_INNER, nullptr, nullptr, (float*)d_out);
}

// Round 7
// 516.902 us; speedup vs baseline: 5.0124x; 1.1502x over previous
//
#include <hip/hip_runtime.h>
#include <hip/hip_bf16.h>
#include <cstddef>

#define D_MODEL   384
#define D_IN_PROJ 1676
#define D_INNER   768
#define D_CONV_IN 896
#define ZXLD      1664
#define NHEADS    12
#define HEADDIM   64
#define D_STATE   64
#define SEQLEN    4096
#define BATCH     8
#define NTOK      (BATCH * SEQLEN)
#define EPSV      1e-5f
#define Q         128
#define NCHUNK    (SEQLEN / Q)
#define NCHB      (BATCH * NHEADS * NCHUNK)
#define NBC       (BATCH * NCHUNK)

typedef __hip_bfloat16 bf16;
typedef __attribute__((ext_vector_type(8))) short bf16x8v;
typedef __attribute__((ext_vector_type(4))) float f32x4v;

__device__ __forceinline__ float b2f(bf16 v) { return __bfloat162float(v); }
__device__ __forceinline__ bf16  f2b(float v) { return __float2bfloat16(v); }
__device__ __forceinline__ float bl(unsigned u)  { return __uint_as_float(u << 16); }
__device__ __forceinline__ float bh(unsigned u)  { return __uint_as_float(u & 0xffff0000u); }
__device__ __forceinline__ float bu(unsigned short v) { return __uint_as_float(((unsigned)v) << 16); }
__device__ __forceinline__ unsigned pk2(float a, float b) {
    return ((unsigned)__bfloat16_as_ushort(f2b(b)) << 16) | (unsigned)__bfloat16_as_ushort(f2b(a));
}
__device__ __forceinline__ int swzf(int r) { return (r ^ (r >> 2)) & 3; }
// XOR slot-swizzle index into a [rows][128]-short tile (slot = 8 shorts = 16B)
__device__ __forceinline__ int tswz(int r, int col) {
    return r * 128 + ((((col >> 3) ^ (r & 7)) << 3) | (col & 7));
}

#define GL_LDS16(g, l) __builtin_amdgcn_global_load_lds( \
    (const __attribute__((address_space(1))) unsigned*)(g), \
    (__attribute__((address_space(3))) unsigned*)(l), 16, 0, 0)

// ---------------------------------------------------------------------------
__global__ __launch_bounds__(256)
void cvt_f32_bf16(const float* __restrict__ in, unsigned short* __restrict__ out, int n) {
    int i = (blockIdx.x * 256 + threadIdx.x) * 4;
    if (i + 3 < n) {
        float4 v = *(const float4*)(in + i);
        uint2 o; o.x = pk2(v.x, v.y); o.y = pk2(v.z, v.w);
        *(uint2*)(out + i) = o;
    }
}

// ---------------------------------------------------------------------------
__global__ __launch_bounds__(256)
void dt_gemm(const float* __restrict__ u, const float* __restrict__ W,
             float* __restrict__ dtraw) {
    int g = blockIdx.x * 256 + threadIdx.x;
    int row = g / NHEADS, head = g % NHEADS;
    const float4* ur = (const float4*)(u + (size_t)row * D_MODEL);
    const float4* wr = (const float4*)(W + (size_t)(ZXLD + head) * D_MODEL);
    float acc = 0.f;
#pragma unroll 8
    for (int k = 0; k < D_MODEL / 4; ++k) {
        float4 a = ur[k], b = wr[k];
        acc += a.x * b.x + a.y * b.y + a.z * b.z + a.w * b.w;
    }
    dtraw[g] = acc;
}

// ---------------------------------------------------------------------------
// MFMA GEMM-NT (unchanged)
// ---------------------------------------------------------------------------
template<int EPI>
__global__ __launch_bounds__(256)
void gemm_mfma(const bf16* __restrict__ A, const bf16* __restrict__ Bw, int K,
               bf16* __restrict__ Zo, bf16* __restrict__ XBCo, float* __restrict__ Co) {
    __shared__ short As[128 * 32];
    __shared__ short Bs[128 * 32];
    const int tid = threadIdx.x;
    const int lane = tid & 63;
    const int w = tid >> 6;
    const int wr = w >> 1, wc = w & 1;
    const int bm = blockIdx.y * 128;
    const int bn = blockIdx.x * 128;

    f32x4v acc[4][4];
#pragma unroll
    for (int mi = 0; mi < 4; ++mi)
#pragma unroll
        for (int ni = 0; ni < 4; ++ni)
            acc[mi][ni] = (f32x4v){0.f, 0.f, 0.f, 0.f};

    size_t aoff[2]; size_t boff[2];
#pragma unroll
    for (int q = 0; q < 2; ++q) {
        int o = q * 4096 + tid * 16;
        int row = o >> 6;
        int ps = (o >> 4) & 3;
        int sl = ps ^ swzf(row);
        aoff[q] = (size_t)(bm + row) * K + sl * 8;
        boff[q] = (size_t)(bn + row) * K + sl * 8;
    }
    short* adst0 = As + tid * 8;          short* adst1 = As + 2048 + tid * 8;
    short* bdst0 = Bs + tid * 8;          short* bdst1 = Bs + 2048 + tid * 8;

    int aidx[4], bidx[4];
#pragma unroll
    for (int i = 0; i < 4; ++i) {
        int ra = wr * 64 + i * 16 + (lane & 15);
        int rb = wc * 64 + i * 16 + (lane & 15);
        aidx[i] = ra * 32 + (((lane >> 4) ^ swzf(ra)) * 8);
        bidx[i] = rb * 32 + (((lane >> 4) ^ swzf(rb)) * 8);
    }

    for (int k0 = 0; k0 < K; k0 += 32) {
        __syncthreads();
        GL_LDS16(A + aoff[0] + k0, adst0);
        GL_LDS16(A + aoff[1] + k0, adst1);
        GL_LDS16(Bw + boff[0] + k0, bdst0);
        GL_LDS16(Bw + boff[1] + k0, bdst1);
        __syncthreads();

        bf16x8v af[4], bf[4];
#pragma unroll
        for (int i = 0; i < 4; ++i) {
            af[i] = *(const bf16x8v*)(As + aidx[i]);
            bf[i] = *(const bf16x8v*)(Bs + bidx[i]);
        }
#pragma unroll
        for (int mi = 0; mi < 4; ++mi)
#pragma unroll
            for (int ni = 0; ni < 4; ++ni)
                acc[mi][ni] = __builtin_amdgcn_mfma_f32_16x16x32_bf16(
                    af[mi], bf[ni], acc[mi][ni], 0, 0, 0);
    }

    const int l15 = lane & 15, l4 = lane >> 4;
#pragma unroll
    for (int mi = 0; mi < 4; ++mi) {
        int rbase = bm + wr * 64 + mi * 16 + l4 * 4;
#pragma unroll
        for (int ni = 0; ni < 4; ++ni) {
            int col = bn + wc * 64 + ni * 16 + l15;
            f32x4v v = acc[mi][ni];
            if (EPI == 0) {
                if (col < D_INNER) {
#pragma unroll
                    for (int j = 0; j < 4; ++j)
                        Zo[(size_t)(rbase + j) * D_INNER + col] = f2b(v[j]);
                } else {
#pragma unroll
                    for (int j = 0; j < 4; ++j)
                        XBCo[(size_t)(rbase + j) * D_CONV_IN + (col - D_INNER)] = f2b(v[j]);
                }
            } else {
#pragma unroll
                for (int j = 0; j < 4; ++j)
                    Co[(size_t)(rbase + j) * D_MODEL + col] = v[j];
            }
        }
    }
}

// ---------------------------------------------------------------------------
// K2 v2: wave-per-token conv + SiLU + RMSNorm + softplus(dt). No LDS.
// lane l<56 owns 16 channels [16l,16l+16); 4 waves = 4 tokens per block.
// ---------------------------------------------------------------------------
__global__ __launch_bounds__(256)
void conv_norm_v2(const bf16* __restrict__ XBC, const float* __restrict__ dtraw,
                  const float* __restrict__ conv_w, const float* __restrict__ conv_b,
                  const float* __restrict__ norm_w, const float* __restrict__ dt_bias,
                  bf16* __restrict__ xn, bf16* __restrict__ Bb,
                  bf16* __restrict__ Cb, float* __restrict__ dtb) {
    const int wv = threadIdx.x >> 6;
    const int lane = threadIdx.x & 63;
    const int token = blockIdx.x * 4 + wv;
    const int l = token & (SEQLEN - 1);

    float acc[16];
    float sumsq = 0.f;

    if (lane < 56) {
        const int ch0 = lane * 16;
        // bias
#pragma unroll
        for (int q = 0; q < 4; ++q) {
            float4 bv = *(const float4*)(conv_b + ch0 + q * 4);
            acc[q * 4 + 0] = bv.x; acc[q * 4 + 1] = bv.y;
            acc[q * 4 + 2] = bv.z; acc[q * 4 + 3] = bv.w;
        }
        // conv weights: [ch][4] contiguous
        float4 wreg[16];
#pragma unroll
        for (int i = 0; i < 16; ++i)
            wreg[i] = *(const float4*)(conv_w + (ch0 + i) * 4);
        // 4 taps
#pragma unroll
        for (int j = 0; j < 4; ++j) {
            int lt = l - 3 + j;
            if (lt >= 0) {
                const unsigned short* row =
                    (const unsigned short*)(XBC + (size_t)(token - 3 + j) * D_CONV_IN + ch0);
                uint4 r0 = *(const uint4*)(row);
                uint4 r1 = *(const uint4*)(row + 8);
                float rv[16] = {bl(r0.x), bh(r0.x), bl(r0.y), bh(r0.y),
                                bl(r0.z), bh(r0.z), bl(r0.w), bh(r0.w),
                                bl(r1.x), bh(r1.x), bl(r1.y), bh(r1.y),
                                bl(r1.z), bh(r1.z), bl(r1.w), bh(r1.w)};
#pragma unroll
                for (int i = 0; i < 16; ++i) {
                    float wj = (j == 0) ? wreg[i].x : (j == 1) ? wreg[i].y
                             : (j == 2) ? wreg[i].z : wreg[i].w;
                    acc[i] += rv[i] * wj;
                }
            }
        }
        // silu + sumsq (x part only: lanes 0..47)
#pragma unroll
        for (int i = 0; i < 16; ++i) {
            float s = acc[i] / (1.f + __expf(-acc[i]));
            acc[i] = s;
            if (lane < 48) sumsq += s * s;
        }
    }
    // wave reduce
#pragma unroll
    for (int off = 32; off > 0; off >>= 1) sumsq += __shfl_xor(sumsq, off, 64);
    const float scale = rsqrtf(sumsq / (float)D_INNER + EPSV);

    if (lane < 48) {
        const int ch0 = lane * 16;
        float nw[16];
#pragma unroll
        for (int q = 0; q < 4; ++q) {
            float4 nv = *(const float4*)(norm_w + ch0 + q * 4);
            nw[q * 4 + 0] = nv.x; nw[q * 4 + 1] = nv.y;
            nw[q * 4 + 2] = nv.z; nw[q * 4 + 3] = nv.w;
        }
        uint4 o0, o1;
        o0.x = pk2(acc[0] * scale * nw[0],  acc[1] * scale * nw[1]);
        o0.y = pk2(acc[2] * scale * nw[2],  acc[3] * scale * nw[3]);
        o0.z = pk2(acc[4] * scale * nw[4],  acc[5] * scale * nw[5]);
        o0.w = pk2(acc[6] * scale * nw[6],  acc[7] * scale * nw[7]);
        o1.x = pk2(acc[8] * scale * nw[8],  acc[9] * scale * nw[9]);
        o1.y = pk2(acc[10] * scale * nw[10], acc[11] * scale * nw[11]);
        o1.z = pk2(acc[12] * scale * nw[12], acc[13] * scale * nw[13]);
        o1.w = pk2(acc[14] * scale * nw[14], acc[15] * scale * nw[15]);
        uint4* dst = (uint4*)(xn + (size_t)token * D_INNER + ch0);
        dst[0] = o0; dst[1] = o1;
    } else if (lane < 56) {
        const int idx = lane * 16 - 768;     // 0,16,32,48 for B; 64.. for C
        uint4 o0, o1;
        o0.x = pk2(acc[0], acc[1]);   o0.y = pk2(acc[2], acc[3]);
        o0.z = pk2(acc[4], acc[5]);   o0.w = pk2(acc[6], acc[7]);
        o1.x = pk2(acc[8], acc[9]);   o1.y = pk2(acc[10], acc[11]);
        o1.z = pk2(acc[12], acc[13]); o1.w = pk2(acc[14], acc[15]);
        bf16* base = (idx < 64) ? (Bb + (size_t)token * D_STATE + idx)
                                : (Cb + (size_t)token * D_STATE + (idx - 64));
        uint4* dst = (uint4*)base;
        dst[0] = o0; dst[1] = o1;
    }
    if (lane < NHEADS) {
        float v = dtraw[(size_t)token * NHEADS + lane] + dt_bias[lane];
        float sp = (v > 20.f) ? v : log1pf(expf(v));
        dtb[(size_t)token * NHEADS + lane] = sp;
    }
}

// ---------------------------------------------------------------------------
// Score kernel (unchanged)
// ---------------------------------------------------------------------------
__global__ __launch_bounds__(256)
void score_kernel(const bf16* __restrict__ Bb, const bf16* __restrict__ Cb,
                  bf16* __restrict__ Graw) {
    const int bc = blockIdx.x;
    const size_t tok0 = (size_t)bc * Q;
    const int tid = threadIdx.x;
    const int lane = tid & 63, w = tid >> 6;
    const int wr = w >> 1, wc = w & 1;
    __shared__ short sC[Q * 64];
    __shared__ short sB[Q * 64];

#pragma unroll
    for (int it = 0; it < 4; ++it) {
        int j = it * 256 + tid;
        int r = j >> 3, sp = j & 7;
        int sl = sp ^ (r & 7);
        GL_LDS16(Cb + tok0 * D_STATE + r * 64 + sl * 8, sC + j * 8);
        GL_LDS16(Bb + tok0 * D_STATE + r * 64 + sl * 8, sB + j * 8);
    }
    __syncthreads();

    const int l15 = lane & 15, qq = lane >> 4;
    f32x4v acc[4][4];
#pragma unroll
    for (int mi = 0; mi < 4; ++mi)
#pragma unroll
        for (int ni = 0; ni < 4; ++ni)
            acc[mi][ni] = (f32x4v){0.f, 0.f, 0.f, 0.f};

#pragma unroll
    for (int kb = 0; kb < 2; ++kb) {
        bf16x8v af[4], bf[4];
#pragma unroll
        for (int i = 0; i < 4; ++i) {
            int ra = wr * 64 + i * 16 + l15;
            int rb = wc * 64 + i * 16 + l15;
            af[i] = *(const bf16x8v*)(sC + ra * 64 + ((kb * 4 + qq) ^ (ra & 7)) * 8);
            bf[i] = *(const bf16x8v*)(sB + rb * 64 + ((kb * 4 + qq) ^ (rb & 7)) * 8);
        }
#pragma unroll
        for (int mi = 0; mi < 4; ++mi)
#pragma unroll
            for (int ni = 0; ni < 4; ++ni)
                acc[mi][ni] = __builtin_amdgcn_mfma_f32_16x16x32_bf16(
                    af[mi], bf[ni], acc[mi][ni], 0, 0, 0);
    }

    bf16* gout = Graw + (size_t)bc * (Q * Q);
#pragma unroll
    for (int mi = 0; mi < 4; ++mi) {
        int t0 = wr * 64 + mi * 16 + qq * 4;
#pragma unroll
        for (int ni = 0; ni < 4; ++ni) {
            int s = wc * 64 + ni * 16 + l15;
            f32x4v v = acc[mi][ni];
#pragma unroll
            for (int j = 0; j < 4; ++j)
                gout[(size_t)(t0 + j) * Q + s] = f2b(v[j]);
        }
    }
}

// ---------------------------------------------------------------------------
// K3a v2 (MFMA): S[n][p] = sum_t (B[t][n]*dt_t*w_t) * x[t][p], 64x64xK128.
// Stage B^T (scaled at pack time) and X^T with XOR slot swizzle.
// wave w owns n in [16w,16w+16); 16 MFMA per wave.
// ---------------------------------------------------------------------------
__global__ __launch_bounds__(256)
void chunk_state_mfma(const bf16* __restrict__ xy, const bf16* __restrict__ Bb,
                      const float* __restrict__ dtb, const float* __restrict__ A_log,
                      float* __restrict__ states, float* __restrict__ cdecay) {
    const int sid = blockIdx.x;
    const int c = sid % NCHUNK;
    const int h = (sid / NCHUNK) % NHEADS;
    const int b = sid / (NCHUNK * NHEADS);
    const int tid = threadIdx.x;
    const int lane = tid & 63, w = tid >> 6;
    const size_t tok0 = (size_t)b * SEQLEN + (size_t)c * Q;
    const float Acoef = -expf(A_log[h]);

    __shared__ __align__(16) unsigned short sBT[64 * 128];  // [n][t], slot-swizzled
    __shared__ __align__(16) unsigned short sXT[64 * 128];  // [p][t], slot-swizzled
    __shared__ float slcum[Q];
    __shared__ float sdt[Q];
    __shared__ float wtot[2];

    // cumulative log-decay scan
    float lx = 0.f;
    if (tid < Q) {
        float dtv = dtb[(tok0 + tid) * NHEADS + h];
        sdt[tid] = dtv;
        lx = dtv * Acoef;
        int ln = tid & 63;
        for (int off = 1; off < 64; off <<= 1) {
            float v = __shfl_up(lx, off, 64);
            if (ln >= off) lx += v;
        }
        if (ln == 63) wtot[tid >> 6] = lx;
    }
    __syncthreads();
    if (tid < Q) {
        if (tid >= 64) lx += wtot[0];
        slcum[tid] = lx;
    }
    __syncthreads();
    const float ltot = slcum[Q - 1];

    // stage transposed operands
    {
        int t = tid >> 1, half = tid & 1;
        float s_t = sdt[t] * __expf(ltot - slcum[t]);
        const unsigned short* br = (const unsigned short*)(Bb + (tok0 + t) * D_STATE) + half * 32;
        const unsigned short* xr = (const unsigned short*)(xy + (tok0 + t) * D_INNER + h * HEADDIM) + half * 32;
#pragma unroll
        for (int i = 0; i < 32; ++i) {
            int r = half * 32 + i;
            sBT[tswz(r, t)] = __bfloat16_as_ushort(f2b(bu(br[i]) * s_t));
            sXT[tswz(r, t)] = xr[i];
        }
    }
    __syncthreads();

    const int l15 = lane & 15, qq = lane >> 4;
    f32x4v acc[4];
#pragma unroll
    for (int ni = 0; ni < 4; ++ni) acc[ni] = (f32x4v){0.f, 0.f, 0.f, 0.f};

#pragma unroll
    for (int kb = 0; kb < 4; ++kb) {
        const int col = kb * 32 + qq * 8;
        bf16x8v af = *(const bf16x8v*)(&sBT[tswz(w * 16 + l15, col)]);
#pragma unroll
        for (int ni = 0; ni < 4; ++ni) {
            bf16x8v bx = *(const bf16x8v*)(&sXT[tswz(ni * 16 + l15, col)]);
            acc[ni] = __builtin_amdgcn_mfma_f32_16x16x32_bf16(af, bx, acc[ni], 0, 0, 0);
        }
    }

    float* out = states + (size_t)sid * 4096;
#pragma unroll
    for (int ni = 0; ni < 4; ++ni) {
#pragma unroll
        for (int j = 0; j < 4; ++j) {
            int n = w * 16 + qq * 4 + j;
            int p = ni * 16 + l15;
            out[n * 64 + p] = acc[ni][j];
        }
    }
    if (tid == 0) cdecay[sid] = expf(ltot);
}

// ---------------------------------------------------------------------------
// K3b: sequential inter-chunk recurrence (unchanged)
// ---------------------------------------------------------------------------
__global__ __launch_bounds__(256)
void state_pass_kernel(float* __restrict__ states, const float* __restrict__ cdecay) {
    const int bh = blockIdx.x;
    const int tid = threadIdx.x;
    float run[16];
#pragma unroll
    for (int i = 0; i < 16; ++i) run[i] = 0.f;
    float* base = states + (size_t)bh * NCHUNK * 4096 + tid * 16;
    const float* cd = cdecay + bh * NCHUNK;
    for (int c = 0; c < NCHUNK; ++c) {
        float dec = cd[c];
        float* ptr = base + (size_t)c * 4096;
        float4 s0 = *(float4*)(ptr + 0);
        float4 s1 = *(float4*)(ptr + 4);
        float4 s2 = *(float4*)(ptr + 8);
        float4 s3 = *(float4*)(ptr + 12);
        float nr[16];
        nr[0] = dec * run[0] + s0.x;  nr[1] = dec * run[1] + s0.y;
        nr[2] = dec * run[2] + s0.z;  nr[3] = dec * run[3] + s0.w;
        nr[4] = dec * run[4] + s1.x;  nr[5] = dec * run[5] + s1.y;
        nr[6] = dec * run[6] + s1.z;  nr[7] = dec * run[7] + s1.w;
        nr[8] = dec * run[8] + s2.x;  nr[9] = dec * run[9] + s2.y;
        nr[10] = dec * run[10] + s2.z; nr[11] = dec * run[11] + s2.w;
        nr[12] = dec * run[12] + s3.x; nr[13] = dec * run[13] + s3.y;
        nr[14] = dec * run[14] + s3.z; nr[15] = dec * run[15] + s3.w;
        *(float4*)(ptr + 0)  = make_float4(run[0], run[1], run[2], run[3]);
        *(float4*)(ptr + 4)  = make_float4(run[4], run[5], run[6], run[7]);
        *(float4*)(ptr + 8)  = make_float4(run[8], run[9], run[10], run[11]);
        *(float4*)(ptr + 12) = make_float4(run[12], run[13], run[14], run[15]);
#pragma unroll
        for (int i = 0; i < 16; ++i) run[i] = nr[i];
    }
}

// ---------------------------------------------------------------------------
// K3c (MFMA): per-token output (unchanged)
// ---------------------------------------------------------------------------
__global__ __launch_bounds__(256)
void chunk_output_mfma(const bf16* __restrict__ Zb, bf16* __restrict__ xy,
                       const bf16* __restrict__ Cb, const bf16* __restrict__ Graw,
                       const float* __restrict__ dtb, const float* __restrict__ A_log,
                       const float* __restrict__ Dpa, const float* __restrict__ states) {
    const int sid = blockIdx.x;
    const int c = sid % NCHUNK;
    const int h = (sid / NCHUNK) % NHEADS;
    const int b = sid / (NCHUNK * NHEADS);
    const int tid = threadIdx.x;
    const int lane = tid & 63, w = tid >> 6;
    const int wr = w >> 1, wc = w & 1;
    const size_t tok0 = (size_t)b * SEQLEN + (size_t)c * Q;
    const int bc = b * NCHUNK + c;
    const float Acoef = -expf(A_log[h]);

    __shared__ __align__(16) float slcum[Q];
    __shared__ __align__(16) float sdt[Q];
    __shared__ float wtot[2];
    __shared__ __align__(16) unsigned short sXt[64][136];
    __shared__ __align__(16) unsigned short sNh[64][72];
    __shared__ __align__(16) unsigned short sNl[64][72];

    float lx = 0.f;
    if (tid < Q) {
        float dtv = dtb[(tok0 + tid) * NHEADS + h];
        sdt[tid] = dtv;
        lx = dtv * Acoef;
        int ln = tid & 63;
        for (int off = 1; off < 64; off <<= 1) {
            float v = __shfl_up(lx, off, 64);
            if (ln >= off) lx += v;
        }
        if (ln == 63) wtot[tid >> 6] = lx;
    }
    __syncthreads();
    if (tid < Q) {
        if (tid >= 64) lx += wtot[0];
        slcum[tid] = lx;
    }

    {
        int t = tid >> 1, ph = (tid & 1) * 32;
        const unsigned short* xr = (const unsigned short*)(xy + (tok0 + t) * D_INNER + h * HEADDIM + ph);
#pragma unroll
        for (int i = 0; i < 32; ++i) sXt[ph + i][t] = xr[i];
    }
    {
        const float* init = states + (size_t)sid * 4096;
        for (int i = tid; i < 1024; i += 256) {
            float4 v = ((const float4*)init)[i];
            int n = i >> 4;
            int p = (i & 15) * 4;
#pragma unroll
            for (int j2 = 0; j2 < 4; ++j2) {
                float f = (&v.x)[j2];
                bf16 hi = f2b(f);
                float lo = f - b2f(hi);
                sNh[p + j2][n] = __bfloat16_as_ushort(hi);
                sNl[p + j2][n] = __bfloat16_as_ushort(f2b(lo));
            }
        }
    }
    __syncthreads();

    const int l15 = lane & 15, qq = lane >> 4;
    const int twr = wr * 64;

    float lct_mi[4], elct[4];
    int tcur[4];
#pragma unroll
    for (int mi = 0; mi < 4; ++mi) {
        tcur[mi] = twr + mi * 16 + l15;
        lct_mi[mi] = slcum[tcur[mi]];
        elct[mi] = __expf(lct_mi[mi]);
    }

    f32x4v acc[4][2];
#pragma unroll
    for (int mi = 0; mi < 4; ++mi)
#pragma unroll
        for (int ni = 0; ni < 2; ++ni)
            acc[mi][ni] = (f32x4v){0.f, 0.f, 0.f, 0.f};

    const bf16* grow = Graw + (size_t)bc * (Q * Q);

#pragma unroll
    for (int kb = 0; kb < 4; ++kb) {
        const int s0 = kb * 32 + qq * 8;
        float4 lcA = *(const float4*)(slcum + s0);
        float4 lcB = *(const float4*)(slcum + s0 + 4);
        float4 dtA = *(const float4*)(sdt + s0);
        float4 dtB = *(const float4*)(sdt + s0 + 4);
        bf16x8v af[4];
#pragma unroll
        for (int mi = 0; mi < 4; ++mi) {
            int t = tcur[mi];
            float lct = lct_mi[mi];
            uint4 gv = *(const uint4*)(grow + (size_t)t * Q + s0);
            float f0 = (s0 + 0 <= t) ? bl(gv.x) * dtA.x * __expf(lct - lcA.x) : 0.f;
            float f1 = (s0 + 1 <= t) ? bh(gv.x) * dtA.y * __expf(lct - lcA.y) : 0.f;
            float f2 = (s0 + 2 <= t) ? bl(gv.y) * dtA.z * __expf(lct - lcA.z) : 0.f;
            float f3 = (s0 + 3 <= t) ? bh(gv.y) * dtA.w * __expf(lct - lcA.w) : 0.f;
            float f4 = (s0 + 4 <= t) ? bl(gv.z) * dtB.x * __expf(lct - lcB.x) : 0.f;
            float f5 = (s0 + 5 <= t) ? bh(gv.z) * dtB.y * __expf(lct - lcB.y) : 0.f;
            float f6 = (s0 + 6 <= t) ? bl(gv.w) * dtB.z * __expf(lct - lcB.z) : 0.f;
            float f7 = (s0 + 7 <= t) ? bh(gv.w) * dtB.w * __expf(lct - lcB.w) : 0.f;
            union { bf16x8v v; unsigned u[4]; } r;
            r.u[0] = pk2(f0, f1); r.u[1] = pk2(f2, f3);
            r.u[2] = pk2(f4, f5); r.u[3] = pk2(f6, f7);
            af[mi] = r.v;
        }
        bf16x8v bfr[2];
#pragma unroll
        for (int ni = 0; ni < 2; ++ni) {
            int p = wc * 32 + ni * 16 + l15;
            bfr[ni] = *(const bf16x8v*)(&sXt[p][s0]);
        }
#pragma unroll
        for (int mi = 0; mi < 4; ++mi)
#pragma unroll
            for (int ni = 0; ni < 2; ++ni)
                acc[mi][ni] = __builtin_amdgcn_mfma_f32_16x16x32_bf16(
                    af[mi], bfr[ni], acc[mi][ni], 0, 0, 0);
    }

#pragma unroll
    for (int half = 0; half < 2; ++half) {
        const int n0 = half * 32 + qq * 8;
        bf16x8v af[4];
#pragma unroll
        for (int mi = 0; mi < 4; ++mi) {
            uint4 cv = *(const uint4*)(Cb + (tok0 + tcur[mi]) * D_STATE + n0);
            float el = elct[mi];
            union { bf16x8v v; unsigned u[4]; } r;
            r.u[0] = pk2(bl(cv.x) * el, bh(cv.x) * el);
            r.u[1] = pk2(bl(cv.y) * el, bh(cv.y) * el);
            r.u[2] = pk2(bl(cv.z) * el, bh(cv.z) * el);
            r.u[3] = pk2(bl(cv.w) * el, bh(cv.w) * el);
            af[mi] = r.v;
        }
        bf16x8v bh_[2], bl_[2];
#pragma unroll
        for (int ni = 0; ni < 2; ++ni) {
            int p = wc * 32 + ni * 16 + l15;
            bh_[ni] = *(const bf16x8v*)(&sNh[p][n0]);
            bl_[ni] = *(const bf16x8v*)(&sNl[p][n0]);
        }
#pragma unroll
        for (int mi = 0; mi < 4; ++mi)
#pragma unroll
            for (int ni = 0; ni < 2; ++ni) {
                acc[mi][ni] = __builtin_amdgcn_mfma_f32_16x16x32_bf16(
                    af[mi], bh_[ni], acc[mi][ni], 0, 0, 0);
                acc[mi][ni] = __builtin_amdgcn_mfma_f32_16x16x32_bf16(
                    af[mi], bl_[ni], acc[mi][ni], 0, 0, 0);
            }
    }

    const float Dh = Dpa[h];
#pragma unroll
    for (int mi = 0; mi < 4; ++mi) {
        int t0 = twr + mi * 16 + qq * 4;
#pragma unroll
        for (int ni = 0; ni < 2; ++ni) {
            int p = wc * 32 + ni * 16 + l15;
            f32x4v v = acc[mi][ni];
#pragma unroll
            for (int jj = 0; jj < 4; ++jj) {
                size_t off = (tok0 + t0 + jj) * D_INNER + h * HEADDIM + p;
                float xv = b2f(xy[off]);
                float zv = b2f(Zb[off]);
                float yv = v[jj] + Dh * xv;
                yv *= zv / (1.f + __expf(-zv));
                xy[off] = f2b(yv);
            }
        }
    }
}

// ---------------------------------------------------------------------------
extern "C" void kernel_launch(void* const* d_in, const int* in_sizes, int n_in,
                              void* d_out, int out_size, void* d_ws, size_t ws_size,
                              hipStream_t stream) {
    (void)in_sizes; (void)n_in; (void)out_size; (void)ws_size;
    const float* u          = (const float*)d_in[0];
    const float* in_proj_w  = (const float*)d_in[1];
    const float* conv_w     = (const float*)d_in[2];
    const float* conv_b     = (const float*)d_in[3];
    const float* norm_w     = (const float*)d_in[4];
    const float* out_proj_w = (const float*)d_in[5];
    const float* A_log      = (const float*)d_in[6];
    const float* Dp         = (const float*)d_in[7];
    const float* dt_bias    = (const float*)d_in[8];

    char* w = (char*)d_ws;
    bf16*  Zb     = (bf16*)w;     w += (size_t)NTOK * D_INNER * 2;
    bf16*  XBC    = (bf16*)w;     w += (size_t)NTOK * D_CONV_IN * 2;
    bf16*  xy     = (bf16*)w;     w += (size_t)NTOK * D_INNER * 2;
    bf16*  Bb     = (bf16*)w;     w += (size_t)NTOK * D_STATE * 2;
    bf16*  Cb     = (bf16*)w;     w += (size_t)NTOK * D_STATE * 2;
    float* dtraw  = (float*)w;    w += (size_t)NTOK * NHEADS * 4;
    float* dtb    = (float*)w;    w += (size_t)NTOK * NHEADS * 4;
    float* cdecay = (float*)w;    w += (size_t)NCHB * 4;
    bf16*  wA     = (bf16*)w;     w += (size_t)ZXLD * D_MODEL * 2;
    bf16*  wO     = (bf16*)w;
    float* states = (float*)XBC;
    bf16*  Graw   = (bf16*)((char*)XBC + (size_t)NCHB * 4096 * 4);
    bf16*  uB     = xy;

    { int n = NTOK * D_MODEL;
      cvt_f32_bf16<<<(n / 4 + 255) / 256, 256, 0, stream>>>(u, (unsigned short*)uB, n); }
    { int n = ZXLD * D_MODEL;
      cvt_f32_bf16<<<(n / 4 + 255) / 256, 256, 0, stream>>>(in_proj_w, (unsigned short*)wA, n); }
    { int n = D_MODEL * D_INNER;
      cvt_f32_bf16<<<(n / 4 + 255) / 256, 256, 0, stream>>>(out_proj_w, (unsigned short*)wO, n); }

    dt_gemm<<<NTOK * NHEADS / 256, 256, 0, stream>>>(u, in_proj_w, dtraw);

    dim3 g1(ZXLD / 128, NTOK / 128);
    gemm_mfma<0><<<g1, 256, 0, stream>>>(uB, wA, D_MODEL, Zb, XBC, nullptr);

    conv_norm_v2<<<NTOK / 4, 256, 0, stream>>>(XBC, dtraw, conv_w, conv_b, norm_w, dt_bias,
                                               xy, Bb, Cb, dtb);

    score_kernel<<<NBC, 256, 0, stream>>>(Bb, Cb, Graw);
    chunk_state_mfma<<<NCHB, 256, 0, stream>>>(xy, Bb, dtb, A_log, states, cdecay);
    state_pass_kernel<<<BATCH * NHEADS, 256, 0, stream>>>(states, cdecay);
    chunk_output_mfma<<<NCHB, 256, 0, stream>>>(Zb, xy, Cb, Graw, dtb, A_log, Dp, states);

    dim3 g4(D_MODEL / 128, NTOK / 128);
    gemm_mfma<1><<<g4, 256, 0, stream>>>(xy, wO, D_INNER, nullptr, nullptr, (float*)d_out);
}

// Round 8
// 415.287 us; speedup vs baseline: 6.2388x; 1.2447x over previous
//
#include <hip/hip_runtime.h>
#include <hip/hip_bf16.h>
#include <cstddef>

#define D_MODEL   384
#define D_IN_PROJ 1676
#define D_INNER   768
#define D_CONV_IN 896
#define ZXLD      1664
#define NHEADS    12
#define HEADDIM   64
#define D_STATE   64
#define SEQLEN    4096
#define BATCH     8
#define NTOK      (BATCH * SEQLEN)
#define EPSV      1e-5f
#define Q         128
#define NCHUNK    (SEQLEN / Q)
#define NCHB      (BATCH * NHEADS * NCHUNK)
#define NBC       (BATCH * NCHUNK)

typedef __hip_bfloat16 bf16;
typedef __attribute__((ext_vector_type(8))) short bf16x8v;
typedef __attribute__((ext_vector_type(4))) float f32x4v;

__device__ __forceinline__ float b2f(bf16 v) { return __bfloat162float(v); }
__device__ __forceinline__ bf16  f2b(float v) { return __float2bfloat16(v); }
__device__ __forceinline__ float bl(unsigned u)  { return __uint_as_float(u << 16); }
__device__ __forceinline__ float bh(unsigned u)  { return __uint_as_float(u & 0xffff0000u); }
__device__ __forceinline__ float bu(unsigned short v) { return __uint_as_float(((unsigned)v) << 16); }
__device__ __forceinline__ unsigned pk2(float a, float b) {
    return ((unsigned)__bfloat16_as_ushort(f2b(b)) << 16) | (unsigned)__bfloat16_as_ushort(f2b(a));
}
__device__ __forceinline__ int swzf(int r) { return (r ^ (r >> 2)) & 3; }
__device__ __forceinline__ int tswz(int r, int col) {
    return r * 128 + ((((col >> 3) ^ (r & 7)) << 3) | (col & 7));
}

#define GL_LDS16(g, l) __builtin_amdgcn_global_load_lds( \
    (const __attribute__((address_space(1))) unsigned*)(g), \
    (__attribute__((address_space(3))) unsigned*)(l), 16, 0, 0)

// ---------------------------------------------------------------------------
__global__ __launch_bounds__(256)
void cvt_f32_bf16(const float* __restrict__ in, unsigned short* __restrict__ out, int n) {
    int i = (blockIdx.x * 256 + threadIdx.x) * 4;
    if (i + 3 < n) {
        float4 v = *(const float4*)(in + i);
        uint2 o; o.x = pk2(v.x, v.y); o.y = pk2(v.z, v.w);
        *(uint2*)(out + i) = o;
    }
}

// ---------------------------------------------------------------------------
__global__ __launch_bounds__(256)
void dt_gemm(const float* __restrict__ u, const float* __restrict__ W,
             float* __restrict__ dtraw) {
    int g = blockIdx.x * 256 + threadIdx.x;
    int row = g / NHEADS, head = g % NHEADS;
    const float4* ur = (const float4*)(u + (size_t)row * D_MODEL);
    const float4* wr = (const float4*)(W + (size_t)(ZXLD + head) * D_MODEL);
    float acc = 0.f;
#pragma unroll 8
    for (int k = 0; k < D_MODEL / 4; ++k) {
        float4 a = ur[k], b = wr[k];
        acc += a.x * b.x + a.y * b.y + a.z * b.z + a.w * b.w;
    }
    dtraw[g] = acc;
}

// ---------------------------------------------------------------------------
// MFMA GEMM-NT (unchanged)
// ---------------------------------------------------------------------------
template<int EPI>
__global__ __launch_bounds__(256)
void gemm_mfma(const bf16* __restrict__ A, const bf16* __restrict__ Bw, int K,
               bf16* __restrict__ Zo, bf16* __restrict__ XBCo, float* __restrict__ Co) {
    __shared__ short As[128 * 32];
    __shared__ short Bs[128 * 32];
    const int tid = threadIdx.x;
    const int lane = tid & 63;
    const int w = tid >> 6;
    const int wr = w >> 1, wc = w & 1;
    const int bm = blockIdx.y * 128;
    const int bn = blockIdx.x * 128;

    f32x4v acc[4][4];
#pragma unroll
    for (int mi = 0; mi < 4; ++mi)
#pragma unroll
        for (int ni = 0; ni < 4; ++ni)
            acc[mi][ni] = (f32x4v){0.f, 0.f, 0.f, 0.f};

    size_t aoff[2]; size_t boff[2];
#pragma unroll
    for (int q = 0; q < 2; ++q) {
        int o = q * 4096 + tid * 16;
        int row = o >> 6;
        int ps = (o >> 4) & 3;
        int sl = ps ^ swzf(row);
        aoff[q] = (size_t)(bm + row) * K + sl * 8;
        boff[q] = (size_t)(bn + row) * K + sl * 8;
    }
    short* adst0 = As + tid * 8;          short* adst1 = As + 2048 + tid * 8;
    short* bdst0 = Bs + tid * 8;          short* bdst1 = Bs + 2048 + tid * 8;

    int aidx[4], bidx[4];
#pragma unroll
    for (int i = 0; i < 4; ++i) {
        int ra = wr * 64 + i * 16 + (lane & 15);
        int rb = wc * 64 + i * 16 + (lane & 15);
        aidx[i] = ra * 32 + (((lane >> 4) ^ swzf(ra)) * 8);
        bidx[i] = rb * 32 + (((lane >> 4) ^ swzf(rb)) * 8);
    }

    for (int k0 = 0; k0 < K; k0 += 32) {
        __syncthreads();
        GL_LDS16(A + aoff[0] + k0, adst0);
        GL_LDS16(A + aoff[1] + k0, adst1);
        GL_LDS16(Bw + boff[0] + k0, bdst0);
        GL_LDS16(Bw + boff[1] + k0, bdst1);
        __syncthreads();

        bf16x8v af[4], bf[4];
#pragma unroll
        for (int i = 0; i < 4; ++i) {
            af[i] = *(const bf16x8v*)(As + aidx[i]);
            bf[i] = *(const bf16x8v*)(Bs + bidx[i]);
        }
#pragma unroll
        for (int mi = 0; mi < 4; ++mi)
#pragma unroll
            for (int ni = 0; ni < 4; ++ni)
                acc[mi][ni] = __builtin_amdgcn_mfma_f32_16x16x32_bf16(
                    af[mi], bf[ni], acc[mi][ni], 0, 0, 0);
    }

    const int l15 = lane & 15, l4 = lane >> 4;
#pragma unroll
    for (int mi = 0; mi < 4; ++mi) {
        int rbase = bm + wr * 64 + mi * 16 + l4 * 4;
#pragma unroll
        for (int ni = 0; ni < 4; ++ni) {
            int col = bn + wc * 64 + ni * 16 + l15;
            f32x4v v = acc[mi][ni];
            if (EPI == 0) {
                if (col < D_INNER) {
#pragma unroll
                    for (int j = 0; j < 4; ++j)
                        Zo[(size_t)(rbase + j) * D_INNER + col] = f2b(v[j]);
                } else {
#pragma unroll
                    for (int j = 0; j < 4; ++j)
                        XBCo[(size_t)(rbase + j) * D_CONV_IN + (col - D_INNER)] = f2b(v[j]);
                }
            } else {
#pragma unroll
                for (int j = 0; j < 4; ++j)
                    Co[(size_t)(rbase + j) * D_MODEL + col] = v[j];
            }
        }
    }
}

// ---------------------------------------------------------------------------
// K2 v3: 8 tokens per block, thread owns 4 channels. Weights loaded once per
// 8 tokens; 11 input rows loaded once and reused across the <=4 tokens each
// feeds (sliding window, compile-time indices). RMSNorm: 2-stage LDS reduce.
// ---------------------------------------------------------------------------
__global__ __launch_bounds__(256)
void conv_norm_v3(const bf16* __restrict__ XBC, const float* __restrict__ dtraw,
                  const float* __restrict__ conv_w, const float* __restrict__ conv_b,
                  const float* __restrict__ norm_w, const float* __restrict__ dt_bias,
                  bf16* __restrict__ xn, bf16* __restrict__ Bb,
                  bf16* __restrict__ Cb, float* __restrict__ dtb) {
    const int tid = threadIdx.x;
    const int t0 = blockIdx.x * 8;
    const int l0 = t0 & (SEQLEN - 1);

    __shared__ float sp[8][200];
    __shared__ float sq[8][8];
    __shared__ float sscale[8];

    const int c = tid;
    const bool active = (c < 224);
    const int ch0 = c * 4;

    float acc[8][4];
    float w0[4], w1[4], w2[4], w3[4];

    if (active) {
        float4 wa = *(const float4*)(conv_w + (ch0 + 0) * 4);
        float4 wb = *(const float4*)(conv_w + (ch0 + 1) * 4);
        float4 wcc = *(const float4*)(conv_w + (ch0 + 2) * 4);
        float4 wd = *(const float4*)(conv_w + (ch0 + 3) * 4);
        w0[0] = wa.x; w1[0] = wa.y; w2[0] = wa.z; w3[0] = wa.w;
        w0[1] = wb.x; w1[1] = wb.y; w2[1] = wb.z; w3[1] = wb.w;
        w0[2] = wcc.x; w1[2] = wcc.y; w2[2] = wcc.z; w3[2] = wcc.w;
        w0[3] = wd.x; w1[3] = wd.y; w2[3] = wd.z; w3[3] = wd.w;
        float4 bv = *(const float4*)(conv_b + ch0);
#pragma unroll
        for (int t = 0; t < 8; ++t) {
            acc[t][0] = bv.x; acc[t][1] = bv.y; acc[t][2] = bv.z; acc[t][3] = bv.w;
        }
        // 11 rows: global token t0-3+ri, feeds output tokens t in [ri-3, ri]
#pragma unroll
        for (int ri = 0; ri < 11; ++ri) {
            int lr = l0 - 3 + ri;
            if (lr >= 0) {
                uint2 rv = *(const uint2*)((const unsigned short*)XBC
                              + (size_t)(t0 - 3 + ri) * D_CONV_IN + ch0);
                float r0 = bl(rv.x), r1 = bh(rv.x), r2 = bl(rv.y), r3 = bh(rv.y);
#pragma unroll
                for (int t = 0; t < 8; ++t) {
                    if (t >= ri - 3 && t <= ri) {
                        const int j = ri - t;   // compile-time after unroll
                        const float* wj = (j == 0) ? w0 : (j == 1) ? w1 : (j == 2) ? w2 : w3;
                        acc[t][0] += r0 * wj[0];
                        acc[t][1] += r1 * wj[1];
                        acc[t][2] += r2 * wj[2];
                        acc[t][3] += r3 * wj[3];
                    }
                }
            }
        }
        // silu + per-token partial sumsq
#pragma unroll
        for (int t = 0; t < 8; ++t) {
            float ss = 0.f;
#pragma unroll
            for (int i = 0; i < 4; ++i) {
                float v = acc[t][i];
                float s = v / (1.f + __expf(-v));
                acc[t][i] = s;
                ss += s * s;
            }
            if (c < 192) sp[t][c] = ss;
        }
    }
    __syncthreads();
    if (tid < 64) {
        int t = tid >> 3, i = tid & 7;
        float s = 0.f;
#pragma unroll
        for (int k = 0; k < 24; ++k) s += sp[t][i * 24 + k];
        sq[t][i] = s;
    }
    __syncthreads();
    if (tid < 8) {
        float tot = 0.f;
#pragma unroll
        for (int i = 0; i < 8; ++i) tot += sq[tid][i];
        sscale[tid] = rsqrtf(tot / (float)D_INNER + EPSV);
    }
    __syncthreads();

    if (c < 192) {
        float4 nv = *(const float4*)(norm_w + ch0);
#pragma unroll
        for (int t = 0; t < 8; ++t) {
            float sc = sscale[t];
            uint2 o;
            o.x = pk2(acc[t][0] * sc * nv.x, acc[t][1] * sc * nv.y);
            o.y = pk2(acc[t][2] * sc * nv.z, acc[t][3] * sc * nv.w);
            *(uint2*)(xn + (size_t)(t0 + t) * D_INNER + ch0) = o;
        }
    } else if (c < 224) {
        const int idx = ch0 - 768;    // 0..127
#pragma unroll
        for (int t = 0; t < 8; ++t) {
            uint2 o;
            o.x = pk2(acc[t][0], acc[t][1]);
            o.y = pk2(acc[t][2], acc[t][3]);
            bf16* base = (idx < 64) ? (Bb + (size_t)(t0 + t) * D_STATE + idx)
                                    : (Cb + (size_t)(t0 + t) * D_STATE + (idx - 64));
            *(uint2*)base = o;
        }
    }
    if (tid < 96) {
        int t = tid / 12, hh = tid % 12;
        float v = dtraw[(size_t)(t0 + t) * NHEADS + hh] + dt_bias[hh];
        float spv = (v > 20.f) ? v : log1pf(expf(v));
        dtb[(size_t)(t0 + t) * NHEADS + hh] = spv;
    }
}

// ---------------------------------------------------------------------------
// Score kernel (unchanged)
// ---------------------------------------------------------------------------
__global__ __launch_bounds__(256)
void score_kernel(const bf16* __restrict__ Bb, const bf16* __restrict__ Cb,
                  bf16* __restrict__ Graw) {
    const int bc = blockIdx.x;
    const size_t tok0 = (size_t)bc * Q;
    const int tid = threadIdx.x;
    const int lane = tid & 63, w = tid >> 6;
    const int wr = w >> 1, wc = w & 1;
    __shared__ short sC[Q * 64];
    __shared__ short sB[Q * 64];

#pragma unroll
    for (int it = 0; it < 4; ++it) {
        int j = it * 256 + tid;
        int r = j >> 3, sp = j & 7;
        int sl = sp ^ (r & 7);
        GL_LDS16(Cb + tok0 * D_STATE + r * 64 + sl * 8, sC + j * 8);
        GL_LDS16(Bb + tok0 * D_STATE + r * 64 + sl * 8, sB + j * 8);
    }
    __syncthreads();

    const int l15 = lane & 15, qq = lane >> 4;
    f32x4v acc[4][4];
#pragma unroll
    for (int mi = 0; mi < 4; ++mi)
#pragma unroll
        for (int ni = 0; ni < 4; ++ni)
            acc[mi][ni] = (f32x4v){0.f, 0.f, 0.f, 0.f};

#pragma unroll
    for (int kb = 0; kb < 2; ++kb) {
        bf16x8v af[4], bf[4];
#pragma unroll
        for (int i = 0; i < 4; ++i) {
            int ra = wr * 64 + i * 16 + l15;
            int rb = wc * 64 + i * 16 + l15;
            af[i] = *(const bf16x8v*)(sC + ra * 64 + ((kb * 4 + qq) ^ (ra & 7)) * 8);
            bf[i] = *(const bf16x8v*)(sB + rb * 64 + ((kb * 4 + qq) ^ (rb & 7)) * 8);
        }
#pragma unroll
        for (int mi = 0; mi < 4; ++mi)
#pragma unroll
            for (int ni = 0; ni < 4; ++ni)
                acc[mi][ni] = __builtin_amdgcn_mfma_f32_16x16x32_bf16(
                    af[mi], bf[ni], acc[mi][ni], 0, 0, 0);
    }

    bf16* gout = Graw + (size_t)bc * (Q * Q);
#pragma unroll
    for (int mi = 0; mi < 4; ++mi) {
        int t0 = wr * 64 + mi * 16 + qq * 4;
#pragma unroll
        for (int ni = 0; ni < 4; ++ni) {
            int s = wc * 64 + ni * 16 + l15;
            f32x4v v = acc[mi][ni];
#pragma unroll
            for (int j = 0; j < 4; ++j)
                gout[(size_t)(t0 + j) * Q + s] = f2b(v[j]);
        }
    }
}

// ---------------------------------------------------------------------------
// K3a (MFMA) (unchanged)
// ---------------------------------------------------------------------------
__global__ __launch_bounds__(256)
void chunk_state_mfma(const bf16* __restrict__ xy, const bf16* __restrict__ Bb,
                      const float* __restrict__ dtb, const float* __restrict__ A_log,
                      float* __restrict__ states, float* __restrict__ cdecay) {
    const int sid = blockIdx.x;
    const int c = sid % NCHUNK;
    const int h = (sid / NCHUNK) % NHEADS;
    const int b = sid / (NCHUNK * NHEADS);
    const int tid = threadIdx.x;
    const int lane = tid & 63, w = tid >> 6;
    const size_t tok0 = (size_t)b * SEQLEN + (size_t)c * Q;
    const float Acoef = -expf(A_log[h]);

    __shared__ __align__(16) unsigned short sBT[64 * 128];
    __shared__ __align__(16) unsigned short sXT[64 * 128];
    __shared__ float slcum[Q];
    __shared__ float sdt[Q];
    __shared__ float wtot[2];

    float lx = 0.f;
    if (tid < Q) {
        float dtv = dtb[(tok0 + tid) * NHEADS + h];
        sdt[tid] = dtv;
        lx = dtv * Acoef;
        int ln = tid & 63;
        for (int off = 1; off < 64; off <<= 1) {
            float v = __shfl_up(lx, off, 64);
            if (ln >= off) lx += v;
        }
        if (ln == 63) wtot[tid >> 6] = lx;
    }
    __syncthreads();
    if (tid < Q) {
        if (tid >= 64) lx += wtot[0];
        slcum[tid] = lx;
    }
    __syncthreads();
    const float ltot = slcum[Q - 1];

    {
        int t = tid >> 1, half = tid & 1;
        float s_t = sdt[t] * __expf(ltot - slcum[t]);
        const unsigned short* br = (const unsigned short*)(Bb + (tok0 + t) * D_STATE) + half * 32;
        const unsigned short* xr = (const unsigned short*)(xy + (tok0 + t) * D_INNER + h * HEADDIM) + half * 32;
#pragma unroll
        for (int i = 0; i < 32; ++i) {
            int r = half * 32 + i;
            sBT[tswz(r, t)] = __bfloat16_as_ushort(f2b(bu(br[i]) * s_t));
            sXT[tswz(r, t)] = xr[i];
        }
    }
    __syncthreads();

    const int l15 = lane & 15, qq = lane >> 4;
    f32x4v acc[4];
#pragma unroll
    for (int ni = 0; ni < 4; ++ni) acc[ni] = (f32x4v){0.f, 0.f, 0.f, 0.f};

#pragma unroll
    for (int kb = 0; kb < 4; ++kb) {
        const int col = kb * 32 + qq * 8;
        bf16x8v af = *(const bf16x8v*)(&sBT[tswz(w * 16 + l15, col)]);
#pragma unroll
        for (int ni = 0; ni < 4; ++ni) {
            bf16x8v bx = *(const bf16x8v*)(&sXT[tswz(ni * 16 + l15, col)]);
            acc[ni] = __builtin_amdgcn_mfma_f32_16x16x32_bf16(af, bx, acc[ni], 0, 0, 0);
        }
    }

    float* out = states + (size_t)sid * 4096;
#pragma unroll
    for (int ni = 0; ni < 4; ++ni) {
#pragma unroll
        for (int j = 0; j < 4; ++j) {
            int n = w * 16 + qq * 4 + j;
            int p = ni * 16 + l15;
            out[n * 64 + p] = acc[ni][j];
        }
    }
    if (tid == 0) cdecay[sid] = expf(ltot);
}

// ---------------------------------------------------------------------------
// K3b (unchanged)
// ---------------------------------------------------------------------------
__global__ __launch_bounds__(256)
void state_pass_kernel(float* __restrict__ states, const float* __restrict__ cdecay) {
    const int bh = blockIdx.x;
    const int tid = threadIdx.x;
    float run[16];
#pragma unroll
    for (int i = 0; i < 16; ++i) run[i] = 0.f;
    float* base = states + (size_t)bh * NCHUNK * 4096 + tid * 16;
    const float* cd = cdecay + bh * NCHUNK;
    for (int c = 0; c < NCHUNK; ++c) {
        float dec = cd[c];
        float* ptr = base + (size_t)c * 4096;
        float4 s0 = *(float4*)(ptr + 0);
        float4 s1 = *(float4*)(ptr + 4);
        float4 s2 = *(float4*)(ptr + 8);
        float4 s3 = *(float4*)(ptr + 12);
        float nr[16];
        nr[0] = dec * run[0] + s0.x;  nr[1] = dec * run[1] + s0.y;
        nr[2] = dec * run[2] + s0.z;  nr[3] = dec * run[3] + s0.w;
        nr[4] = dec * run[4] + s1.x;  nr[5] = dec * run[5] + s1.y;
        nr[6] = dec * run[6] + s1.z;  nr[7] = dec * run[7] + s1.w;
        nr[8] = dec * run[8] + s2.x;  nr[9] = dec * run[9] + s2.y;
        nr[10] = dec * run[10] + s2.z; nr[11] = dec * run[11] + s2.w;
        nr[12] = dec * run[12] + s3.x; nr[13] = dec * run[13] + s3.y;
        nr[14] = dec * run[14] + s3.z; nr[15] = dec * run[15] + s3.w;
        *(float4*)(ptr + 0)  = make_float4(run[0], run[1], run[2], run[3]);
        *(float4*)(ptr + 4)  = make_float4(run[4], run[5], run[6], run[7]);
        *(float4*)(ptr + 8)  = make_float4(run[8], run[9], run[10], run[11]);
        *(float4*)(ptr + 12) = make_float4(run[12], run[13], run[14], run[15]);
#pragma unroll
        for (int i = 0; i < 16; ++i) run[i] = nr[i];
    }
}

// ---------------------------------------------------------------------------
// K3c (MFMA) (unchanged)
// ---------------------------------------------------------------------------
__global__ __launch_bounds__(256)
void chunk_output_mfma(const bf16* __restrict__ Zb, bf16* __restrict__ xy,
                       const bf16* __restrict__ Cb, const bf16* __restrict__ Graw,
                       const float* __restrict__ dtb, const float* __restrict__ A_log,
                       const float* __restrict__ Dpa, const float* __restrict__ states) {
    const int sid = blockIdx.x;
    const int c = sid % NCHUNK;
    const int h = (sid / NCHUNK) % NHEADS;
    const int b = sid / (NCHUNK * NHEADS);
    const int tid = threadIdx.x;
    const int lane = tid & 63, w = tid >> 6;
    const int wr = w >> 1, wc = w & 1;
    const size_t tok0 = (size_t)b * SEQLEN + (size_t)c * Q;
    const int bc = b * NCHUNK + c;
    const float Acoef = -expf(A_log[h]);

    __shared__ __align__(16) float slcum[Q];
    __shared__ __align__(16) float sdt[Q];
    __shared__ float wtot[2];
    __shared__ __align__(16) unsigned short sXt[64][136];
    __shared__ __align__(16) unsigned short sNh[64][72];
    __shared__ __align__(16) unsigned short sNl[64][72];

    float lx = 0.f;
    if (tid < Q) {
        float dtv = dtb[(tok0 + tid) * NHEADS + h];
        sdt[tid] = dtv;
        lx = dtv * Acoef;
        int ln = tid & 63;
        for (int off = 1; off < 64; off <<= 1) {
            float v = __shfl_up(lx, off, 64);
            if (ln >= off) lx += v;
        }
        if (ln == 63) wtot[tid >> 6] = lx;
    }
    __syncthreads();
    if (tid < Q) {
        if (tid >= 64) lx += wtot[0];
        slcum[tid] = lx;
    }

    {
        int t = tid >> 1, ph = (tid & 1) * 32;
        const unsigned short* xr = (const unsigned short*)(xy + (tok0 + t) * D_INNER + h * HEADDIM + ph);
#pragma unroll
        for (int i = 0; i < 32; ++i) sXt[ph + i][t] = xr[i];
    }
    {
        const float* init = states + (size_t)sid * 4096;
        for (int i = tid; i < 1024; i += 256) {
            float4 v = ((const float4*)init)[i];
            int n = i >> 4;
            int p = (i & 15) * 4;
#pragma unroll
            for (int j2 = 0; j2 < 4; ++j2) {
                float f = (&v.x)[j2];
                bf16 hi = f2b(f);
                float lo = f - b2f(hi);
                sNh[p + j2][n] = __bfloat16_as_ushort(hi);
                sNl[p + j2][n] = __bfloat16_as_ushort(f2b(lo));
            }
        }
    }
    __syncthreads();

    const int l15 = lane & 15, qq = lane >> 4;
    const int twr = wr * 64;

    float lct_mi[4], elct[4];
    int tcur[4];
#pragma unroll
    for (int mi = 0; mi < 4; ++mi) {
        tcur[mi] = twr + mi * 16 + l15;
        lct_mi[mi] = slcum[tcur[mi]];
        elct[mi] = __expf(lct_mi[mi]);
    }

    f32x4v acc[4][2];
#pragma unroll
    for (int mi = 0; mi < 4; ++mi)
#pragma unroll
        for (int ni = 0; ni < 2; ++ni)
            acc[mi][ni] = (f32x4v){0.f, 0.f, 0.f, 0.f};

    const bf16* grow = Graw + (size_t)bc * (Q * Q);

#pragma unroll
    for (int kb = 0; kb < 4; ++kb) {
        const int s0 = kb * 32 + qq * 8;
        float4 lcA = *(const float4*)(slcum + s0);
        float4 lcB = *(const float4*)(slcum + s0 + 4);
        float4 dtA = *(const float4*)(sdt + s0);
        float4 dtB = *(const float4*)(sdt + s0 + 4);
        bf16x8v af[4];
#pragma unroll
        for (int mi = 0; mi < 4; ++mi) {
            int t = tcur[mi];
            float lct = lct_mi[mi];
            uint4 gv = *(const uint4*)(grow + (size_t)t * Q + s0);
            float f0 = (s0 + 0 <= t) ? bl(gv.x) * dtA.x * __expf(lct - lcA.x) : 0.f;
            float f1 = (s0 + 1 <= t) ? bh(gv.x) * dtA.y * __expf(lct - lcA.y) : 0.f;
            float f2 = (s0 + 2 <= t) ? bl(gv.y) * dtA.z * __expf(lct - lcA.z) : 0.f;
            float f3 = (s0 + 3 <= t) ? bh(gv.y) * dtA.w * __expf(lct - lcA.w) : 0.f;
            float f4 = (s0 + 4 <= t) ? bl(gv.z) * dtB.x * __expf(lct - lcB.x) : 0.f;
            float f5 = (s0 + 5 <= t) ? bh(gv.z) * dtB.y * __expf(lct - lcB.y) : 0.f;
            float f6 = (s0 + 6 <= t) ? bl(gv.w) * dtB.z * __expf(lct - lcB.z) : 0.f;
            float f7 = (s0 + 7 <= t) ? bh(gv.w) * dtB.w * __expf(lct - lcB.w) : 0.f;
            union { bf16x8v v; unsigned u[4]; } r;
            r.u[0] = pk2(f0, f1); r.u[1] = pk2(f2, f3);
            r.u[2] = pk2(f4, f5); r.u[3] = pk2(f6, f7);
            af[mi] = r.v;
        }
        bf16x8v bfr[2];
#pragma unroll
        for (int ni = 0; ni < 2; ++ni) {
            int p = wc * 32 + ni * 16 + l15;
            bfr[ni] = *(const bf16x8v*)(&sXt[p][s0]);
        }
#pragma unroll
        for (int mi = 0; mi < 4; ++mi)
#pragma unroll
            for (int ni = 0; ni < 2; ++ni)
                acc[mi][ni] = __builtin_amdgcn_mfma_f32_16x16x32_bf16(
                    af[mi], bfr[ni], acc[mi][ni], 0, 0, 0);
    }

#pragma unroll
    for (int half = 0; half < 2; ++half) {
        const int n0 = half * 32 + qq * 8;
        bf16x8v af[4];
#pragma unroll
        for (int mi = 0; mi < 4; ++mi) {
            uint4 cv = *(const uint4*)(Cb + (tok0 + tcur[mi]) * D_STATE + n0);
            float el = elct[mi];
            union { bf16x8v v; unsigned u[4]; } r;
            r.u[0] = pk2(bl(cv.x) * el, bh(cv.x) * el);
            r.u[1] = pk2(bl(cv.y) * el, bh(cv.y) * el);
            r.u[2] = pk2(bl(cv.z) * el, bh(cv.z) * el);
            r.u[3] = pk2(bl(cv.w) * el, bh(cv.w) * el);
            af[mi] = r.v;
        }
        bf16x8v bh_[2], bl_[2];
#pragma unroll
        for (int ni = 0; ni < 2; ++ni) {
            int p = wc * 32 + ni * 16 + l15;
            bh_[ni] = *(const bf16x8v*)(&sNh[p][n0]);
            bl_[ni] = *(const bf16x8v*)(&sNl[p][n0]);
        }
#pragma unroll
        for (int mi = 0; mi < 4; ++mi)
#pragma unroll
            for (int ni = 0; ni < 2; ++ni) {
                acc[mi][ni] = __builtin_amdgcn_mfma_f32_16x16x32_bf16(
                    af[mi], bh_[ni], acc[mi][ni], 0, 0, 0);
                acc[mi][ni] = __builtin_amdgcn_mfma_f32_16x16x32_bf16(
                    af[mi], bl_[ni], acc[mi][ni], 0, 0, 0);
            }
    }

    const float Dh = Dpa[h];
#pragma unroll
    for (int mi = 0; mi < 4; ++mi) {
        int t0 = twr + mi * 16 + qq * 4;
#pragma unroll
        for (int ni = 0; ni < 2; ++ni) {
            int p = wc * 32 + ni * 16 + l15;
            f32x4v v = acc[mi][ni];
#pragma unroll
            for (int jj = 0; jj < 4; ++jj) {
                size_t off = (tok0 + t0 + jj) * D_INNER + h * HEADDIM + p;
                float xv = b2f(xy[off]);
                float zv = b2f(Zb[off]);
                float yv = v[jj] + Dh * xv;
                yv *= zv / (1.f + __expf(-zv));
                xy[off] = f2b(yv);
            }
        }
    }
}

// ---------------------------------------------------------------------------
extern "C" void kernel_launch(void* const* d_in, const int* in_sizes, int n_in,
                              void* d_out, int out_size, void* d_ws, size_t ws_size,
                              hipStream_t stream) {
    (void)in_sizes; (void)n_in; (void)out_size; (void)ws_size;
    const float* u          = (const float*)d_in[0];
    const float* in_proj_w  = (const float*)d_in[1];
    const float* conv_w     = (const float*)d_in[2];
    const float* conv_b     = (const float*)d_in[3];
    const float* norm_w     = (const float*)d_in[4];
    const float* out_proj_w = (const float*)d_in[5];
    const float* A_log      = (const float*)d_in[6];
    const float* Dp         = (const float*)d_in[7];
    const float* dt_bias    = (const float*)d_in[8];

    char* w = (char*)d_ws;
    bf16*  Zb     = (bf16*)w;     w += (size_t)NTOK * D_INNER * 2;
    bf16*  XBC    = (bf16*)w;     w += (size_t)NTOK * D_CONV_IN * 2;
    bf16*  xy     = (bf16*)w;     w += (size_t)NTOK * D_INNER * 2;
    bf16*  Bb     = (bf16*)w;     w += (size_t)NTOK * D_STATE * 2;
    bf16*  Cb     = (bf16*)w;     w += (size_t)NTOK * D_STATE * 2;
    float* dtraw  = (float*)w;    w += (size_t)NTOK * NHEADS * 4;
    float* dtb    = (float*)w;    w += (size_t)NTOK * NHEADS * 4;
    float* cdecay = (float*)w;    w += (size_t)NCHB * 4;
    bf16*  wA     = (bf16*)w;     w += (size_t)ZXLD * D_MODEL * 2;
    bf16*  wO     = (bf16*)w;
    float* states = (float*)XBC;
    bf16*  Graw   = (bf16*)((char*)XBC + (size_t)NCHB * 4096 * 4);
    bf16*  uB     = xy;

    { int n = NTOK * D_MODEL;
      cvt_f32_bf16<<<(n / 4 + 255) / 256, 256, 0, stream>>>(u, (unsigned short*)uB, n); }
    { int n = ZXLD * D_MODEL;
      cvt_f32_bf16<<<(n / 4 + 255) / 256, 256, 0, stream>>>(in_proj_w, (unsigned short*)wA, n); }
    { int n = D_MODEL * D_INNER;
      cvt_f32_bf16<<<(n / 4 + 255) / 256, 256, 0, stream>>>(out_proj_w, (unsigned short*)wO, n); }

    dt_gemm<<<NTOK * NHEADS / 256, 256, 0, stream>>>(u, in_proj_w, dtraw);

    dim3 g1(ZXLD / 128, NTOK / 128);
    gemm_mfma<0><<<g1, 256, 0, stream>>>(uB, wA, D_MODEL, Zb, XBC, nullptr);

    conv_norm_v3<<<NTOK / 8, 256, 0, stream>>>(XBC, dtraw, conv_w, conv_b, norm_w, dt_bias,
                                               xy, Bb, Cb, dtb);

    score_kernel<<<NBC, 256, 0, stream>>>(Bb, Cb, Graw);
    chunk_state_mfma<<<NCHB, 256, 0, stream>>>(xy, Bb, dtb, A_log, states, cdecay);
    state_pass_kernel<<<BATCH * NHEADS, 256, 0, stream>>>(states, cdecay);
    chunk_output_mfma<<<NCHB, 256, 0, stream>>>(Zb, xy, Cb, Graw, dtb, A_log, Dp, states);

    dim3 g4(D_MODEL / 128, NTOK / 128);
    gemm_mfma<1><<<g4, 256, 0, stream>>>(xy, wO, D_INNER, nullptr, nullptr, (float*)d_out);
}

// Round 9
// 358.141 us; speedup vs baseline: 7.2343x; 1.1596x over previous
//
#include <hip/hip_runtime.h>
#include <hip/hip_bf16.h>
#include <cstddef>

#define D_MODEL   384
#define D_IN_PROJ 1676
#define D_INNER   768
#define D_CONV_IN 896
#define ZXLD      1664
#define NHEADS    12
#define HEADDIM   64
#define D_STATE   64
#define SEQLEN    4096
#define BATCH     8
#define NTOK      (BATCH * SEQLEN)
#define EPSV      1e-5f
#define Q         128
#define NCHUNK    (SEQLEN / Q)
#define NCHB      (BATCH * NHEADS * NCHUNK)
#define NBC       (BATCH * NCHUNK)

typedef __hip_bfloat16 bf16;
typedef __attribute__((ext_vector_type(8))) short bf16x8v;
typedef __attribute__((ext_vector_type(4))) float f32x4v;

__device__ __forceinline__ float b2f(bf16 v) { return __bfloat162float(v); }
__device__ __forceinline__ bf16  f2b(float v) { return __float2bfloat16(v); }
__device__ __forceinline__ float bl(unsigned u)  { return __uint_as_float(u << 16); }
__device__ __forceinline__ float bh(unsigned u)  { return __uint_as_float(u & 0xffff0000u); }
__device__ __forceinline__ float bu(unsigned short v) { return __uint_as_float(((unsigned)v) << 16); }
__device__ __forceinline__ unsigned pk2(float a, float b) {
    return ((unsigned)__bfloat16_as_ushort(f2b(b)) << 16) | (unsigned)__bfloat16_as_ushort(f2b(a));
}
__device__ __forceinline__ int swzf(int r) { return (r ^ (r >> 2)) & 3; }
__device__ __forceinline__ int tswz(int r, int col) {
    return r * 128 + ((((col >> 3) ^ (r & 7)) << 3) | (col & 7));
}

#define GL_LDS16(g, l) __builtin_amdgcn_global_load_lds( \
    (const __attribute__((address_space(1))) unsigned*)(g), \
    (__attribute__((address_space(3))) unsigned*)(l), 16, 0, 0)

// ---------------------------------------------------------------------------
__global__ __launch_bounds__(256)
void cvt_f32_bf16(const float* __restrict__ in, unsigned short* __restrict__ out, int n) {
    int i = (blockIdx.x * 256 + threadIdx.x) * 4;
    if (i + 3 < n) {
        float4 v = *(const float4*)(in + i);
        uint2 o; o.x = pk2(v.x, v.y); o.y = pk2(v.z, v.w);
        *(uint2*)(out + i) = o;
    }
}

// ---------------------------------------------------------------------------
__global__ __launch_bounds__(256)
void dt_gemm(const float* __restrict__ u, const float* __restrict__ W,
             float* __restrict__ dtraw) {
    int g = blockIdx.x * 256 + threadIdx.x;
    int row = g / NHEADS, head = g % NHEADS;
    const float4* ur = (const float4*)(u + (size_t)row * D_MODEL);
    const float4* wr = (const float4*)(W + (size_t)(ZXLD + head) * D_MODEL);
    float acc = 0.f;
#pragma unroll 8
    for (int k = 0; k < D_MODEL / 4; ++k) {
        float4 a = ur[k], b = wr[k];
        acc += a.x * b.x + a.y * b.y + a.z * b.z + a.w * b.w;
    }
    dtraw[g] = acc;
}

// ---------------------------------------------------------------------------
// MFMA GEMM-NT (unchanged)
// ---------------------------------------------------------------------------
template<int EPI>
__global__ __launch_bounds__(256)
void gemm_mfma(const bf16* __restrict__ A, const bf16* __restrict__ Bw, int K,
               bf16* __restrict__ Zo, bf16* __restrict__ XBCo, float* __restrict__ Co) {
    __shared__ short As[128 * 32];
    __shared__ short Bs[128 * 32];
    const int tid = threadIdx.x;
    const int lane = tid & 63;
    const int w = tid >> 6;
    const int wr = w >> 1, wc = w & 1;
    const int bm = blockIdx.y * 128;
    const int bn = blockIdx.x * 128;

    f32x4v acc[4][4];
#pragma unroll
    for (int mi = 0; mi < 4; ++mi)
#pragma unroll
        for (int ni = 0; ni < 4; ++ni)
            acc[mi][ni] = (f32x4v){0.f, 0.f, 0.f, 0.f};

    size_t aoff[2]; size_t boff[2];
#pragma unroll
    for (int q = 0; q < 2; ++q) {
        int o = q * 4096 + tid * 16;
        int row = o >> 6;
        int ps = (o >> 4) & 3;
        int sl = ps ^ swzf(row);
        aoff[q] = (size_t)(bm + row) * K + sl * 8;
        boff[q] = (size_t)(bn + row) * K + sl * 8;
    }
    short* adst0 = As + tid * 8;          short* adst1 = As + 2048 + tid * 8;
    short* bdst0 = Bs + tid * 8;          short* bdst1 = Bs + 2048 + tid * 8;

    int aidx[4], bidx[4];
#pragma unroll
    for (int i = 0; i < 4; ++i) {
        int ra = wr * 64 + i * 16 + (lane & 15);
        int rb = wc * 64 + i * 16 + (lane & 15);
        aidx[i] = ra * 32 + (((lane >> 4) ^ swzf(ra)) * 8);
        bidx[i] = rb * 32 + (((lane >> 4) ^ swzf(rb)) * 8);
    }

    for (int k0 = 0; k0 < K; k0 += 32) {
        __syncthreads();
        GL_LDS16(A + aoff[0] + k0, adst0);
        GL_LDS16(A + aoff[1] + k0, adst1);
        GL_LDS16(Bw + boff[0] + k0, bdst0);
        GL_LDS16(Bw + boff[1] + k0, bdst1);
        __syncthreads();

        bf16x8v af[4], bf[4];
#pragma unroll
        for (int i = 0; i < 4; ++i) {
            af[i] = *(const bf16x8v*)(As + aidx[i]);
            bf[i] = *(const bf16x8v*)(Bs + bidx[i]);
        }
#pragma unroll
        for (int mi = 0; mi < 4; ++mi)
#pragma unroll
            for (int ni = 0; ni < 4; ++ni)
                acc[mi][ni] = __builtin_amdgcn_mfma_f32_16x16x32_bf16(
                    af[mi], bf[ni], acc[mi][ni], 0, 0, 0);
    }

    const int l15 = lane & 15, l4 = lane >> 4;
#pragma unroll
    for (int mi = 0; mi < 4; ++mi) {
        int rbase = bm + wr * 64 + mi * 16 + l4 * 4;
#pragma unroll
        for (int ni = 0; ni < 4; ++ni) {
            int col = bn + wc * 64 + ni * 16 + l15;
            f32x4v v = acc[mi][ni];
            if (EPI == 0) {
                if (col < D_INNER) {
#pragma unroll
                    for (int j = 0; j < 4; ++j)
                        Zo[(size_t)(rbase + j) * D_INNER + col] = f2b(v[j]);
                } else {
#pragma unroll
                    for (int j = 0; j < 4; ++j)
                        XBCo[(size_t)(rbase + j) * D_CONV_IN + (col - D_INNER)] = f2b(v[j]);
                }
            } else {
#pragma unroll
                for (int j = 0; j < 4; ++j)
                    Co[(size_t)(rbase + j) * D_MODEL + col] = v[j];
            }
        }
    }
}

// ---------------------------------------------------------------------------
// K2 v3 (unchanged)
// ---------------------------------------------------------------------------
__global__ __launch_bounds__(256)
void conv_norm_v3(const bf16* __restrict__ XBC, const float* __restrict__ dtraw,
                  const float* __restrict__ conv_w, const float* __restrict__ conv_b,
                  const float* __restrict__ norm_w, const float* __restrict__ dt_bias,
                  bf16* __restrict__ xn, bf16* __restrict__ Bb,
                  bf16* __restrict__ Cb, float* __restrict__ dtb) {
    const int tid = threadIdx.x;
    const int t0 = blockIdx.x * 8;
    const int l0 = t0 & (SEQLEN - 1);

    __shared__ float sp[8][200];
    __shared__ float sq[8][8];
    __shared__ float sscale[8];

    const int c = tid;
    const bool active = (c < 224);
    const int ch0 = c * 4;

    float acc[8][4];
    float w0[4], w1[4], w2[4], w3[4];

    if (active) {
        float4 wa = *(const float4*)(conv_w + (ch0 + 0) * 4);
        float4 wb = *(const float4*)(conv_w + (ch0 + 1) * 4);
        float4 wcc = *(const float4*)(conv_w + (ch0 + 2) * 4);
        float4 wd = *(const float4*)(conv_w + (ch0 + 3) * 4);
        w0[0] = wa.x; w1[0] = wa.y; w2[0] = wa.z; w3[0] = wa.w;
        w0[1] = wb.x; w1[1] = wb.y; w2[1] = wb.z; w3[1] = wb.w;
        w0[2] = wcc.x; w1[2] = wcc.y; w2[2] = wcc.z; w3[2] = wcc.w;
        w0[3] = wd.x; w1[3] = wd.y; w2[3] = wd.z; w3[3] = wd.w;
        float4 bv = *(const float4*)(conv_b + ch0);
#pragma unroll
        for (int t = 0; t < 8; ++t) {
            acc[t][0] = bv.x; acc[t][1] = bv.y; acc[t][2] = bv.z; acc[t][3] = bv.w;
        }
#pragma unroll
        for (int ri = 0; ri < 11; ++ri) {
            int lr = l0 - 3 + ri;
            if (lr >= 0) {
                uint2 rv = *(const uint2*)((const unsigned short*)XBC
                              + (size_t)(t0 - 3 + ri) * D_CONV_IN + ch0);
                float r0 = bl(rv.x), r1 = bh(rv.x), r2 = bl(rv.y), r3 = bh(rv.y);
#pragma unroll
                for (int t = 0; t < 8; ++t) {
                    if (t >= ri - 3 && t <= ri) {
                        const int j = ri - t;
                        const float* wj = (j == 0) ? w0 : (j == 1) ? w1 : (j == 2) ? w2 : w3;
                        acc[t][0] += r0 * wj[0];
                        acc[t][1] += r1 * wj[1];
                        acc[t][2] += r2 * wj[2];
                        acc[t][3] += r3 * wj[3];
                    }
                }
            }
        }
#pragma unroll
        for (int t = 0; t < 8; ++t) {
            float ss = 0.f;
#pragma unroll
            for (int i = 0; i < 4; ++i) {
                float v = acc[t][i];
                float s = v / (1.f + __expf(-v));
                acc[t][i] = s;
                ss += s * s;
            }
            if (c < 192) sp[t][c] = ss;
        }
    }
    __syncthreads();
    if (tid < 64) {
        int t = tid >> 3, i = tid & 7;
        float s = 0.f;
#pragma unroll
        for (int k = 0; k < 24; ++k) s += sp[t][i * 24 + k];
        sq[t][i] = s;
    }
    __syncthreads();
    if (tid < 8) {
        float tot = 0.f;
#pragma unroll
        for (int i = 0; i < 8; ++i) tot += sq[tid][i];
        sscale[tid] = rsqrtf(tot / (float)D_INNER + EPSV);
    }
    __syncthreads();

    if (c < 192) {
        float4 nv = *(const float4*)(norm_w + ch0);
#pragma unroll
        for (int t = 0; t < 8; ++t) {
            float sc = sscale[t];
            uint2 o;
            o.x = pk2(acc[t][0] * sc * nv.x, acc[t][1] * sc * nv.y);
            o.y = pk2(acc[t][2] * sc * nv.z, acc[t][3] * sc * nv.w);
            *(uint2*)(xn + (size_t)(t0 + t) * D_INNER + ch0) = o;
        }
    } else if (c < 224) {
        const int idx = ch0 - 768;
#pragma unroll
        for (int t = 0; t < 8; ++t) {
            uint2 o;
            o.x = pk2(acc[t][0], acc[t][1]);
            o.y = pk2(acc[t][2], acc[t][3]);
            bf16* base = (idx < 64) ? (Bb + (size_t)(t0 + t) * D_STATE + idx)
                                    : (Cb + (size_t)(t0 + t) * D_STATE + (idx - 64));
            *(uint2*)base = o;
        }
    }
    if (tid < 96) {
        int t = tid / 12, hh = tid % 12;
        float v = dtraw[(size_t)(t0 + t) * NHEADS + hh] + dt_bias[hh];
        float spv = (v > 20.f) ? v : log1pf(expf(v));
        dtb[(size_t)(t0 + t) * NHEADS + hh] = spv;
    }
}

// ---------------------------------------------------------------------------
// Score kernel (unchanged)
// ---------------------------------------------------------------------------
__global__ __launch_bounds__(256)
void score_kernel(const bf16* __restrict__ Bb, const bf16* __restrict__ Cb,
                  bf16* __restrict__ Graw) {
    const int bc = blockIdx.x;
    const size_t tok0 = (size_t)bc * Q;
    const int tid = threadIdx.x;
    const int lane = tid & 63, w = tid >> 6;
    const int wr = w >> 1, wc = w & 1;
    __shared__ short sC[Q * 64];
    __shared__ short sB[Q * 64];

#pragma unroll
    for (int it = 0; it < 4; ++it) {
        int j = it * 256 + tid;
        int r = j >> 3, sp = j & 7;
        int sl = sp ^ (r & 7);
        GL_LDS16(Cb + tok0 * D_STATE + r * 64 + sl * 8, sC + j * 8);
        GL_LDS16(Bb + tok0 * D_STATE + r * 64 + sl * 8, sB + j * 8);
    }
    __syncthreads();

    const int l15 = lane & 15, qq = lane >> 4;
    f32x4v acc[4][4];
#pragma unroll
    for (int mi = 0; mi < 4; ++mi)
#pragma unroll
        for (int ni = 0; ni < 4; ++ni)
            acc[mi][ni] = (f32x4v){0.f, 0.f, 0.f, 0.f};

#pragma unroll
    for (int kb = 0; kb < 2; ++kb) {
        bf16x8v af[4], bf[4];
#pragma unroll
        for (int i = 0; i < 4; ++i) {
            int ra = wr * 64 + i * 16 + l15;
            int rb = wc * 64 + i * 16 + l15;
            af[i] = *(const bf16x8v*)(sC + ra * 64 + ((kb * 4 + qq) ^ (ra & 7)) * 8);
            bf[i] = *(const bf16x8v*)(sB + rb * 64 + ((kb * 4 + qq) ^ (rb & 7)) * 8);
        }
#pragma unroll
        for (int mi = 0; mi < 4; ++mi)
#pragma unroll
            for (int ni = 0; ni < 4; ++ni)
                acc[mi][ni] = __builtin_amdgcn_mfma_f32_16x16x32_bf16(
                    af[mi], bf[ni], acc[mi][ni], 0, 0, 0);
    }

    bf16* gout = Graw + (size_t)bc * (Q * Q);
#pragma unroll
    for (int mi = 0; mi < 4; ++mi) {
        int t0 = wr * 64 + mi * 16 + qq * 4;
#pragma unroll
        for (int ni = 0; ni < 4; ++ni) {
            int s = wc * 64 + ni * 16 + l15;
            f32x4v v = acc[mi][ni];
#pragma unroll
            for (int j = 0; j < 4; ++j)
                gout[(size_t)(t0 + j) * Q + s] = f2b(v[j]);
        }
    }
}

// ---------------------------------------------------------------------------
// K3a (MFMA) (unchanged)
// ---------------------------------------------------------------------------
__global__ __launch_bounds__(256)
void chunk_state_mfma(const bf16* __restrict__ xy, const bf16* __restrict__ Bb,
                      const float* __restrict__ dtb, const float* __restrict__ A_log,
                      float* __restrict__ states, float* __restrict__ cdecay) {
    const int sid = blockIdx.x;
    const int c = sid % NCHUNK;
    const int h = (sid / NCHUNK) % NHEADS;
    const int b = sid / (NCHUNK * NHEADS);
    const int tid = threadIdx.x;
    const int lane = tid & 63, w = tid >> 6;
    const size_t tok0 = (size_t)b * SEQLEN + (size_t)c * Q;
    const float Acoef = -expf(A_log[h]);

    __shared__ __align__(16) unsigned short sBT[64 * 128];
    __shared__ __align__(16) unsigned short sXT[64 * 128];
    __shared__ float slcum[Q];
    __shared__ float sdt[Q];
    __shared__ float wtot[2];

    float lx = 0.f;
    if (tid < Q) {
        float dtv = dtb[(tok0 + tid) * NHEADS + h];
        sdt[tid] = dtv;
        lx = dtv * Acoef;
        int ln = tid & 63;
        for (int off = 1; off < 64; off <<= 1) {
            float v = __shfl_up(lx, off, 64);
            if (ln >= off) lx += v;
        }
        if (ln == 63) wtot[tid >> 6] = lx;
    }
    __syncthreads();
    if (tid < Q) {
        if (tid >= 64) lx += wtot[0];
        slcum[tid] = lx;
    }
    __syncthreads();
    const float ltot = slcum[Q - 1];

    {
        int t = tid >> 1, half = tid & 1;
        float s_t = sdt[t] * __expf(ltot - slcum[t]);
        const unsigned short* br = (const unsigned short*)(Bb + (tok0 + t) * D_STATE) + half * 32;
        const unsigned short* xr = (const unsigned short*)(xy + (tok0 + t) * D_INNER + h * HEADDIM) + half * 32;
#pragma unroll
        for (int i = 0; i < 32; ++i) {
            int r = half * 32 + i;
            sBT[tswz(r, t)] = __bfloat16_as_ushort(f2b(bu(br[i]) * s_t));
            sXT[tswz(r, t)] = xr[i];
        }
    }
    __syncthreads();

    const int l15 = lane & 15, qq = lane >> 4;
    f32x4v acc[4];
#pragma unroll
    for (int ni = 0; ni < 4; ++ni) acc[ni] = (f32x4v){0.f, 0.f, 0.f, 0.f};

#pragma unroll
    for (int kb = 0; kb < 4; ++kb) {
        const int col = kb * 32 + qq * 8;
        bf16x8v af = *(const bf16x8v*)(&sBT[tswz(w * 16 + l15, col)]);
#pragma unroll
        for (int ni = 0; ni < 4; ++ni) {
            bf16x8v bx = *(const bf16x8v*)(&sXT[tswz(ni * 16 + l15, col)]);
            acc[ni] = __builtin_amdgcn_mfma_f32_16x16x32_bf16(af, bx, acc[ni], 0, 0, 0);
        }
    }

    float* out = states + (size_t)sid * 4096;
#pragma unroll
    for (int ni = 0; ni < 4; ++ni) {
#pragma unroll
        for (int j = 0; j < 4; ++j) {
            int n = w * 16 + qq * 4 + j;
            int p = ni * 16 + l15;
            out[n * 64 + p] = acc[ni][j];
        }
    }
    if (tid == 0) cdecay[sid] = expf(ltot);
}

// ---------------------------------------------------------------------------
// K3b (unchanged)
// ---------------------------------------------------------------------------
__global__ __launch_bounds__(256)
void state_pass_kernel(float* __restrict__ states, const float* __restrict__ cdecay) {
    const int bh = blockIdx.x;
    const int tid = threadIdx.x;
    float run[16];
#pragma unroll
    for (int i = 0; i < 16; ++i) run[i] = 0.f;
    float* base = states + (size_t)bh * NCHUNK * 4096 + tid * 16;
    const float* cd = cdecay + bh * NCHUNK;
    for (int c = 0; c < NCHUNK; ++c) {
        float dec = cd[c];
        float* ptr = base + (size_t)c * 4096;
        float4 s0 = *(float4*)(ptr + 0);
        float4 s1 = *(float4*)(ptr + 4);
        float4 s2 = *(float4*)(ptr + 8);
        float4 s3 = *(float4*)(ptr + 12);
        float nr[16];
        nr[0] = dec * run[0] + s0.x;  nr[1] = dec * run[1] + s0.y;
        nr[2] = dec * run[2] + s0.z;  nr[3] = dec * run[3] + s0.w;
        nr[4] = dec * run[4] + s1.x;  nr[5] = dec * run[5] + s1.y;
        nr[6] = dec * run[6] + s1.z;  nr[7] = dec * run[7] + s1.w;
        nr[8] = dec * run[8] + s2.x;  nr[9] = dec * run[9] + s2.y;
        nr[10] = dec * run[10] + s2.z; nr[11] = dec * run[11] + s2.w;
        nr[12] = dec * run[12] + s3.x; nr[13] = dec * run[13] + s3.y;
        nr[14] = dec * run[14] + s3.z; nr[15] = dec * run[15] + s3.w;
        *(float4*)(ptr + 0)  = make_float4(run[0], run[1], run[2], run[3]);
        *(float4*)(ptr + 4)  = make_float4(run[4], run[5], run[6], run[7]);
        *(float4*)(ptr + 8)  = make_float4(run[8], run[9], run[10], run[11]);
        *(float4*)(ptr + 12) = make_float4(run[12], run[13], run[14], run[15]);
#pragma unroll
        for (int i = 0; i < 16; ++i) run[i] = nr[i];
    }
}

// ---------------------------------------------------------------------------
// K3c v2 (MFMA): 4x1 wave layout (wave owns 32 t-rows x all 64 p).
// Mask factor = __expf(lct - sldn[s]) with sldn[s] = lcum[s] - log(dt_s).
// Epilogue via LDS transpose -> uint4 global I/O.
// ---------------------------------------------------------------------------
__global__ __launch_bounds__(256)
void chunk_output_mfma(const bf16* __restrict__ Zb, bf16* __restrict__ xy,
                       const bf16* __restrict__ Cb, const bf16* __restrict__ Graw,
                       const float* __restrict__ dtb, const float* __restrict__ A_log,
                       const float* __restrict__ Dpa, const float* __restrict__ states) {
    const int sid = blockIdx.x;
    const int c = sid % NCHUNK;
    const int h = (sid / NCHUNK) % NHEADS;
    const int b = sid / (NCHUNK * NHEADS);
    const int tid = threadIdx.x;
    const int lane = tid & 63, w = tid >> 6;
    const size_t tok0 = (size_t)b * SEQLEN + (size_t)c * Q;
    const int bc = b * NCHUNK + c;
    const float Acoef = -expf(A_log[h]);

    // LDS union: staging {sXt 17408 | sNh 9216 | sNl 9216} = 35840 B,
    // then reused as sY[128][68] f32 (34816 B) for the epilogue transpose.
    __shared__ __align__(16) char smem[35840];
    unsigned short (*sXt)[136] = (unsigned short(*)[136])smem;
    unsigned short (*sNh)[72]  = (unsigned short(*)[72])(smem + 17408);
    unsigned short (*sNl)[72]  = (unsigned short(*)[72])(smem + 17408 + 9216);
    float (*sY)[68] = (float(*)[68])smem;
    __shared__ float slc[Q];    // lcum
    __shared__ float sldn[Q];   // lcum[s] - log(dt_s)
    __shared__ float wtot[2];

    // --- cumulative log-decay scan (threads 0..127) ---
    float lx = 0.f, l2dt = 0.f;
    if (tid < Q) {
        float dtv = dtb[(tok0 + tid) * NHEADS + h];
        l2dt = __logf(dtv);
        lx = dtv * Acoef;
        int ln = tid & 63;
        for (int off = 1; off < 64; off <<= 1) {
            float v = __shfl_up(lx, off, 64);
            if (ln >= off) lx += v;
        }
        if (ln == 63) wtot[tid >> 6] = lx;
    }
    __syncthreads();
    if (tid < Q) {
        if (tid >= 64) lx += wtot[0];
        slc[tid] = lx;
        sldn[tid] = lx - l2dt;
    }

    // --- stage X^T ---
    {
        int t = tid >> 1, ph = (tid & 1) * 32;
        const unsigned short* xr = (const unsigned short*)(xy + (tok0 + t) * D_INNER + h * HEADDIM + ph);
#pragma unroll
        for (int i = 0; i < 32; ++i) sXt[ph + i][t] = xr[i];
    }
    // --- stage init^T hi/lo ---
    {
        const float* init = states + (size_t)sid * 4096;
        for (int i = tid; i < 1024; i += 256) {
            float4 v = ((const float4*)init)[i];
            int n = i >> 4;
            int p = (i & 15) * 4;
#pragma unroll
            for (int j2 = 0; j2 < 4; ++j2) {
                float f = (&v.x)[j2];
                bf16 hi = f2b(f);
                float lo = f - b2f(hi);
                sNh[p + j2][n] = __bfloat16_as_ushort(hi);
                sNl[p + j2][n] = __bfloat16_as_ushort(f2b(lo));
            }
        }
    }
    __syncthreads();

    const int l15 = lane & 15, qq = lane >> 4;

    int tcur[2]; float lct_mi[2], elct[2];
#pragma unroll
    for (int mi = 0; mi < 2; ++mi) {
        tcur[mi] = w * 32 + mi * 16 + l15;
        lct_mi[mi] = slc[tcur[mi]];
        elct[mi] = __expf(lct_mi[mi]);
    }

    f32x4v acc[2][4];
#pragma unroll
    for (int mi = 0; mi < 2; ++mi)
#pragma unroll
        for (int ni = 0; ni < 4; ++ni)
            acc[mi][ni] = (f32x4v){0.f, 0.f, 0.f, 0.f};

    const bf16* grow = Graw + (size_t)bc * (Q * Q);

    // --- intra-chunk: K = 128 over s ---
#pragma unroll
    for (int kb = 0; kb < 4; ++kb) {
        const int s0 = kb * 32 + qq * 8;
        float4 dA = *(const float4*)(sldn + s0);
        float4 dB = *(const float4*)(sldn + s0 + 4);
        bf16x8v af[2];
#pragma unroll
        for (int mi = 0; mi < 2; ++mi) {
            int t = tcur[mi];
            float lct = lct_mi[mi];
            uint4 gv = *(const uint4*)(grow + (size_t)t * Q + s0);
            float f0 = (s0 + 0 <= t) ? bl(gv.x) * __expf(lct - dA.x) : 0.f;
            float f1 = (s0 + 1 <= t) ? bh(gv.x) * __expf(lct - dA.y) : 0.f;
            float f2 = (s0 + 2 <= t) ? bl(gv.y) * __expf(lct - dA.z) : 0.f;
            float f3 = (s0 + 3 <= t) ? bh(gv.y) * __expf(lct - dA.w) : 0.f;
            float f4 = (s0 + 4 <= t) ? bl(gv.z) * __expf(lct - dB.x) : 0.f;
            float f5 = (s0 + 5 <= t) ? bh(gv.z) * __expf(lct - dB.y) : 0.f;
            float f6 = (s0 + 6 <= t) ? bl(gv.w) * __expf(lct - dB.z) : 0.f;
            float f7 = (s0 + 7 <= t) ? bh(gv.w) * __expf(lct - dB.w) : 0.f;
            union { bf16x8v v; unsigned u[4]; } r;
            r.u[0] = pk2(f0, f1); r.u[1] = pk2(f2, f3);
            r.u[2] = pk2(f4, f5); r.u[3] = pk2(f6, f7);
            af[mi] = r.v;
        }
        bf16x8v bfr[4];
#pragma unroll
        for (int ni = 0; ni < 4; ++ni)
            bfr[ni] = *(const bf16x8v*)(&sXt[ni * 16 + l15][s0]);
#pragma unroll
        for (int mi = 0; mi < 2; ++mi)
#pragma unroll
            for (int ni = 0; ni < 4; ++ni)
                acc[mi][ni] = __builtin_amdgcn_mfma_f32_16x16x32_bf16(
                    af[mi], bfr[ni], acc[mi][ni], 0, 0, 0);
    }

    // --- state term: K = 64 over n, hi + lo ---
#pragma unroll
    for (int half = 0; half < 2; ++half) {
        const int n0 = half * 32 + qq * 8;
        bf16x8v af[2];
#pragma unroll
        for (int mi = 0; mi < 2; ++mi) {
            uint4 cv = *(const uint4*)(Cb + (tok0 + tcur[mi]) * D_STATE + n0);
            float el = elct[mi];
            union { bf16x8v v; unsigned u[4]; } r;
            r.u[0] = pk2(bl(cv.x) * el, bh(cv.x) * el);
            r.u[1] = pk2(bl(cv.y) * el, bh(cv.y) * el);
            r.u[2] = pk2(bl(cv.z) * el, bh(cv.z) * el);
            r.u[3] = pk2(bl(cv.w) * el, bh(cv.w) * el);
            af[mi] = r.v;
        }
        bf16x8v bh_[4], bl_[4];
#pragma unroll
        for (int ni = 0; ni < 4; ++ni) {
            int p = ni * 16 + l15;
            bh_[ni] = *(const bf16x8v*)(&sNh[p][n0]);
            bl_[ni] = *(const bf16x8v*)(&sNl[p][n0]);
        }
#pragma unroll
        for (int mi = 0; mi < 2; ++mi)
#pragma unroll
            for (int ni = 0; ni < 4; ++ni) {
                acc[mi][ni] = __builtin_amdgcn_mfma_f32_16x16x32_bf16(
                    af[mi], bh_[ni], acc[mi][ni], 0, 0, 0);
                acc[mi][ni] = __builtin_amdgcn_mfma_f32_16x16x32_bf16(
                    af[mi], bl_[ni], acc[mi][ni], 0, 0, 0);
            }
    }

    // --- transpose through LDS, then coalesced epilogue ---
    __syncthreads();   // done reading sXt/sNh/sNl
#pragma unroll
    for (int mi = 0; mi < 2; ++mi) {
        int r0 = w * 32 + mi * 16 + qq * 4;
#pragma unroll
        for (int ni = 0; ni < 4; ++ni) {
            int p = ni * 16 + l15;
            f32x4v v = acc[mi][ni];
#pragma unroll
            for (int jj = 0; jj < 4; ++jj) sY[r0 + jj][p] = v[jj];
        }
    }
    __syncthreads();

    {
        const float Dh = Dpa[h];
        int t = tid >> 1;
        int p0 = (tid & 1) * 32;
        size_t off = (tok0 + t) * D_INNER + h * HEADDIM + p0;
        const uint4* xrow = (const uint4*)(xy + off);
        const uint4* zrow = (const uint4*)(Zb + off);
        uint4 outv[4];
#pragma unroll
        for (int k4 = 0; k4 < 4; ++k4) {
            uint4 xv = xrow[k4];
            uint4 zv = zrow[k4];
            const float* yr = &sY[t][p0 + k4 * 8];
            float xs[8] = {bl(xv.x), bh(xv.x), bl(xv.y), bh(xv.y),
                           bl(xv.z), bh(xv.z), bl(xv.w), bh(xv.w)};
            float zs[8] = {bl(zv.x), bh(zv.x), bl(zv.y), bh(zv.y),
                           bl(zv.z), bh(zv.z), bl(zv.w), bh(zv.w)};
            unsigned o[4];
#pragma unroll
            for (int j = 0; j < 4; ++j) {
                float y0 = yr[2 * j]     + Dh * xs[2 * j];
                float y1 = yr[2 * j + 1] + Dh * xs[2 * j + 1];
                float z0 = zs[2 * j], z1 = zs[2 * j + 1];
                y0 *= z0 / (1.f + __expf(-z0));
                y1 *= z1 / (1.f + __expf(-z1));
                o[j] = pk2(y0, y1);
            }
            outv[k4].x = o[0]; outv[k4].y = o[1]; outv[k4].z = o[2]; outv[k4].w = o[3];
        }
        uint4* orow = (uint4*)(xy + off);
#pragma unroll
        for (int k4 = 0; k4 < 4; ++k4) orow[k4] = outv[k4];
    }
}

// ---------------------------------------------------------------------------
extern "C" void kernel_launch(void* const* d_in, const int* in_sizes, int n_in,
                              void* d_out, int out_size, void* d_ws, size_t ws_size,
                              hipStream_t stream) {
    (void)in_sizes; (void)n_in; (void)out_size; (void)ws_size;
    const float* u          = (const float*)d_in[0];
    const float* in_proj_w  = (const float*)d_in[1];
    const float* conv_w     = (const float*)d_in[2];
    const float* conv_b     = (const float*)d_in[3];
    const float* norm_w     = (const float*)d_in[4];
    const float* out_proj_w = (const float*)d_in[5];
    const float* A_log      = (const float*)d_in[6];
    const float* Dp         = (const float*)d_in[7];
    const float* dt_bias    = (const float*)d_in[8];

    char* w = (char*)d_ws;
    bf16*  Zb     = (bf16*)w;     w += (size_t)NTOK * D_INNER * 2;
    bf16*  XBC    = (bf16*)w;     w += (size_t)NTOK * D_CONV_IN * 2;
    bf16*  xy     = (bf16*)w;     w += (size_t)NTOK * D_INNER * 2;
    bf16*  Bb     = (bf16*)w;     w += (size_t)NTOK * D_STATE * 2;
    bf16*  Cb     = (bf16*)w;     w += (size_t)NTOK * D_STATE * 2;
    float* dtraw  = (float*)w;    w += (size_t)NTOK * NHEADS * 4;
    float* dtb    = (float*)w;    w += (size_t)NTOK * NHEADS * 4;
    float* cdecay = (float*)w;    w += (size_t)NCHB * 4;
    bf16*  wA     = (bf16*)w;     w += (size_t)ZXLD * D_MODEL * 2;
    bf16*  wO     = (bf16*)w;
    float* states = (float*)XBC;
    bf16*  Graw   = (bf16*)((char*)XBC + (size_t)NCHB * 4096 * 4);
    bf16*  uB     = xy;

    { int n = NTOK * D_MODEL;
      cvt_f32_bf16<<<(n / 4 + 255) / 256, 256, 0, stream>>>(u, (unsigned short*)uB, n); }
    { int n = ZXLD * D_MODEL;
      cvt_f32_bf16<<<(n / 4 + 255) / 256, 256, 0, stream>>>(in_proj_w, (unsigned short*)wA, n); }
    { int n = D_MODEL * D_INNER;
      cvt_f32_bf16<<<(n / 4 + 255) / 256, 256, 0, stream>>>(out_proj_w, (unsigned short*)wO, n); }

    dt_gemm<<<NTOK * NHEADS / 256, 256, 0, stream>>>(u, in_proj_w, dtraw);

    dim3 g1(ZXLD / 128, NTOK / 128);
    gemm_mfma<0><<<g1, 256, 0, stream>>>(uB, wA, D_MODEL, Zb, XBC, nullptr);

    conv_norm_v3<<<NTOK / 8, 256, 0, stream>>>(XBC, dtraw, conv_w, conv_b, norm_w, dt_bias,
                                               xy, Bb, Cb, dtb);

    score_kernel<<<NBC, 256, 0, stream>>>(Bb, Cb, Graw);
    chunk_state_mfma<<<NCHB, 256, 0, stream>>>(xy, Bb, dtb, A_log, states, cdecay);
    state_pass_kernel<<<BATCH * NHEADS, 256, 0, stream>>>(states, cdecay);
    chunk_output_mfma<<<NCHB, 256, 0, stream>>>(Zb, xy, Cb, Graw, dtb, A_log, Dp, states);

    dim3 g4(D_MODEL / 128, NTOK / 128);
    gemm_mfma<1><<<g4, 256, 0, stream>>>(xy, wO, D_INNER, nullptr, nullptr, (float*)d_out);
}

// Round 10
// 284.185 us; speedup vs baseline: 9.1169x; 1.2602x over previous
//
#include <hip/hip_runtime.h>
#include <hip/hip_bf16.h>
#include <cstddef>

#define D_MODEL   384
#define D_IN_PROJ 1676
#define D_INNER   768
#define D_CONV_IN 896
#define ZXLD      1664
#define NPROJPAD  1792          // 14 * 128
#define NHEADS    12
#define HEADDIM   64
#define D_STATE   64
#define SEQLEN    4096
#define BATCH     8
#define NTOK      (BATCH * SEQLEN)
#define EPSV      1e-5f
#define Q         128
#define NCHUNK    (SEQLEN / Q)
#define NCHB      (BATCH * NHEADS * NCHUNK)
#define NBC       (BATCH * NCHUNK)

typedef __hip_bfloat16 bf16;
typedef __attribute__((ext_vector_type(8))) short bf16x8v;
typedef __attribute__((ext_vector_type(4))) float f32x4v;

__device__ __forceinline__ float b2f(bf16 v) { return __bfloat162float(v); }
__device__ __forceinline__ bf16  f2b(float v) { return __float2bfloat16(v); }
__device__ __forceinline__ float bl(unsigned u)  { return __uint_as_float(u << 16); }
__device__ __forceinline__ float bh(unsigned u)  { return __uint_as_float(u & 0xffff0000u); }
__device__ __forceinline__ float bu(unsigned short v) { return __uint_as_float(((unsigned)v) << 16); }
__device__ __forceinline__ unsigned pk2(float a, float b) {
    return ((unsigned)__bfloat16_as_ushort(f2b(b)) << 16) | (unsigned)__bfloat16_as_ushort(f2b(a));
}
__device__ __forceinline__ int swzf(int r) { return (r ^ (r >> 2)) & 3; }
__device__ __forceinline__ int tswz(int r, int col) {
    return r * 128 + ((((col >> 3) ^ (r & 7)) << 3) | (col & 7));
}

#define GL_LDS16(g, l) __builtin_amdgcn_global_load_lds( \
    (const __attribute__((address_space(1))) unsigned*)(g), \
    (__attribute__((address_space(3))) unsigned*)(l), 16, 0, 0)

// ---------------------------------------------------------------------------
__global__ __launch_bounds__(256)
void cvt_f32_bf16(const float* __restrict__ in, unsigned short* __restrict__ out, int n) {
    int i = (blockIdx.x * 256 + threadIdx.x) * 4;
    if (i + 3 < n) {
        float4 v = *(const float4*)(in + i);
        uint2 o; o.x = pk2(v.x, v.y); o.y = pk2(v.z, v.w);
        *(uint2*)(out + i) = o;
    }
}

// cvt with zero-pad: out[i] = i < n_real ? bf16(in[i]) : 0   (n_real % 4 == 0)
__global__ __launch_bounds__(256)
void cvt_pad(const float* __restrict__ in, unsigned short* __restrict__ out,
             int n_real, int n_pad) {
    int i = (blockIdx.x * 256 + threadIdx.x) * 4;
    if (i + 3 < n_pad) {
        uint2 o;
        if (i < n_real) {
            float4 v = *(const float4*)(in + i);
            o.x = pk2(v.x, v.y); o.y = pk2(v.z, v.w);
        } else {
            o.x = 0u; o.y = 0u;
        }
        *(uint2*)(out + i) = o;
    }
}

// ---------------------------------------------------------------------------
// MFMA GEMM-NT. EPI 0: cols<768 -> Z bf16; <1664 -> XBC bf16; <1676 -> dtraw f32.
// EPI 1: f32 out stride D_MODEL.
// ---------------------------------------------------------------------------
template<int EPI>
__global__ __launch_bounds__(256)
void gemm_mfma(const bf16* __restrict__ A, const bf16* __restrict__ Bw, int K,
               bf16* __restrict__ Zo, bf16* __restrict__ XBCo,
               float* __restrict__ Do, float* __restrict__ Co) {
    __shared__ short As[128 * 32];
    __shared__ short Bs[128 * 32];
    const int tid = threadIdx.x;
    const int lane = tid & 63;
    const int w = tid >> 6;
    const int wr = w >> 1, wc = w & 1;
    const int bm = blockIdx.y * 128;
    const int bn = blockIdx.x * 128;

    f32x4v acc[4][4];
#pragma unroll
    for (int mi = 0; mi < 4; ++mi)
#pragma unroll
        for (int ni = 0; ni < 4; ++ni)
            acc[mi][ni] = (f32x4v){0.f, 0.f, 0.f, 0.f};

    size_t aoff[2]; size_t boff[2];
#pragma unroll
    for (int q = 0; q < 2; ++q) {
        int o = q * 4096 + tid * 16;
        int row = o >> 6;
        int ps = (o >> 4) & 3;
        int sl = ps ^ swzf(row);
        aoff[q] = (size_t)(bm + row) * K + sl * 8;
        boff[q] = (size_t)(bn + row) * K + sl * 8;
    }
    short* adst0 = As + tid * 8;          short* adst1 = As + 2048 + tid * 8;
    short* bdst0 = Bs + tid * 8;          short* bdst1 = Bs + 2048 + tid * 8;

    int aidx[4], bidx[4];
#pragma unroll
    for (int i = 0; i < 4; ++i) {
        int ra = wr * 64 + i * 16 + (lane & 15);
        int rb = wc * 64 + i * 16 + (lane & 15);
        aidx[i] = ra * 32 + (((lane >> 4) ^ swzf(ra)) * 8);
        bidx[i] = rb * 32 + (((lane >> 4) ^ swzf(rb)) * 8);
    }

    for (int k0 = 0; k0 < K; k0 += 32) {
        __syncthreads();
        GL_LDS16(A + aoff[0] + k0, adst0);
        GL_LDS16(A + aoff[1] + k0, adst1);
        GL_LDS16(Bw + boff[0] + k0, bdst0);
        GL_LDS16(Bw + boff[1] + k0, bdst1);
        __syncthreads();

        bf16x8v af[4], bf[4];
#pragma unroll
        for (int i = 0; i < 4; ++i) {
            af[i] = *(const bf16x8v*)(As + aidx[i]);
            bf[i] = *(const bf16x8v*)(Bs + bidx[i]);
        }
#pragma unroll
        for (int mi = 0; mi < 4; ++mi)
#pragma unroll
            for (int ni = 0; ni < 4; ++ni)
                acc[mi][ni] = __builtin_amdgcn_mfma_f32_16x16x32_bf16(
                    af[mi], bf[ni], acc[mi][ni], 0, 0, 0);
    }

    const int l15 = lane & 15, l4 = lane >> 4;
#pragma unroll
    for (int mi = 0; mi < 4; ++mi) {
        int rbase = bm + wr * 64 + mi * 16 + l4 * 4;
#pragma unroll
        for (int ni = 0; ni < 4; ++ni) {
            int col = bn + wc * 64 + ni * 16 + l15;
            f32x4v v = acc[mi][ni];
            if (EPI == 0) {
                if (col < D_INNER) {
#pragma unroll
                    for (int j = 0; j < 4; ++j)
                        Zo[(size_t)(rbase + j) * D_INNER + col] = f2b(v[j]);
                } else if (col < ZXLD) {
#pragma unroll
                    for (int j = 0; j < 4; ++j)
                        XBCo[(size_t)(rbase + j) * D_CONV_IN + (col - D_INNER)] = f2b(v[j]);
                } else if (col < D_IN_PROJ) {
#pragma unroll
                    for (int j = 0; j < 4; ++j)
                        Do[(size_t)(rbase + j) * NHEADS + (col - ZXLD)] = v[j];
                }
            } else {
#pragma unroll
                for (int j = 0; j < 4; ++j)
                    Co[(size_t)(rbase + j) * D_MODEL + col] = v[j];
            }
        }
    }
}

// ---------------------------------------------------------------------------
// K2 v3 (unchanged)
// ---------------------------------------------------------------------------
__global__ __launch_bounds__(256)
void conv_norm_v3(const bf16* __restrict__ XBC, const float* __restrict__ dtraw,
                  const float* __restrict__ conv_w, const float* __restrict__ conv_b,
                  const float* __restrict__ norm_w, const float* __restrict__ dt_bias,
                  bf16* __restrict__ xn, bf16* __restrict__ Bb,
                  bf16* __restrict__ Cb, float* __restrict__ dtb) {
    const int tid = threadIdx.x;
    const int t0 = blockIdx.x * 8;
    const int l0 = t0 & (SEQLEN - 1);

    __shared__ float sp[8][200];
    __shared__ float sq[8][8];
    __shared__ float sscale[8];

    const int c = tid;
    const bool active = (c < 224);
    const int ch0 = c * 4;

    float acc[8][4];
    float w0[4], w1[4], w2[4], w3[4];

    if (active) {
        float4 wa = *(const float4*)(conv_w + (ch0 + 0) * 4);
        float4 wb = *(const float4*)(conv_w + (ch0 + 1) * 4);
        float4 wcc = *(const float4*)(conv_w + (ch0 + 2) * 4);
        float4 wd = *(const float4*)(conv_w + (ch0 + 3) * 4);
        w0[0] = wa.x; w1[0] = wa.y; w2[0] = wa.z; w3[0] = wa.w;
        w0[1] = wb.x; w1[1] = wb.y; w2[1] = wb.z; w3[1] = wb.w;
        w0[2] = wcc.x; w1[2] = wcc.y; w2[2] = wcc.z; w3[2] = wcc.w;
        w0[3] = wd.x; w1[3] = wd.y; w2[3] = wd.z; w3[3] = wd.w;
        float4 bv = *(const float4*)(conv_b + ch0);
#pragma unroll
        for (int t = 0; t < 8; ++t) {
            acc[t][0] = bv.x; acc[t][1] = bv.y; acc[t][2] = bv.z; acc[t][3] = bv.w;
        }
#pragma unroll
        for (int ri = 0; ri < 11; ++ri) {
            int lr = l0 - 3 + ri;
            if (lr >= 0) {
                uint2 rv = *(const uint2*)((const unsigned short*)XBC
                              + (size_t)(t0 - 3 + ri) * D_CONV_IN + ch0);
                float r0 = bl(rv.x), r1 = bh(rv.x), r2 = bl(rv.y), r3 = bh(rv.y);
#pragma unroll
                for (int t = 0; t < 8; ++t) {
                    if (t >= ri - 3 && t <= ri) {
                        const int j = ri - t;
                        const float* wj = (j == 0) ? w0 : (j == 1) ? w1 : (j == 2) ? w2 : w3;
                        acc[t][0] += r0 * wj[0];
                        acc[t][1] += r1 * wj[1];
                        acc[t][2] += r2 * wj[2];
                        acc[t][3] += r3 * wj[3];
                    }
                }
            }
        }
#pragma unroll
        for (int t = 0; t < 8; ++t) {
            float ss = 0.f;
#pragma unroll
            for (int i = 0; i < 4; ++i) {
                float v = acc[t][i];
                float s = v / (1.f + __expf(-v));
                acc[t][i] = s;
                ss += s * s;
            }
            if (c < 192) sp[t][c] = ss;
        }
    }
    __syncthreads();
    if (tid < 64) {
        int t = tid >> 3, i = tid & 7;
        float s = 0.f;
#pragma unroll
        for (int k = 0; k < 24; ++k) s += sp[t][i * 24 + k];
        sq[t][i] = s;
    }
    __syncthreads();
    if (tid < 8) {
        float tot = 0.f;
#pragma unroll
        for (int i = 0; i < 8; ++i) tot += sq[tid][i];
        sscale[tid] = rsqrtf(tot / (float)D_INNER + EPSV);
    }
    __syncthreads();

    if (c < 192) {
        float4 nv = *(const float4*)(norm_w + ch0);
#pragma unroll
        for (int t = 0; t < 8; ++t) {
            float sc = sscale[t];
            uint2 o;
            o.x = pk2(acc[t][0] * sc * nv.x, acc[t][1] * sc * nv.y);
            o.y = pk2(acc[t][2] * sc * nv.z, acc[t][3] * sc * nv.w);
            *(uint2*)(xn + (size_t)(t0 + t) * D_INNER + ch0) = o;
        }
    } else if (c < 224) {
        const int idx = ch0 - 768;
#pragma unroll
        for (int t = 0; t < 8; ++t) {
            uint2 o;
            o.x = pk2(acc[t][0], acc[t][1]);
            o.y = pk2(acc[t][2], acc[t][3]);
            bf16* base = (idx < 64) ? (Bb + (size_t)(t0 + t) * D_STATE + idx)
                                    : (Cb + (size_t)(t0 + t) * D_STATE + (idx - 64));
            *(uint2*)base = o;
        }
    }
    if (tid < 96) {
        int t = tid / 12, hh = tid % 12;
        float v = dtraw[(size_t)(t0 + t) * NHEADS + hh] + dt_bias[hh];
        float spv = (v > 20.f) ? v : log1pf(expf(v));
        dtb[(size_t)(t0 + t) * NHEADS + hh] = spv;
    }
}

// ---------------------------------------------------------------------------
// Score kernel (unchanged)
// ---------------------------------------------------------------------------
__global__ __launch_bounds__(256)
void score_kernel(const bf16* __restrict__ Bb, const bf16* __restrict__ Cb,
                  bf16* __restrict__ Graw) {
    const int bc = blockIdx.x;
    const size_t tok0 = (size_t)bc * Q;
    const int tid = threadIdx.x;
    const int lane = tid & 63, w = tid >> 6;
    const int wr = w >> 1, wc = w & 1;
    __shared__ short sC[Q * 64];
    __shared__ short sB[Q * 64];

#pragma unroll
    for (int it = 0; it < 4; ++it) {
        int j = it * 256 + tid;
        int r = j >> 3, sp = j & 7;
        int sl = sp ^ (r & 7);
        GL_LDS16(Cb + tok0 * D_STATE + r * 64 + sl * 8, sC + j * 8);
        GL_LDS16(Bb + tok0 * D_STATE + r * 64 + sl * 8, sB + j * 8);
    }
    __syncthreads();

    const int l15 = lane & 15, qq = lane >> 4;
    f32x4v acc[4][4];
#pragma unroll
    for (int mi = 0; mi < 4; ++mi)
#pragma unroll
        for (int ni = 0; ni < 4; ++ni)
            acc[mi][ni] = (f32x4v){0.f, 0.f, 0.f, 0.f};

#pragma unroll
    for (int kb = 0; kb < 2; ++kb) {
        bf16x8v af[4], bf[4];
#pragma unroll
        for (int i = 0; i < 4; ++i) {
            int ra = wr * 64 + i * 16 + l15;
            int rb = wc * 64 + i * 16 + l15;
            af[i] = *(const bf16x8v*)(sC + ra * 64 + ((kb * 4 + qq) ^ (ra & 7)) * 8);
            bf[i] = *(const bf16x8v*)(sB + rb * 64 + ((kb * 4 + qq) ^ (rb & 7)) * 8);
        }
#pragma unroll
        for (int mi = 0; mi < 4; ++mi)
#pragma unroll
            for (int ni = 0; ni < 4; ++ni)
                acc[mi][ni] = __builtin_amdgcn_mfma_f32_16x16x32_bf16(
                    af[mi], bf[ni], acc[mi][ni], 0, 0, 0);
    }

    bf16* gout = Graw + (size_t)bc * (Q * Q);
#pragma unroll
    for (int mi = 0; mi < 4; ++mi) {
        int t0 = wr * 64 + mi * 16 + qq * 4;
#pragma unroll
        for (int ni = 0; ni < 4; ++ni) {
            int s = wc * 64 + ni * 16 + l15;
            f32x4v v = acc[mi][ni];
#pragma unroll
            for (int j = 0; j < 4; ++j)
                gout[(size_t)(t0 + j) * Q + s] = f2b(v[j]);
        }
    }
}

// ---------------------------------------------------------------------------
// K3a (MFMA) (unchanged)
// ---------------------------------------------------------------------------
__global__ __launch_bounds__(256)
void chunk_state_mfma(const bf16* __restrict__ xy, const bf16* __restrict__ Bb,
                      const float* __restrict__ dtb, const float* __restrict__ A_log,
                      float* __restrict__ states, float* __restrict__ cdecay) {
    const int sid = blockIdx.x;
    const int c = sid % NCHUNK;
    const int h = (sid / NCHUNK) % NHEADS;
    const int b = sid / (NCHUNK * NHEADS);
    const int tid = threadIdx.x;
    const int lane = tid & 63, w = tid >> 6;
    const size_t tok0 = (size_t)b * SEQLEN + (size_t)c * Q;
    const float Acoef = -expf(A_log[h]);

    __shared__ __align__(16) unsigned short sBT[64 * 128];
    __shared__ __align__(16) unsigned short sXT[64 * 128];
    __shared__ float slcum[Q];
    __shared__ float sdt[Q];
    __shared__ float wtot[2];

    float lx = 0.f;
    if (tid < Q) {
        float dtv = dtb[(tok0 + tid) * NHEADS + h];
        sdt[tid] = dtv;
        lx = dtv * Acoef;
        int ln = tid & 63;
        for (int off = 1; off < 64; off <<= 1) {
            float v = __shfl_up(lx, off, 64);
            if (ln >= off) lx += v;
        }
        if (ln == 63) wtot[tid >> 6] = lx;
    }
    __syncthreads();
    if (tid < Q) {
        if (tid >= 64) lx += wtot[0];
        slcum[tid] = lx;
    }
    __syncthreads();
    const float ltot = slcum[Q - 1];

    {
        int t = tid >> 1, half = tid & 1;
        float s_t = sdt[t] * __expf(ltot - slcum[t]);
        const unsigned short* br = (const unsigned short*)(Bb + (tok0 + t) * D_STATE) + half * 32;
        const unsigned short* xr = (const unsigned short*)(xy + (tok0 + t) * D_INNER + h * HEADDIM) + half * 32;
#pragma unroll
        for (int i = 0; i < 32; ++i) {
            int r = half * 32 + i;
            sBT[tswz(r, t)] = __bfloat16_as_ushort(f2b(bu(br[i]) * s_t));
            sXT[tswz(r, t)] = xr[i];
        }
    }
    __syncthreads();

    const int l15 = lane & 15, qq = lane >> 4;
    f32x4v acc[4];
#pragma unroll
    for (int ni = 0; ni < 4; ++ni) acc[ni] = (f32x4v){0.f, 0.f, 0.f, 0.f};

#pragma unroll
    for (int kb = 0; kb < 4; ++kb) {
        const int col = kb * 32 + qq * 8;
        bf16x8v af = *(const bf16x8v*)(&sBT[tswz(w * 16 + l15, col)]);
#pragma unroll
        for (int ni = 0; ni < 4; ++ni) {
            bf16x8v bx = *(const bf16x8v*)(&sXT[tswz(ni * 16 + l15, col)]);
            acc[ni] = __builtin_amdgcn_mfma_f32_16x16x32_bf16(af, bx, acc[ni], 0, 0, 0);
        }
    }

    float* out = states + (size_t)sid * 4096;
#pragma unroll
    for (int ni = 0; ni < 4; ++ni) {
#pragma unroll
        for (int j = 0; j < 4; ++j) {
            int n = w * 16 + qq * 4 + j;
            int p = ni * 16 + l15;
            out[n * 64 + p] = acc[ni][j];
        }
    }
    if (tid == 0) cdecay[sid] = expf(ltot);
}

// ---------------------------------------------------------------------------
// K3b (unchanged)
// ---------------------------------------------------------------------------
__global__ __launch_bounds__(256)
void state_pass_kernel(float* __restrict__ states, const float* __restrict__ cdecay) {
    const int bh = blockIdx.x;
    const int tid = threadIdx.x;
    float run[16];
#pragma unroll
    for (int i = 0; i < 16; ++i) run[i] = 0.f;
    float* base = states + (size_t)bh * NCHUNK * 4096 + tid * 16;
    const float* cd = cdecay + bh * NCHUNK;
    for (int c = 0; c < NCHUNK; ++c) {
        float dec = cd[c];
        float* ptr = base + (size_t)c * 4096;
        float4 s0 = *(float4*)(ptr + 0);
        float4 s1 = *(float4*)(ptr + 4);
        float4 s2 = *(float4*)(ptr + 8);
        float4 s3 = *(float4*)(ptr + 12);
        float nr[16];
        nr[0] = dec * run[0] + s0.x;  nr[1] = dec * run[1] + s0.y;
        nr[2] = dec * run[2] + s0.z;  nr[3] = dec * run[3] + s0.w;
        nr[4] = dec * run[4] + s1.x;  nr[5] = dec * run[5] + s1.y;
        nr[6] = dec * run[6] + s1.z;  nr[7] = dec * run[7] + s1.w;
        nr[8] = dec * run[8] + s2.x;  nr[9] = dec * run[9] + s2.y;
        nr[10] = dec * run[10] + s2.z; nr[11] = dec * run[11] + s2.w;
        nr[12] = dec * run[12] + s3.x; nr[13] = dec * run[13] + s3.y;
        nr[14] = dec * run[14] + s3.z; nr[15] = dec * run[15] + s3.w;
        *(float4*)(ptr + 0)  = make_float4(run[0], run[1], run[2], run[3]);
        *(float4*)(ptr + 4)  = make_float4(run[4], run[5], run[6], run[7]);
        *(float4*)(ptr + 8)  = make_float4(run[8], run[9], run[10], run[11]);
        *(float4*)(ptr + 12) = make_float4(run[12], run[13], run[14], run[15]);
#pragma unroll
        for (int i = 0; i < 16; ++i) run[i] = nr[i];
    }
}

// ---------------------------------------------------------------------------
// K3c v2 (MFMA) (unchanged)
// ---------------------------------------------------------------------------
__global__ __launch_bounds__(256)
void chunk_output_mfma(const bf16* __restrict__ Zb, bf16* __restrict__ xy,
                       const bf16* __restrict__ Cb, const bf16* __restrict__ Graw,
                       const float* __restrict__ dtb, const float* __restrict__ A_log,
                       const float* __restrict__ Dpa, const float* __restrict__ states) {
    const int sid = blockIdx.x;
    const int c = sid % NCHUNK;
    const int h = (sid / NCHUNK) % NHEADS;
    const int b = sid / (NCHUNK * NHEADS);
    const int tid = threadIdx.x;
    const int lane = tid & 63, w = tid >> 6;
    const size_t tok0 = (size_t)b * SEQLEN + (size_t)c * Q;
    const int bc = b * NCHUNK + c;
    const float Acoef = -expf(A_log[h]);

    __shared__ __align__(16) char smem[35840];
    unsigned short (*sXt)[136] = (unsigned short(*)[136])smem;
    unsigned short (*sNh)[72]  = (unsigned short(*)[72])(smem + 17408);
    unsigned short (*sNl)[72]  = (unsigned short(*)[72])(smem + 17408 + 9216);
    float (*sY)[68] = (float(*)[68])smem;
    __shared__ float slc[Q];
    __shared__ float sldn[Q];
    __shared__ float wtot[2];

    float lx = 0.f, l2dt = 0.f;
    if (tid < Q) {
        float dtv = dtb[(tok0 + tid) * NHEADS + h];
        l2dt = __logf(dtv);
        lx = dtv * Acoef;
        int ln = tid & 63;
        for (int off = 1; off < 64; off <<= 1) {
            float v = __shfl_up(lx, off, 64);
            if (ln >= off) lx += v;
        }
        if (ln == 63) wtot[tid >> 6] = lx;
    }
    __syncthreads();
    if (tid < Q) {
        if (tid >= 64) lx += wtot[0];
        slc[tid] = lx;
        sldn[tid] = lx - l2dt;
    }

    {
        int t = tid >> 1, ph = (tid & 1) * 32;
        const unsigned short* xr = (const unsigned short*)(xy + (tok0 + t) * D_INNER + h * HEADDIM + ph);
#pragma unroll
        for (int i = 0; i < 32; ++i) sXt[ph + i][t] = xr[i];
    }
    {
        const float* init = states + (size_t)sid * 4096;
        for (int i = tid; i < 1024; i += 256) {
            float4 v = ((const float4*)init)[i];
            int n = i >> 4;
            int p = (i & 15) * 4;
#pragma unroll
            for (int j2 = 0; j2 < 4; ++j2) {
                float f = (&v.x)[j2];
                bf16 hi = f2b(f);
                float lo = f - b2f(hi);
                sNh[p + j2][n] = __bfloat16_as_ushort(hi);
                sNl[p + j2][n] = __bfloat16_as_ushort(f2b(lo));
            }
        }
    }
    __syncthreads();

    const int l15 = lane & 15, qq = lane >> 4;

    int tcur[2]; float lct_mi[2], elct[2];
#pragma unroll
    for (int mi = 0; mi < 2; ++mi) {
        tcur[mi] = w * 32 + mi * 16 + l15;
        lct_mi[mi] = slc[tcur[mi]];
        elct[mi] = __expf(lct_mi[mi]);
    }

    f32x4v acc[2][4];
#pragma unroll
    for (int mi = 0; mi < 2; ++mi)
#pragma unroll
        for (int ni = 0; ni < 4; ++ni)
            acc[mi][ni] = (f32x4v){0.f, 0.f, 0.f, 0.f};

    const bf16* grow = Graw + (size_t)bc * (Q * Q);

#pragma unroll
    for (int kb = 0; kb < 4; ++kb) {
        const int s0 = kb * 32 + qq * 8;
        float4 dA = *(const float4*)(sldn + s0);
        float4 dB = *(const float4*)(sldn + s0 + 4);
        bf16x8v af[2];
#pragma unroll
        for (int mi = 0; mi < 2; ++mi) {
            int t = tcur[mi];
            float lct = lct_mi[mi];
            uint4 gv = *(const uint4*)(grow + (size_t)t * Q + s0);
            float f0 = (s0 + 0 <= t) ? bl(gv.x) * __expf(lct - dA.x) : 0.f;
            float f1 = (s0 + 1 <= t) ? bh(gv.x) * __expf(lct - dA.y) : 0.f;
            float f2 = (s0 + 2 <= t) ? bl(gv.y) * __expf(lct - dA.z) : 0.f;
            float f3 = (s0 + 3 <= t) ? bh(gv.y) * __expf(lct - dA.w) : 0.f;
            float f4 = (s0 + 4 <= t) ? bl(gv.z) * __expf(lct - dB.x) : 0.f;
            float f5 = (s0 + 5 <= t) ? bh(gv.z) * __expf(lct - dB.y) : 0.f;
            float f6 = (s0 + 6 <= t) ? bl(gv.w) * __expf(lct - dB.z) : 0.f;
            float f7 = (s0 + 7 <= t) ? bh(gv.w) * __expf(lct - dB.w) : 0.f;
            union { bf16x8v v; unsigned u[4]; } r;
            r.u[0] = pk2(f0, f1); r.u[1] = pk2(f2, f3);
            r.u[2] = pk2(f4, f5); r.u[3] = pk2(f6, f7);
            af[mi] = r.v;
        }
        bf16x8v bfr[4];
#pragma unroll
        for (int ni = 0; ni < 4; ++ni)
            bfr[ni] = *(const bf16x8v*)(&sXt[ni * 16 + l15][s0]);
#pragma unroll
        for (int mi = 0; mi < 2; ++mi)
#pragma unroll
            for (int ni = 0; ni < 4; ++ni)
                acc[mi][ni] = __builtin_amdgcn_mfma_f32_16x16x32_bf16(
                    af[mi], bfr[ni], acc[mi][ni], 0, 0, 0);
    }

#pragma unroll
    for (int half = 0; half < 2; ++half) {
        const int n0 = half * 32 + qq * 8;
        bf16x8v af[2];
#pragma unroll
        for (int mi = 0; mi < 2; ++mi) {
            uint4 cv = *(const uint4*)(Cb + (tok0 + tcur[mi]) * D_STATE + n0);
            float el = elct[mi];
            union { bf16x8v v; unsigned u[4]; } r;
            r.u[0] = pk2(bl(cv.x) * el, bh(cv.x) * el);
            r.u[1] = pk2(bl(cv.y) * el, bh(cv.y) * el);
            r.u[2] = pk2(bl(cv.z) * el, bh(cv.z) * el);
            r.u[3] = pk2(bl(cv.w) * el, bh(cv.w) * el);
            af[mi] = r.v;
        }
        bf16x8v bh_[4], bl_[4];
#pragma unroll
        for (int ni = 0; ni < 4; ++ni) {
            int p = ni * 16 + l15;
            bh_[ni] = *(const bf16x8v*)(&sNh[p][n0]);
            bl_[ni] = *(const bf16x8v*)(&sNl[p][n0]);
        }
#pragma unroll
        for (int mi = 0; mi < 2; ++mi)
#pragma unroll
            for (int ni = 0; ni < 4; ++ni) {
                acc[mi][ni] = __builtin_amdgcn_mfma_f32_16x16x32_bf16(
                    af[mi], bh_[ni], acc[mi][ni], 0, 0, 0);
                acc[mi][ni] = __builtin_amdgcn_mfma_f32_16x16x32_bf16(
                    af[mi], bl_[ni], acc[mi][ni], 0, 0, 0);
            }
    }

    __syncthreads();
#pragma unroll
    for (int mi = 0; mi < 2; ++mi) {
        int r0 = w * 32 + mi * 16 + qq * 4;
#pragma unroll
        for (int ni = 0; ni < 4; ++ni) {
            int p = ni * 16 + l15;
            f32x4v v = acc[mi][ni];
#pragma unroll
            for (int jj = 0; jj < 4; ++jj) sY[r0 + jj][p] = v[jj];
        }
    }
    __syncthreads();

    {
        const float Dh = Dpa[h];
        int t = tid >> 1;
        int p0 = (tid & 1) * 32;
        size_t off = (tok0 + t) * D_INNER + h * HEADDIM + p0;
        const uint4* xrow = (const uint4*)(xy + off);
        const uint4* zrow = (const uint4*)(Zb + off);
        uint4 outv[4];
#pragma unroll
        for (int k4 = 0; k4 < 4; ++k4) {
            uint4 xv = xrow[k4];
            uint4 zv = zrow[k4];
            const float* yr = &sY[t][p0 + k4 * 8];
            float xs[8] = {bl(xv.x), bh(xv.x), bl(xv.y), bh(xv.y),
                           bl(xv.z), bh(xv.z), bl(xv.w), bh(xv.w)};
            float zs[8] = {bl(zv.x), bh(zv.x), bl(zv.y), bh(zv.y),
                           bl(zv.z), bh(zv.z), bl(zv.w), bh(zv.w)};
            unsigned o[4];
#pragma unroll
            for (int j = 0; j < 4; ++j) {
                float y0 = yr[2 * j]     + Dh * xs[2 * j];
                float y1 = yr[2 * j + 1] + Dh * xs[2 * j + 1];
                float z0 = zs[2 * j], z1 = zs[2 * j + 1];
                y0 *= z0 / (1.f + __expf(-z0));
                y1 *= z1 / (1.f + __expf(-z1));
                o[j] = pk2(y0, y1);
            }
            outv[k4].x = o[0]; outv[k4].y = o[1]; outv[k4].z = o[2]; outv[k4].w = o[3];
        }
        uint4* orow = (uint4*)(xy + off);
#pragma unroll
        for (int k4 = 0; k4 < 4; ++k4) orow[k4] = outv[k4];
    }
}

// ---------------------------------------------------------------------------
extern "C" void kernel_launch(void* const* d_in, const int* in_sizes, int n_in,
                              void* d_out, int out_size, void* d_ws, size_t ws_size,
                              hipStream_t stream) {
    (void)in_sizes; (void)n_in; (void)out_size; (void)ws_size;
    const float* u          = (const float*)d_in[0];
    const float* in_proj_w  = (const float*)d_in[1];
    const float* conv_w     = (const float*)d_in[2];
    const float* conv_b     = (const float*)d_in[3];
    const float* norm_w     = (const float*)d_in[4];
    const float* out_proj_w = (const float*)d_in[5];
    const float* A_log      = (const float*)d_in[6];
    const float* Dp         = (const float*)d_in[7];
    const float* dt_bias    = (const float*)d_in[8];

    char* w = (char*)d_ws;
    bf16*  Zb     = (bf16*)w;     w += (size_t)NTOK * D_INNER * 2;
    bf16*  XBC    = (bf16*)w;     w += (size_t)NTOK * D_CONV_IN * 2;
    bf16*  xy     = (bf16*)w;     w += (size_t)NTOK * D_INNER * 2;
    bf16*  Bb     = (bf16*)w;     w += (size_t)NTOK * D_STATE * 2;
    bf16*  Cb     = (bf16*)w;     w += (size_t)NTOK * D_STATE * 2;
    float* dtraw  = (float*)w;    w += (size_t)NTOK * NHEADS * 4;
    float* dtb    = (float*)w;    w += (size_t)NTOK * NHEADS * 4;
    float* cdecay = (float*)w;    w += (size_t)NCHB * 4;
    bf16*  wA     = (bf16*)w;     w += (size_t)NPROJPAD * D_MODEL * 2;
    bf16*  wO     = (bf16*)w;
    float* states = (float*)XBC;
    bf16*  Graw   = (bf16*)((char*)XBC + (size_t)NCHB * 4096 * 4);
    bf16*  uB     = xy;

    { int n = NTOK * D_MODEL;
      cvt_f32_bf16<<<(n / 4 + 255) / 256, 256, 0, stream>>>(u, (unsigned short*)uB, n); }
    { int nr = D_IN_PROJ * D_MODEL, np = NPROJPAD * D_MODEL;
      cvt_pad<<<(np / 4 + 255) / 256, 256, 0, stream>>>(in_proj_w, (unsigned short*)wA, nr, np); }
    { int n = D_MODEL * D_INNER;
      cvt_f32_bf16<<<(n / 4 + 255) / 256, 256, 0, stream>>>(out_proj_w, (unsigned short*)wO, n); }

    dim3 g1(NPROJPAD / 128, NTOK / 128);
    gemm_mfma<0><<<g1, 256, 0, stream>>>(uB, wA, D_MODEL, Zb, XBC, dtraw, nullptr);

    conv_norm_v3<<<NTOK / 8, 256, 0, stream>>>(XBC, dtraw, conv_w, conv_b, norm_w, dt_bias,
                                               xy, Bb, Cb, dtb);

    score_kernel<<<NBC, 256, 0, stream>>>(Bb, Cb, Graw);
    chunk_state_mfma<<<NCHB, 256, 0, stream>>>(xy, Bb, dtb, A_log, states, cdecay);
    state_pass_kernel<<<BATCH * NHEADS, 256, 0, stream>>>(states, cdecay);
    chunk_output_mfma<<<NCHB, 256, 0, stream>>>(Zb, xy, Cb, Graw, dtb, A_log, Dp, states);

    dim3 g4(D_MODEL / 128, NTOK / 128);
    gemm_mfma<1><<<g4, 256, 0, stream>>>(xy, wO, D_INNER, nullptr, nullptr, nullptr, (float*)d_out);
}

// Round 11
// 272.916 us; speedup vs baseline: 9.4934x; 1.0413x over previous
//
#include <hip/hip_runtime.h>
#include <hip/hip_bf16.h>
#include <cstddef>

#define D_MODEL   384
#define D_IN_PROJ 1676
#define D_INNER   768
#define D_CONV_IN 896
#define ZXLD      1664
#define NPROJPAD  1792          // 14 * 128
#define NHEADS    12
#define HEADDIM   64
#define D_STATE   64
#define SEQLEN    4096
#define BATCH     8
#define NTOK      (BATCH * SEQLEN)
#define EPSV      1e-5f
#define Q         128
#define NCHUNK    (SEQLEN / Q)
#define NCHB      (BATCH * NHEADS * NCHUNK)
#define NBC       (BATCH * NCHUNK)

typedef __hip_bfloat16 bf16;
typedef __attribute__((ext_vector_type(8))) short bf16x8v;
typedef __attribute__((ext_vector_type(4))) float f32x4v;

__device__ __forceinline__ float b2f(bf16 v) { return __bfloat162float(v); }
__device__ __forceinline__ bf16  f2b(float v) { return __float2bfloat16(v); }
__device__ __forceinline__ float bl(unsigned u)  { return __uint_as_float(u << 16); }
__device__ __forceinline__ float bh(unsigned u)  { return __uint_as_float(u & 0xffff0000u); }
__device__ __forceinline__ float bu(unsigned short v) { return __uint_as_float(((unsigned)v) << 16); }
__device__ __forceinline__ unsigned pk2(float a, float b) {
    return ((unsigned)__bfloat16_as_ushort(f2b(b)) << 16) | (unsigned)__bfloat16_as_ushort(f2b(a));
}
__device__ __forceinline__ int tswz(int r, int col) {
    return r * 128 + ((((col >> 3) ^ (r & 7)) << 3) | (col & 7));
}

#define GL_LDS16(g, l) __builtin_amdgcn_global_load_lds( \
    (const __attribute__((address_space(1))) unsigned*)(g), \
    (__attribute__((address_space(3))) unsigned*)(l), 16, 0, 0)

// ---------------------------------------------------------------------------
__global__ __launch_bounds__(256)
void cvt_f32_bf16(const float* __restrict__ in, unsigned short* __restrict__ out, int n) {
    int i = (blockIdx.x * 256 + threadIdx.x) * 4;
    if (i + 3 < n) {
        float4 v = *(const float4*)(in + i);
        uint2 o; o.x = pk2(v.x, v.y); o.y = pk2(v.z, v.w);
        *(uint2*)(out + i) = o;
    }
}

__global__ __launch_bounds__(256)
void cvt_pad(const float* __restrict__ in, unsigned short* __restrict__ out,
             int n_real, int n_pad) {
    int i = (blockIdx.x * 256 + threadIdx.x) * 4;
    if (i + 3 < n_pad) {
        uint2 o;
        if (i < n_real) {
            float4 v = *(const float4*)(in + i);
            o.x = pk2(v.x, v.y); o.y = pk2(v.z, v.w);
        } else {
            o.x = 0u; o.y = 0u;
        }
        *(uint2*)(out + i) = o;
    }
}

// ---------------------------------------------------------------------------
// MFMA GEMM-NT, BK=64, XCD-aware bijective block remap (panel-contiguous).
// 1D grid of NX * 256 blocks; xcd = id&7 owns row-panels {xcd, xcd+8, ...}.
// EPI 0: cols<768 -> Z bf16; <1664 -> XBC bf16; <1676 -> dtraw f32.
// EPI 1: f32 out stride D_MODEL.
// ---------------------------------------------------------------------------
template<int EPI, int NX>
__global__ __launch_bounds__(256)
void gemm_mfma(const bf16* __restrict__ A, const bf16* __restrict__ Bw, int K,
               bf16* __restrict__ Zo, bf16* __restrict__ XBCo,
               float* __restrict__ Do, float* __restrict__ Co) {
    __shared__ short As[128 * 64];
    __shared__ short Bs[128 * 64];
    const int tid = threadIdx.x;
    const int lane = tid & 63;
    const int w = tid >> 6;
    const int wr = w >> 1, wc = w & 1;

    // XCD swizzle: all NX column-tiles of one row-panel land on one XCD's L2
    const int id = blockIdx.x;
    const int xcd = id & 7;
    const int j = id >> 3;
    const int by = xcd + 8 * (j / NX);
    const int bx = j % NX;
    const int bm = by * 128;
    const int bn = bx * 128;

    f32x4v acc[4][4];
#pragma unroll
    for (int mi = 0; mi < 4; ++mi)
#pragma unroll
        for (int ni = 0; ni < 4; ++ni)
            acc[mi][ni] = (f32x4v){0.f, 0.f, 0.f, 0.f};

    // staging: 4 chunks of 4KB per matrix; row = 128B = 8 x 16B slots,
    // physical slot ps holds logical slot sl = ps ^ (row & 7)
    int aoff[4], boff[4];
#pragma unroll
    for (int q = 0; q < 4; ++q) {
        int o = q * 4096 + tid * 16;
        int row = o >> 7;
        int ps = (o >> 4) & 7;
        int sl = ps ^ (row & 7);
        aoff[q] = (bm + row) * K + sl * 8;
        boff[q] = (bn + row) * K + sl * 8;
    }

    const int l15 = lane & 15, qq = lane >> 4;
    int rowa[4], rowb[4];
#pragma unroll
    for (int i = 0; i < 4; ++i) {
        rowa[i] = wr * 64 + i * 16 + l15;
        rowb[i] = wc * 64 + i * 16 + l15;
    }

    for (int k0 = 0; k0 < K; k0 += 64) {
        __syncthreads();
#pragma unroll
        for (int q = 0; q < 4; ++q) {
            GL_LDS16(A + (size_t)aoff[q] + k0, As + q * 2048 + tid * 8);
            GL_LDS16(Bw + (size_t)boff[q] + k0, Bs + q * 2048 + tid * 8);
        }
        __syncthreads();

#pragma unroll
        for (int kb = 0; kb < 2; ++kb) {
            bf16x8v af[4], bf[4];
#pragma unroll
            for (int i = 0; i < 4; ++i) {
                int sa = ((kb << 2) | qq) ^ (rowa[i] & 7);
                int sb = ((kb << 2) | qq) ^ (rowb[i] & 7);
                af[i] = *(const bf16x8v*)(As + rowa[i] * 64 + sa * 8);
                bf[i] = *(const bf16x8v*)(Bs + rowb[i] * 64 + sb * 8);
            }
#pragma unroll
            for (int mi = 0; mi < 4; ++mi)
#pragma unroll
                for (int ni = 0; ni < 4; ++ni)
                    acc[mi][ni] = __builtin_amdgcn_mfma_f32_16x16x32_bf16(
                        af[mi], bf[ni], acc[mi][ni], 0, 0, 0);
        }
    }

    const int l4 = lane >> 4;
#pragma unroll
    for (int mi = 0; mi < 4; ++mi) {
        int rbase = bm + wr * 64 + mi * 16 + l4 * 4;
#pragma unroll
        for (int ni = 0; ni < 4; ++ni) {
            int col = bn + wc * 64 + ni * 16 + l15;
            f32x4v v = acc[mi][ni];
            if (EPI == 0) {
                if (col < D_INNER) {
#pragma unroll
                    for (int jj = 0; jj < 4; ++jj)
                        Zo[(size_t)(rbase + jj) * D_INNER + col] = f2b(v[jj]);
                } else if (col < ZXLD) {
#pragma unroll
                    for (int jj = 0; jj < 4; ++jj)
                        XBCo[(size_t)(rbase + jj) * D_CONV_IN + (col - D_INNER)] = f2b(v[jj]);
                } else if (col < D_IN_PROJ) {
#pragma unroll
                    for (int jj = 0; jj < 4; ++jj)
                        Do[(size_t)(rbase + jj) * NHEADS + (col - ZXLD)] = v[jj];
                }
            } else {
#pragma unroll
                for (int jj = 0; jj < 4; ++jj)
                    Co[(size_t)(rbase + jj) * D_MODEL + col] = v[jj];
            }
        }
    }
}

// ---------------------------------------------------------------------------
// K2 v3 (unchanged)
// ---------------------------------------------------------------------------
__global__ __launch_bounds__(256)
void conv_norm_v3(const bf16* __restrict__ XBC, const float* __restrict__ dtraw,
                  const float* __restrict__ conv_w, const float* __restrict__ conv_b,
                  const float* __restrict__ norm_w, const float* __restrict__ dt_bias,
                  bf16* __restrict__ xn, bf16* __restrict__ Bb,
                  bf16* __restrict__ Cb, float* __restrict__ dtb) {
    const int tid = threadIdx.x;
    const int t0 = blockIdx.x * 8;
    const int l0 = t0 & (SEQLEN - 1);

    __shared__ float sp[8][200];
    __shared__ float sq[8][8];
    __shared__ float sscale[8];

    const int c = tid;
    const bool active = (c < 224);
    const int ch0 = c * 4;

    float acc[8][4];
    float w0[4], w1[4], w2[4], w3[4];

    if (active) {
        float4 wa = *(const float4*)(conv_w + (ch0 + 0) * 4);
        float4 wb = *(const float4*)(conv_w + (ch0 + 1) * 4);
        float4 wcc = *(const float4*)(conv_w + (ch0 + 2) * 4);
        float4 wd = *(const float4*)(conv_w + (ch0 + 3) * 4);
        w0[0] = wa.x; w1[0] = wa.y; w2[0] = wa.z; w3[0] = wa.w;
        w0[1] = wb.x; w1[1] = wb.y; w2[1] = wb.z; w3[1] = wb.w;
        w0[2] = wcc.x; w1[2] = wcc.y; w2[2] = wcc.z; w3[2] = wcc.w;
        w0[3] = wd.x; w1[3] = wd.y; w2[3] = wd.z; w3[3] = wd.w;
        float4 bv = *(const float4*)(conv_b + ch0);
#pragma unroll
        for (int t = 0; t < 8; ++t) {
            acc[t][0] = bv.x; acc[t][1] = bv.y; acc[t][2] = bv.z; acc[t][3] = bv.w;
        }
#pragma unroll
        for (int ri = 0; ri < 11; ++ri) {
            int lr = l0 - 3 + ri;
            if (lr >= 0) {
                uint2 rv = *(const uint2*)((const unsigned short*)XBC
                              + (size_t)(t0 - 3 + ri) * D_CONV_IN + ch0);
                float r0 = bl(rv.x), r1 = bh(rv.x), r2 = bl(rv.y), r3 = bh(rv.y);
#pragma unroll
                for (int t = 0; t < 8; ++t) {
                    if (t >= ri - 3 && t <= ri) {
                        const int jt = ri - t;
                        const float* wj = (jt == 0) ? w0 : (jt == 1) ? w1 : (jt == 2) ? w2 : w3;
                        acc[t][0] += r0 * wj[0];
                        acc[t][1] += r1 * wj[1];
                        acc[t][2] += r2 * wj[2];
                        acc[t][3] += r3 * wj[3];
                    }
                }
            }
        }
#pragma unroll
        for (int t = 0; t < 8; ++t) {
            float ss = 0.f;
#pragma unroll
            for (int i = 0; i < 4; ++i) {
                float v = acc[t][i];
                float s = v / (1.f + __expf(-v));
                acc[t][i] = s;
                ss += s * s;
            }
            if (c < 192) sp[t][c] = ss;
        }
    }
    __syncthreads();
    if (tid < 64) {
        int t = tid >> 3, i = tid & 7;
        float s = 0.f;
#pragma unroll
        for (int k = 0; k < 24; ++k) s += sp[t][i * 24 + k];
        sq[t][i] = s;
    }
    __syncthreads();
    if (tid < 8) {
        float tot = 0.f;
#pragma unroll
        for (int i = 0; i < 8; ++i) tot += sq[tid][i];
        sscale[tid] = rsqrtf(tot / (float)D_INNER + EPSV);
    }
    __syncthreads();

    if (c < 192) {
        float4 nv = *(const float4*)(norm_w + ch0);
#pragma unroll
        for (int t = 0; t < 8; ++t) {
            float sc = sscale[t];
            uint2 o;
            o.x = pk2(acc[t][0] * sc * nv.x, acc[t][1] * sc * nv.y);
            o.y = pk2(acc[t][2] * sc * nv.z, acc[t][3] * sc * nv.w);
            *(uint2*)(xn + (size_t)(t0 + t) * D_INNER + ch0) = o;
        }
    } else if (c < 224) {
        const int idx = ch0 - 768;
#pragma unroll
        for (int t = 0; t < 8; ++t) {
            uint2 o;
            o.x = pk2(acc[t][0], acc[t][1]);
            o.y = pk2(acc[t][2], acc[t][3]);
            bf16* base = (idx < 64) ? (Bb + (size_t)(t0 + t) * D_STATE + idx)
                                    : (Cb + (size_t)(t0 + t) * D_STATE + (idx - 64));
            *(uint2*)base = o;
        }
    }
    if (tid < 96) {
        int t = tid / 12, hh = tid % 12;
        float v = dtraw[(size_t)(t0 + t) * NHEADS + hh] + dt_bias[hh];
        float spv = (v > 20.f) ? v : log1pf(expf(v));
        dtb[(size_t)(t0 + t) * NHEADS + hh] = spv;
    }
}

// ---------------------------------------------------------------------------
// Score kernel (unchanged)
// ---------------------------------------------------------------------------
__global__ __launch_bounds__(256)
void score_kernel(const bf16* __restrict__ Bb, const bf16* __restrict__ Cb,
                  bf16* __restrict__ Graw) {
    const int bc = blockIdx.x;
    const size_t tok0 = (size_t)bc * Q;
    const int tid = threadIdx.x;
    const int lane = tid & 63, w = tid >> 6;
    const int wr = w >> 1, wc = w & 1;
    __shared__ short sC[Q * 64];
    __shared__ short sB[Q * 64];

#pragma unroll
    for (int it = 0; it < 4; ++it) {
        int j = it * 256 + tid;
        int r = j >> 3, sp = j & 7;
        int sl = sp ^ (r & 7);
        GL_LDS16(Cb + tok0 * D_STATE + r * 64 + sl * 8, sC + j * 8);
        GL_LDS16(Bb + tok0 * D_STATE + r * 64 + sl * 8, sB + j * 8);
    }
    __syncthreads();

    const int l15 = lane & 15, qq = lane >> 4;
    f32x4v acc[4][4];
#pragma unroll
    for (int mi = 0; mi < 4; ++mi)
#pragma unroll
        for (int ni = 0; ni < 4; ++ni)
            acc[mi][ni] = (f32x4v){0.f, 0.f, 0.f, 0.f};

#pragma unroll
    for (int kb = 0; kb < 2; ++kb) {
        bf16x8v af[4], bf[4];
#pragma unroll
        for (int i = 0; i < 4; ++i) {
            int ra = wr * 64 + i * 16 + l15;
            int rb = wc * 64 + i * 16 + l15;
            af[i] = *(const bf16x8v*)(sC + ra * 64 + ((kb * 4 + qq) ^ (ra & 7)) * 8);
            bf[i] = *(const bf16x8v*)(sB + rb * 64 + ((kb * 4 + qq) ^ (rb & 7)) * 8);
        }
#pragma unroll
        for (int mi = 0; mi < 4; ++mi)
#pragma unroll
            for (int ni = 0; ni < 4; ++ni)
                acc[mi][ni] = __builtin_amdgcn_mfma_f32_16x16x32_bf16(
                    af[mi], bf[ni], acc[mi][ni], 0, 0, 0);
    }

    bf16* gout = Graw + (size_t)bc * (Q * Q);
#pragma unroll
    for (int mi = 0; mi < 4; ++mi) {
        int t0 = wr * 64 + mi * 16 + qq * 4;
#pragma unroll
        for (int ni = 0; ni < 4; ++ni) {
            int s = wc * 64 + ni * 16 + l15;
            f32x4v v = acc[mi][ni];
#pragma unroll
            for (int j = 0; j < 4; ++j)
                gout[(size_t)(t0 + j) * Q + s] = f2b(v[j]);
        }
    }
}

// ---------------------------------------------------------------------------
// K3a (MFMA) (unchanged)
// ---------------------------------------------------------------------------
__global__ __launch_bounds__(256)
void chunk_state_mfma(const bf16* __restrict__ xy, const bf16* __restrict__ Bb,
                      const float* __restrict__ dtb, const float* __restrict__ A_log,
                      float* __restrict__ states, float* __restrict__ cdecay) {
    const int sid = blockIdx.x;
    const int c = sid % NCHUNK;
    const int h = (sid / NCHUNK) % NHEADS;
    const int b = sid / (NCHUNK * NHEADS);
    const int tid = threadIdx.x;
    const int lane = tid & 63, w = tid >> 6;
    const size_t tok0 = (size_t)b * SEQLEN + (size_t)c * Q;
    const float Acoef = -expf(A_log[h]);

    __shared__ __align__(16) unsigned short sBT[64 * 128];
    __shared__ __align__(16) unsigned short sXT[64 * 128];
    __shared__ float slcum[Q];
    __shared__ float sdt[Q];
    __shared__ float wtot[2];

    float lx = 0.f;
    if (tid < Q) {
        float dtv = dtb[(tok0 + tid) * NHEADS + h];
        sdt[tid] = dtv;
        lx = dtv * Acoef;
        int ln = tid & 63;
        for (int off = 1; off < 64; off <<= 1) {
            float v = __shfl_up(lx, off, 64);
            if (ln >= off) lx += v;
        }
        if (ln == 63) wtot[tid >> 6] = lx;
    }
    __syncthreads();
    if (tid < Q) {
        if (tid >= 64) lx += wtot[0];
        slcum[tid] = lx;
    }
    __syncthreads();
    const float ltot = slcum[Q - 1];

    {
        int t = tid >> 1, half = tid & 1;
        float s_t = sdt[t] * __expf(ltot - slcum[t]);
        const unsigned short* br = (const unsigned short*)(Bb + (tok0 + t) * D_STATE) + half * 32;
        const unsigned short* xr = (const unsigned short*)(xy + (tok0 + t) * D_INNER + h * HEADDIM) + half * 32;
#pragma unroll
        for (int i = 0; i < 32; ++i) {
            int r = half * 32 + i;
            sBT[tswz(r, t)] = __bfloat16_as_ushort(f2b(bu(br[i]) * s_t));
            sXT[tswz(r, t)] = xr[i];
        }
    }
    __syncthreads();

    const int l15 = lane & 15, qq = lane >> 4;
    f32x4v acc[4];
#pragma unroll
    for (int ni = 0; ni < 4; ++ni) acc[ni] = (f32x4v){0.f, 0.f, 0.f, 0.f};

#pragma unroll
    for (int kb = 0; kb < 4; ++kb) {
        const int col = kb * 32 + qq * 8;
        bf16x8v af = *(const bf16x8v*)(&sBT[tswz(w * 16 + l15, col)]);
#pragma unroll
        for (int ni = 0; ni < 4; ++ni) {
            bf16x8v bx = *(const bf16x8v*)(&sXT[tswz(ni * 16 + l15, col)]);
            acc[ni] = __builtin_amdgcn_mfma_f32_16x16x32_bf16(af, bx, acc[ni], 0, 0, 0);
        }
    }

    float* out = states + (size_t)sid * 4096;
#pragma unroll
    for (int ni = 0; ni < 4; ++ni) {
#pragma unroll
        for (int j = 0; j < 4; ++j) {
            int n = w * 16 + qq * 4 + j;
            int p = ni * 16 + l15;
            out[n * 64 + p] = acc[ni][j];
        }
    }
    if (tid == 0) cdecay[sid] = expf(ltot);
}

// ---------------------------------------------------------------------------
// K3b (unchanged)
// ---------------------------------------------------------------------------
__global__ __launch_bounds__(256)
void state_pass_kernel(float* __restrict__ states, const float* __restrict__ cdecay) {
    const int bh = blockIdx.x;
    const int tid = threadIdx.x;
    float run[16];
#pragma unroll
    for (int i = 0; i < 16; ++i) run[i] = 0.f;
    float* base = states + (size_t)bh * NCHUNK * 4096 + tid * 16;
    const float* cd = cdecay + bh * NCHUNK;
    for (int c = 0; c < NCHUNK; ++c) {
        float dec = cd[c];
        float* ptr = base + (size_t)c * 4096;
        float4 s0 = *(float4*)(ptr + 0);
        float4 s1 = *(float4*)(ptr + 4);
        float4 s2 = *(float4*)(ptr + 8);
        float4 s3 = *(float4*)(ptr + 12);
        float nr[16];
        nr[0] = dec * run[0] + s0.x;  nr[1] = dec * run[1] + s0.y;
        nr[2] = dec * run[2] + s0.z;  nr[3] = dec * run[3] + s0.w;
        nr[4] = dec * run[4] + s1.x;  nr[5] = dec * run[5] + s1.y;
        nr[6] = dec * run[6] + s1.z;  nr[7] = dec * run[7] + s1.w;
        nr[8] = dec * run[8] + s2.x;  nr[9] = dec * run[9] + s2.y;
        nr[10] = dec * run[10] + s2.z; nr[11] = dec * run[11] + s2.w;
        nr[12] = dec * run[12] + s3.x; nr[13] = dec * run[13] + s3.y;
        nr[14] = dec * run[14] + s3.z; nr[15] = dec * run[15] + s3.w;
        *(float4*)(ptr + 0)  = make_float4(run[0], run[1], run[2], run[3]);
        *(float4*)(ptr + 4)  = make_float4(run[4], run[5], run[6], run[7]);
        *(float4*)(ptr + 8)  = make_float4(run[8], run[9], run[10], run[11]);
        *(float4*)(ptr + 12) = make_float4(run[12], run[13], run[14], run[15]);
#pragma unroll
        for (int i = 0; i < 16; ++i) run[i] = nr[i];
    }
}

// ---------------------------------------------------------------------------
// K3c v2 (MFMA) (unchanged)
// ---------------------------------------------------------------------------
__global__ __launch_bounds__(256)
void chunk_output_mfma(const bf16* __restrict__ Zb, bf16* __restrict__ xy,
                       const bf16* __restrict__ Cb, const bf16* __restrict__ Graw,
                       const float* __restrict__ dtb, const float* __restrict__ A_log,
                       const float* __restrict__ Dpa, const float* __restrict__ states) {
    const int sid = blockIdx.x;
    const int c = sid % NCHUNK;
    const int h = (sid / NCHUNK) % NHEADS;
    const int b = sid / (NCHUNK * NHEADS);
    const int tid = threadIdx.x;
    const int lane = tid & 63, w = tid >> 6;
    const size_t tok0 = (size_t)b * SEQLEN + (size_t)c * Q;
    const int bc = b * NCHUNK + c;
    const float Acoef = -expf(A_log[h]);

    __shared__ __align__(16) char smem[35840];
    unsigned short (*sXt)[136] = (unsigned short(*)[136])smem;
    unsigned short (*sNh)[72]  = (unsigned short(*)[72])(smem + 17408);
    unsigned short (*sNl)[72]  = (unsigned short(*)[72])(smem + 17408 + 9216);
    float (*sY)[68] = (float(*)[68])smem;
    __shared__ float slc[Q];
    __shared__ float sldn[Q];
    __shared__ float wtot[2];

    float lx = 0.f, l2dt = 0.f;
    if (tid < Q) {
        float dtv = dtb[(tok0 + tid) * NHEADS + h];
        l2dt = __logf(dtv);
        lx = dtv * Acoef;
        int ln = tid & 63;
        for (int off = 1; off < 64; off <<= 1) {
            float v = __shfl_up(lx, off, 64);
            if (ln >= off) lx += v;
        }
        if (ln == 63) wtot[tid >> 6] = lx;
    }
    __syncthreads();
    if (tid < Q) {
        if (tid >= 64) lx += wtot[0];
        slc[tid] = lx;
        sldn[tid] = lx - l2dt;
    }

    {
        int t = tid >> 1, ph = (tid & 1) * 32;
        const unsigned short* xr = (const unsigned short*)(xy + (tok0 + t) * D_INNER + h * HEADDIM + ph);
#pragma unroll
        for (int i = 0; i < 32; ++i) sXt[ph + i][t] = xr[i];
    }
    {
        const float* init = states + (size_t)sid * 4096;
        for (int i = tid; i < 1024; i += 256) {
            float4 v = ((const float4*)init)[i];
            int n = i >> 4;
            int p = (i & 15) * 4;
#pragma unroll
            for (int j2 = 0; j2 < 4; ++j2) {
                float f = (&v.x)[j2];
                bf16 hi = f2b(f);
                float lo = f - b2f(hi);
                sNh[p + j2][n] = __bfloat16_as_ushort(hi);
                sNl[p + j2][n] = __bfloat16_as_ushort(f2b(lo));
            }
        }
    }
    __syncthreads();

    const int l15 = lane & 15, qq = lane >> 4;

    int tcur[2]; float lct_mi[2], elct[2];
#pragma unroll
    for (int mi = 0; mi < 2; ++mi) {
        tcur[mi] = w * 32 + mi * 16 + l15;
        lct_mi[mi] = slc[tcur[mi]];
        elct[mi] = __expf(lct_mi[mi]);
    }

    f32x4v acc[2][4];
#pragma unroll
    for (int mi = 0; mi < 2; ++mi)
#pragma unroll
        for (int ni = 0; ni < 4; ++ni)
            acc[mi][ni] = (f32x4v){0.f, 0.f, 0.f, 0.f};

    const bf16* grow = Graw + (size_t)bc * (Q * Q);

#pragma unroll
    for (int kb = 0; kb < 4; ++kb) {
        const int s0 = kb * 32 + qq * 8;
        float4 dA = *(const float4*)(sldn + s0);
        float4 dB = *(const float4*)(sldn + s0 + 4);
        bf16x8v af[2];
#pragma unroll
        for (int mi = 0; mi < 2; ++mi) {
            int t = tcur[mi];
            float lct = lct_mi[mi];
            uint4 gv = *(const uint4*)(grow + (size_t)t * Q + s0);
            float f0 = (s0 + 0 <= t) ? bl(gv.x) * __expf(lct - dA.x) : 0.f;
            float f1 = (s0 + 1 <= t) ? bh(gv.x) * __expf(lct - dA.y) : 0.f;
            float f2 = (s0 + 2 <= t) ? bl(gv.y) * __expf(lct - dA.z) : 0.f;
            float f3 = (s0 + 3 <= t) ? bh(gv.y) * __expf(lct - dA.w) : 0.f;
            float f4 = (s0 + 4 <= t) ? bl(gv.z) * __expf(lct - dB.x) : 0.f;
            float f5 = (s0 + 5 <= t) ? bh(gv.z) * __expf(lct - dB.y) : 0.f;
            float f6 = (s0 + 6 <= t) ? bl(gv.w) * __expf(lct - dB.z) : 0.f;
            float f7 = (s0 + 7 <= t) ? bh(gv.w) * __expf(lct - dB.w) : 0.f;
            union { bf16x8v v; unsigned u[4]; } r;
            r.u[0] = pk2(f0, f1); r.u[1] = pk2(f2, f3);
            r.u[2] = pk2(f4, f5); r.u[3] = pk2(f6, f7);
            af[mi] = r.v;
        }
        bf16x8v bfr[4];
#pragma unroll
        for (int ni = 0; ni < 4; ++ni)
            bfr[ni] = *(const bf16x8v*)(&sXt[ni * 16 + l15][s0]);
#pragma unroll
        for (int mi = 0; mi < 2; ++mi)
#pragma unroll
            for (int ni = 0; ni < 4; ++ni)
                acc[mi][ni] = __builtin_amdgcn_mfma_f32_16x16x32_bf16(
                    af[mi], bfr[ni], acc[mi][ni], 0, 0, 0);
    }

#pragma unroll
    for (int half = 0; half < 2; ++half) {
        const int n0 = half * 32 + qq * 8;
        bf16x8v af[2];
#pragma unroll
        for (int mi = 0; mi < 2; ++mi) {
            uint4 cv = *(const uint4*)(Cb + (tok0 + tcur[mi]) * D_STATE + n0);
            float el = elct[mi];
            union { bf16x8v v; unsigned u[4]; } r;
            r.u[0] = pk2(bl(cv.x) * el, bh(cv.x) * el);
            r.u[1] = pk2(bl(cv.y) * el, bh(cv.y) * el);
            r.u[2] = pk2(bl(cv.z) * el, bh(cv.z) * el);
            r.u[3] = pk2(bl(cv.w) * el, bh(cv.w) * el);
            af[mi] = r.v;
        }
        bf16x8v bh_[4], bl_[4];
#pragma unroll
        for (int ni = 0; ni < 4; ++ni) {
            int p = ni * 16 + l15;
            bh_[ni] = *(const bf16x8v*)(&sNh[p][n0]);
            bl_[ni] = *(const bf16x8v*)(&sNl[p][n0]);
        }
#pragma unroll
        for (int mi = 0; mi < 2; ++mi)
#pragma unroll
            for (int ni = 0; ni < 4; ++ni) {
                acc[mi][ni] = __builtin_amdgcn_mfma_f32_16x16x32_bf16(
                    af[mi], bh_[ni], acc[mi][ni], 0, 0, 0);
                acc[mi][ni] = __builtin_amdgcn_mfma_f32_16x16x32_bf16(
                    af[mi], bl_[ni], acc[mi][ni], 0, 0, 0);
            }
    }

    __syncthreads();
#pragma unroll
    for (int mi = 0; mi < 2; ++mi) {
        int r0 = w * 32 + mi * 16 + qq * 4;
#pragma unroll
        for (int ni = 0; ni < 4; ++ni) {
            int p = ni * 16 + l15;
            f32x4v v = acc[mi][ni];
#pragma unroll
            for (int jj = 0; jj < 4; ++jj) sY[r0 + jj][p] = v[jj];
        }
    }
    __syncthreads();

    {
        const float Dh = Dpa[h];
        int t = tid >> 1;
        int p0 = (tid & 1) * 32;
        size_t off = (tok0 + t) * D_INNER + h * HEADDIM + p0;
        const uint4* xrow = (const uint4*)(xy + off);
        const uint4* zrow = (const uint4*)(Zb + off);
        uint4 outv[4];
#pragma unroll
        for (int k4 = 0; k4 < 4; ++k4) {
            uint4 xv = xrow[k4];
            uint4 zv = zrow[k4];
            const float* yr = &sY[t][p0 + k4 * 8];
            float xs[8] = {bl(xv.x), bh(xv.x), bl(xv.y), bh(xv.y),
                           bl(xv.z), bh(xv.z), bl(xv.w), bh(xv.w)};
            float zs[8] = {bl(zv.x), bh(zv.x), bl(zv.y), bh(zv.y),
                           bl(zv.z), bh(zv.z), bl(zv.w), bh(zv.w)};
            unsigned o[4];
#pragma unroll
            for (int j = 0; j < 4; ++j) {
                float y0 = yr[2 * j]     + Dh * xs[2 * j];
                float y1 = yr[2 * j + 1] + Dh * xs[2 * j + 1];
                float z0 = zs[2 * j], z1 = zs[2 * j + 1];
                y0 *= z0 / (1.f + __expf(-z0));
                y1 *= z1 / (1.f + __expf(-z1));
                o[j] = pk2(y0, y1);
            }
            outv[k4].x = o[0]; outv[k4].y = o[1]; outv[k4].z = o[2]; outv[k4].w = o[3];
        }
        uint4* orow = (uint4*)(xy + off);
#pragma unroll
        for (int k4 = 0; k4 < 4; ++k4) orow[k4] = outv[k4];
    }
}

// ---------------------------------------------------------------------------
extern "C" void kernel_launch(void* const* d_in, const int* in_sizes, int n_in,
                              void* d_out, int out_size, void* d_ws, size_t ws_size,
                              hipStream_t stream) {
    (void)in_sizes; (void)n_in; (void)out_size; (void)ws_size;
    const float* u          = (const float*)d_in[0];
    const float* in_proj_w  = (const float*)d_in[1];
    const float* conv_w     = (const float*)d_in[2];
    const float* conv_b     = (const float*)d_in[3];
    const float* norm_w     = (const float*)d_in[4];
    const float* out_proj_w = (const float*)d_in[5];
    const float* A_log      = (const float*)d_in[6];
    const float* Dp         = (const float*)d_in[7];
    const float* dt_bias    = (const float*)d_in[8];

    char* w = (char*)d_ws;
    bf16*  Zb     = (bf16*)w;     w += (size_t)NTOK * D_INNER * 2;
    bf16*  XBC    = (bf16*)w;     w += (size_t)NTOK * D_CONV_IN * 2;
    bf16*  xy     = (bf16*)w;     w += (size_t)NTOK * D_INNER * 2;
    bf16*  Bb     = (bf16*)w;     w += (size_t)NTOK * D_STATE * 2;
    bf16*  Cb     = (bf16*)w;     w += (size_t)NTOK * D_STATE * 2;
    float* dtraw  = (float*)w;    w += (size_t)NTOK * NHEADS * 4;
    float* dtb    = (float*)w;    w += (size_t)NTOK * NHEADS * 4;
    float* cdecay = (float*)w;    w += (size_t)NCHB * 4;
    bf16*  wA     = (bf16*)w;     w += (size_t)NPROJPAD * D_MODEL * 2;
    bf16*  wO     = (bf16*)w;
    float* states = (float*)XBC;
    bf16*  Graw   = (bf16*)((char*)XBC + (size_t)NCHB * 4096 * 4);
    bf16*  uB     = xy;

    { int n = NTOK * D_MODEL;
      cvt_f32_bf16<<<(n / 4 + 255) / 256, 256, 0, stream>>>(u, (unsigned short*)uB, n); }
    { int nr = D_IN_PROJ * D_MODEL, np = NPROJPAD * D_MODEL;
      cvt_pad<<<(np / 4 + 255) / 256, 256, 0, stream>>>(in_proj_w, (unsigned short*)wA, nr, np); }
    { int n = D_MODEL * D_INNER;
      cvt_f32_bf16<<<(n / 4 + 255) / 256, 256, 0, stream>>>(out_proj_w, (unsigned short*)wO, n); }

    // K1: 1D grid, XCD-swizzled inside (NX = 14 column tiles, 256 row panels)
    gemm_mfma<0, NPROJPAD / 128><<<(NPROJPAD / 128) * (NTOK / 128), 256, 0, stream>>>(
        uB, wA, D_MODEL, Zb, XBC, dtraw, nullptr);

    conv_norm_v3<<<NTOK / 8, 256, 0, stream>>>(XBC, dtraw, conv_w, conv_b, norm_w, dt_bias,
                                               xy, Bb, Cb, dtb);

    score_kernel<<<NBC, 256, 0, stream>>>(Bb, Cb, Graw);
    chunk_state_mfma<<<NCHB, 256, 0, stream>>>(xy, Bb, dtb, A_log, states, cdecay);
    state_pass_kernel<<<BATCH * NHEADS, 256, 0, stream>>>(states, cdecay);
    chunk_output_mfma<<<NCHB, 256, 0, stream>>>(Zb, xy, Cb, Graw, dtb, A_log, Dp, states);

    // K4: NX = 3 column tiles
    gemm_mfma<1, D_MODEL / 128><<<(D_MODEL / 128) * (NTOK / 128), 256, 0, stream>>>(
        xy, wO, D_INNER, nullptr, nullptr, nullptr, (float*)d_out);
}

// Round 12
// 268.269 us; speedup vs baseline: 9.6578x; 1.0173x over previous
//
#include <hip/hip_runtime.h>
#include <hip/hip_bf16.h>
#include <cstddef>

#define D_MODEL   384
#define D_IN_PROJ 1676
#define D_INNER   768
#define D_CONV_IN 896
#define ZXLD      1664
#define NPROJPAD  1792          // 14 * 128
#define NHEADS    12
#define HEADDIM   64
#define D_STATE   64
#define SEQLEN    4096
#define BATCH     8
#define NTOK      (BATCH * SEQLEN)
#define EPSV      1e-5f
#define Q         128
#define NCHUNK    (SEQLEN / Q)
#define NCHB      (BATCH * NHEADS * NCHUNK)
#define NBC       (BATCH * NCHUNK)

typedef __hip_bfloat16 bf16;
typedef __attribute__((ext_vector_type(8))) short bf16x8v;
typedef __attribute__((ext_vector_type(4))) float f32x4v;

__device__ __forceinline__ float b2f(bf16 v) { return __bfloat162float(v); }
__device__ __forceinline__ bf16  f2b(float v) { return __float2bfloat16(v); }
__device__ __forceinline__ float bl(unsigned u)  { return __uint_as_float(u << 16); }
__device__ __forceinline__ float bh(unsigned u)  { return __uint_as_float(u & 0xffff0000u); }
__device__ __forceinline__ float bu(unsigned short v) { return __uint_as_float(((unsigned)v) << 16); }
__device__ __forceinline__ unsigned pk2(float a, float b) {
    return ((unsigned)__bfloat16_as_ushort(f2b(b)) << 16) | (unsigned)__bfloat16_as_ushort(f2b(a));
}
__device__ __forceinline__ int swzf(int r) { return (r ^ (r >> 2)) & 3; }
__device__ __forceinline__ int tswz(int r, int col) {
    return r * 128 + ((((col >> 3) ^ (r & 7)) << 3) | (col & 7));
}

#define GL_LDS16(g, l) __builtin_amdgcn_global_load_lds( \
    (const __attribute__((address_space(1))) unsigned*)(g), \
    (__attribute__((address_space(3))) unsigned*)(l), 16, 0, 0)

// ---------------------------------------------------------------------------
__global__ __launch_bounds__(256)
void cvt_f32_bf16(const float* __restrict__ in, unsigned short* __restrict__ out, int n) {
    int i = (blockIdx.x * 256 + threadIdx.x) * 4;
    if (i + 3 < n) {
        float4 v = *(const float4*)(in + i);
        uint2 o; o.x = pk2(v.x, v.y); o.y = pk2(v.z, v.w);
        *(uint2*)(out + i) = o;
    }
}

__global__ __launch_bounds__(256)
void cvt_pad(const float* __restrict__ in, unsigned short* __restrict__ out,
             int n_real, int n_pad) {
    int i = (blockIdx.x * 256 + threadIdx.x) * 4;
    if (i + 3 < n_pad) {
        uint2 o;
        if (i < n_real) {
            float4 v = *(const float4*)(in + i);
            o.x = pk2(v.x, v.y); o.y = pk2(v.z, v.w);
        } else {
            o.x = 0u; o.y = 0u;
        }
        *(uint2*)(out + i) = o;
    }
}

// ---------------------------------------------------------------------------
// MFMA GEMM-NT, BK=32, double-buffered LDS (2-phase: stage t+1 before compute t,
// single barrier per K-step), XCD-aware bijective block remap.
// EPI 0: cols<768 -> Z bf16; <1664 -> XBC bf16; <1676 -> dtraw f32.
// EPI 1: f32 out stride D_MODEL.
// ---------------------------------------------------------------------------
template<int EPI, int NX>
__global__ __launch_bounds__(256)
void gemm_mfma(const bf16* __restrict__ A, const bf16* __restrict__ Bw, int K,
               bf16* __restrict__ Zo, bf16* __restrict__ XBCo,
               float* __restrict__ Do, float* __restrict__ Co) {
    __shared__ short As[2][128 * 32];
    __shared__ short Bs[2][128 * 32];
    const int tid = threadIdx.x;
    const int lane = tid & 63;
    const int w = tid >> 6;
    const int wr = w >> 1, wc = w & 1;

    // XCD swizzle: all NX column-tiles of one row-panel land on one XCD's L2
    const int id = blockIdx.x;
    const int xcd = id & 7;
    const int j = id >> 3;
    const int by = xcd + 8 * (j / NX);
    const int bx = j % NX;
    const int bm = by * 128;
    const int bn = bx * 128;

    f32x4v acc[4][4];
#pragma unroll
    for (int mi = 0; mi < 4; ++mi)
#pragma unroll
        for (int ni = 0; ni < 4; ++ni)
            acc[mi][ni] = (f32x4v){0.f, 0.f, 0.f, 0.f};

    // staging: 2 chunks of 4KB per matrix per buffer; row = 64B = 4 x 16B slots,
    // physical slot ps holds logical slot sl = ps ^ swzf(row)
    int aoff[2], boff[2];
#pragma unroll
    for (int q = 0; q < 2; ++q) {
        int o = q * 4096 + tid * 16;
        int row = o >> 6;
        int ps = (o >> 4) & 3;
        int sl = ps ^ swzf(row);
        aoff[q] = (bm + row) * K + sl * 8;
        boff[q] = (bn + row) * K + sl * 8;
    }

    const int l15 = lane & 15, qq = lane >> 4;
    int aidx[4], bidx[4];
#pragma unroll
    for (int i = 0; i < 4; ++i) {
        int ra = wr * 64 + i * 16 + l15;
        int rb = wc * 64 + i * 16 + l15;
        aidx[i] = ra * 32 + ((qq ^ swzf(ra)) * 8);
        bidx[i] = rb * 32 + ((qq ^ swzf(rb)) * 8);
    }

    // prologue: stage tile 0 into buffer 0
    GL_LDS16(A + (size_t)aoff[0], &As[0][tid * 8]);
    GL_LDS16(A + (size_t)aoff[1], &As[0][2048 + tid * 8]);
    GL_LDS16(Bw + (size_t)boff[0], &Bs[0][tid * 8]);
    GL_LDS16(Bw + (size_t)boff[1], &Bs[0][2048 + tid * 8]);
    __syncthreads();   // compiler drains vmcnt(0) before s_barrier

    const int nt = K >> 5;
    for (int t = 0; t < nt; ++t) {
        const int cur = t & 1;
        // issue next tile's staging into the alternate buffer (overlaps compute)
        if (t + 1 < nt) {
            const int k0 = (t + 1) << 5;
            GL_LDS16(A + (size_t)aoff[0] + k0, &As[cur ^ 1][tid * 8]);
            GL_LDS16(A + (size_t)aoff[1] + k0, &As[cur ^ 1][2048 + tid * 8]);
            GL_LDS16(Bw + (size_t)boff[0] + k0, &Bs[cur ^ 1][tid * 8]);
            GL_LDS16(Bw + (size_t)boff[1] + k0, &Bs[cur ^ 1][2048 + tid * 8]);
        }
        bf16x8v af[4], bf[4];
#pragma unroll
        for (int i = 0; i < 4; ++i) {
            af[i] = *(const bf16x8v*)(&As[cur][aidx[i]]);
            bf[i] = *(const bf16x8v*)(&Bs[cur][bidx[i]]);
        }
#pragma unroll
        for (int mi = 0; mi < 4; ++mi)
#pragma unroll
            for (int ni = 0; ni < 4; ++ni)
                acc[mi][ni] = __builtin_amdgcn_mfma_f32_16x16x32_bf16(
                    af[mi], bf[ni], acc[mi][ni], 0, 0, 0);
        __syncthreads();   // drains next-tile staging (in flight during MFMA)
                           // and guards buffer reuse
    }

    const int l4 = lane >> 4;
#pragma unroll
    for (int mi = 0; mi < 4; ++mi) {
        int rbase = bm + wr * 64 + mi * 16 + l4 * 4;
#pragma unroll
        for (int ni = 0; ni < 4; ++ni) {
            int col = bn + wc * 64 + ni * 16 + l15;
            f32x4v v = acc[mi][ni];
            if (EPI == 0) {
                if (col < D_INNER) {
#pragma unroll
                    for (int jj = 0; jj < 4; ++jj)
                        Zo[(size_t)(rbase + jj) * D_INNER + col] = f2b(v[jj]);
                } else if (col < ZXLD) {
#pragma unroll
                    for (int jj = 0; jj < 4; ++jj)
                        XBCo[(size_t)(rbase + jj) * D_CONV_IN + (col - D_INNER)] = f2b(v[jj]);
                } else if (col < D_IN_PROJ) {
#pragma unroll
                    for (int jj = 0; jj < 4; ++jj)
                        Do[(size_t)(rbase + jj) * NHEADS + (col - ZXLD)] = v[jj];
                }
            } else {
#pragma unroll
                for (int jj = 0; jj < 4; ++jj)
                    Co[(size_t)(rbase + jj) * D_MODEL + col] = v[jj];
            }
        }
    }
}

// ---------------------------------------------------------------------------
// K2 v3 (unchanged)
// ---------------------------------------------------------------------------
__global__ __launch_bounds__(256)
void conv_norm_v3(const bf16* __restrict__ XBC, const float* __restrict__ dtraw,
                  const float* __restrict__ conv_w, const float* __restrict__ conv_b,
                  const float* __restrict__ norm_w, const float* __restrict__ dt_bias,
                  bf16* __restrict__ xn, bf16* __restrict__ Bb,
                  bf16* __restrict__ Cb, float* __restrict__ dtb) {
    const int tid = threadIdx.x;
    const int t0 = blockIdx.x * 8;
    const int l0 = t0 & (SEQLEN - 1);

    __shared__ float sp[8][200];
    __shared__ float sq[8][8];
    __shared__ float sscale[8];

    const int c = tid;
    const bool active = (c < 224);
    const int ch0 = c * 4;

    float acc[8][4];
    float w0[4], w1[4], w2[4], w3[4];

    if (active) {
        float4 wa = *(const float4*)(conv_w + (ch0 + 0) * 4);
        float4 wb = *(const float4*)(conv_w + (ch0 + 1) * 4);
        float4 wcc = *(const float4*)(conv_w + (ch0 + 2) * 4);
        float4 wd = *(const float4*)(conv_w + (ch0 + 3) * 4);
        w0[0] = wa.x; w1[0] = wa.y; w2[0] = wa.z; w3[0] = wa.w;
        w0[1] = wb.x; w1[1] = wb.y; w2[1] = wb.z; w3[1] = wb.w;
        w0[2] = wcc.x; w1[2] = wcc.y; w2[2] = wcc.z; w3[2] = wcc.w;
        w0[3] = wd.x; w1[3] = wd.y; w2[3] = wd.z; w3[3] = wd.w;
        float4 bv = *(const float4*)(conv_b + ch0);
#pragma unroll
        for (int t = 0; t < 8; ++t) {
            acc[t][0] = bv.x; acc[t][1] = bv.y; acc[t][2] = bv.z; acc[t][3] = bv.w;
        }
#pragma unroll
        for (int ri = 0; ri < 11; ++ri) {
            int lr = l0 - 3 + ri;
            if (lr >= 0) {
                uint2 rv = *(const uint2*)((const unsigned short*)XBC
                              + (size_t)(t0 - 3 + ri) * D_CONV_IN + ch0);
                float r0 = bl(rv.x), r1 = bh(rv.x), r2 = bl(rv.y), r3 = bh(rv.y);
#pragma unroll
                for (int t = 0; t < 8; ++t) {
                    if (t >= ri - 3 && t <= ri) {
                        const int jt = ri - t;
                        const float* wj = (jt == 0) ? w0 : (jt == 1) ? w1 : (jt == 2) ? w2 : w3;
                        acc[t][0] += r0 * wj[0];
                        acc[t][1] += r1 * wj[1];
                        acc[t][2] += r2 * wj[2];
                        acc[t][3] += r3 * wj[3];
                    }
                }
            }
        }
#pragma unroll
        for (int t = 0; t < 8; ++t) {
            float ss = 0.f;
#pragma unroll
            for (int i = 0; i < 4; ++i) {
                float v = acc[t][i];
                float s = v / (1.f + __expf(-v));
                acc[t][i] = s;
                ss += s * s;
            }
            if (c < 192) sp[t][c] = ss;
        }
    }
    __syncthreads();
    if (tid < 64) {
        int t = tid >> 3, i = tid & 7;
        float s = 0.f;
#pragma unroll
        for (int k = 0; k < 24; ++k) s += sp[t][i * 24 + k];
        sq[t][i] = s;
    }
    __syncthreads();
    if (tid < 8) {
        float tot = 0.f;
#pragma unroll
        for (int i = 0; i < 8; ++i) tot += sq[tid][i];
        sscale[tid] = rsqrtf(tot / (float)D_INNER + EPSV);
    }
    __syncthreads();

    if (c < 192) {
        float4 nv = *(const float4*)(norm_w + ch0);
#pragma unroll
        for (int t = 0; t < 8; ++t) {
            float sc = sscale[t];
            uint2 o;
            o.x = pk2(acc[t][0] * sc * nv.x, acc[t][1] * sc * nv.y);
            o.y = pk2(acc[t][2] * sc * nv.z, acc[t][3] * sc * nv.w);
            *(uint2*)(xn + (size_t)(t0 + t) * D_INNER + ch0) = o;
        }
    } else if (c < 224) {
        const int idx = ch0 - 768;
#pragma unroll
        for (int t = 0; t < 8; ++t) {
            uint2 o;
            o.x = pk2(acc[t][0], acc[t][1]);
            o.y = pk2(acc[t][2], acc[t][3]);
            bf16* base = (idx < 64) ? (Bb + (size_t)(t0 + t) * D_STATE + idx)
                                    : (Cb + (size_t)(t0 + t) * D_STATE + (idx - 64));
            *(uint2*)base = o;
        }
    }
    if (tid < 96) {
        int t = tid / 12, hh = tid % 12;
        float v = dtraw[(size_t)(t0 + t) * NHEADS + hh] + dt_bias[hh];
        float spv = (v > 20.f) ? v : log1pf(expf(v));
        dtb[(size_t)(t0 + t) * NHEADS + hh] = spv;
    }
}

// ---------------------------------------------------------------------------
// Score kernel (unchanged)
// ---------------------------------------------------------------------------
__global__ __launch_bounds__(256)
void score_kernel(const bf16* __restrict__ Bb, const bf16* __restrict__ Cb,
                  bf16* __restrict__ Graw) {
    const int bc = blockIdx.x;
    const size_t tok0 = (size_t)bc * Q;
    const int tid = threadIdx.x;
    const int lane = tid & 63, w = tid >> 6;
    const int wr = w >> 1, wc = w & 1;
    __shared__ short sC[Q * 64];
    __shared__ short sB[Q * 64];

#pragma unroll
    for (int it = 0; it < 4; ++it) {
        int j = it * 256 + tid;
        int r = j >> 3, sp = j & 7;
        int sl = sp ^ (r & 7);
        GL_LDS16(Cb + tok0 * D_STATE + r * 64 + sl * 8, sC + j * 8);
        GL_LDS16(Bb + tok0 * D_STATE + r * 64 + sl * 8, sB + j * 8);
    }
    __syncthreads();

    const int l15 = lane & 15, qq = lane >> 4;
    f32x4v acc[4][4];
#pragma unroll
    for (int mi = 0; mi < 4; ++mi)
#pragma unroll
        for (int ni = 0; ni < 4; ++ni)
            acc[mi][ni] = (f32x4v){0.f, 0.f, 0.f, 0.f};

#pragma unroll
    for (int kb = 0; kb < 2; ++kb) {
        bf16x8v af[4], bf[4];
#pragma unroll
        for (int i = 0; i < 4; ++i) {
            int ra = wr * 64 + i * 16 + l15;
            int rb = wc * 64 + i * 16 + l15;
            af[i] = *(const bf16x8v*)(sC + ra * 64 + ((kb * 4 + qq) ^ (ra & 7)) * 8);
            bf[i] = *(const bf16x8v*)(sB + rb * 64 + ((kb * 4 + qq) ^ (rb & 7)) * 8);
        }
#pragma unroll
        for (int mi = 0; mi < 4; ++mi)
#pragma unroll
            for (int ni = 0; ni < 4; ++ni)
                acc[mi][ni] = __builtin_amdgcn_mfma_f32_16x16x32_bf16(
                    af[mi], bf[ni], acc[mi][ni], 0, 0, 0);
    }

    bf16* gout = Graw + (size_t)bc * (Q * Q);
#pragma unroll
    for (int mi = 0; mi < 4; ++mi) {
        int t0 = wr * 64 + mi * 16 + qq * 4;
#pragma unroll
        for (int ni = 0; ni < 4; ++ni) {
            int s = wc * 64 + ni * 16 + l15;
            f32x4v v = acc[mi][ni];
#pragma unroll
            for (int j = 0; j < 4; ++j)
                gout[(size_t)(t0 + j) * Q + s] = f2b(v[j]);
        }
    }
}

// ---------------------------------------------------------------------------
// K3a (MFMA) (unchanged)
// ---------------------------------------------------------------------------
__global__ __launch_bounds__(256)
void chunk_state_mfma(const bf16* __restrict__ xy, const bf16* __restrict__ Bb,
                      const float* __restrict__ dtb, const float* __restrict__ A_log,
                      float* __restrict__ states, float* __restrict__ cdecay) {
    const int sid = blockIdx.x;
    const int c = sid % NCHUNK;
    const int h = (sid / NCHUNK) % NHEADS;
    const int b = sid / (NCHUNK * NHEADS);
    const int tid = threadIdx.x;
    const int lane = tid & 63, w = tid >> 6;
    const size_t tok0 = (size_t)b * SEQLEN + (size_t)c * Q;
    const float Acoef = -expf(A_log[h]);

    __shared__ __align__(16) unsigned short sBT[64 * 128];
    __shared__ __align__(16) unsigned short sXT[64 * 128];
    __shared__ float slcum[Q];
    __shared__ float sdt[Q];
    __shared__ float wtot[2];

    float lx = 0.f;
    if (tid < Q) {
        float dtv = dtb[(tok0 + tid) * NHEADS + h];
        sdt[tid] = dtv;
        lx = dtv * Acoef;
        int ln = tid & 63;
        for (int off = 1; off < 64; off <<= 1) {
            float v = __shfl_up(lx, off, 64);
            if (ln >= off) lx += v;
        }
        if (ln == 63) wtot[tid >> 6] = lx;
    }
    __syncthreads();
    if (tid < Q) {
        if (tid >= 64) lx += wtot[0];
        slcum[tid] = lx;
    }
    __syncthreads();
    const float ltot = slcum[Q - 1];

    {
        int t = tid >> 1, half = tid & 1;
        float s_t = sdt[t] * __expf(ltot - slcum[t]);
        const unsigned short* br = (const unsigned short*)(Bb + (tok0 + t) * D_STATE) + half * 32;
        const unsigned short* xr = (const unsigned short*)(xy + (tok0 + t) * D_INNER + h * HEADDIM) + half * 32;
#pragma unroll
        for (int i = 0; i < 32; ++i) {
            int r = half * 32 + i;
            sBT[tswz(r, t)] = __bfloat16_as_ushort(f2b(bu(br[i]) * s_t));
            sXT[tswz(r, t)] = xr[i];
        }
    }
    __syncthreads();

    const int l15 = lane & 15, qq = lane >> 4;
    f32x4v acc[4];
#pragma unroll
    for (int ni = 0; ni < 4; ++ni) acc[ni] = (f32x4v){0.f, 0.f, 0.f, 0.f};

#pragma unroll
    for (int kb = 0; kb < 4; ++kb) {
        const int col = kb * 32 + qq * 8;
        bf16x8v af = *(const bf16x8v*)(&sBT[tswz(w * 16 + l15, col)]);
#pragma unroll
        for (int ni = 0; ni < 4; ++ni) {
            bf16x8v bx = *(const bf16x8v*)(&sXT[tswz(ni * 16 + l15, col)]);
            acc[ni] = __builtin_amdgcn_mfma_f32_16x16x32_bf16(af, bx, acc[ni], 0, 0, 0);
        }
    }

    float* out = states + (size_t)sid * 4096;
#pragma unroll
    for (int ni = 0; ni < 4; ++ni) {
#pragma unroll
        for (int j = 0; j < 4; ++j) {
            int n = w * 16 + qq * 4 + j;
            int p = ni * 16 + l15;
            out[n * 64 + p] = acc[ni][j];
        }
    }
    if (tid == 0) cdecay[sid] = expf(ltot);
}

// ---------------------------------------------------------------------------
// K3b (unchanged)
// ---------------------------------------------------------------------------
__global__ __launch_bounds__(256)
void state_pass_kernel(float* __restrict__ states, const float* __restrict__ cdecay) {
    const int bh = blockIdx.x;
    const int tid = threadIdx.x;
    float run[16];
#pragma unroll
    for (int i = 0; i < 16; ++i) run[i] = 0.f;
    float* base = states + (size_t)bh * NCHUNK * 4096 + tid * 16;
    const float* cd = cdecay + bh * NCHUNK;
    for (int c = 0; c < NCHUNK; ++c) {
        float dec = cd[c];
        float* ptr = base + (size_t)c * 4096;
        float4 s0 = *(float4*)(ptr + 0);
        float4 s1 = *(float4*)(ptr + 4);
        float4 s2 = *(float4*)(ptr + 8);
        float4 s3 = *(float4*)(ptr + 12);
        float nr[16];
        nr[0] = dec * run[0] + s0.x;  nr[1] = dec * run[1] + s0.y;
        nr[2] = dec * run[2] + s0.z;  nr[3] = dec * run[3] + s0.w;
        nr[4] = dec * run[4] + s1.x;  nr[5] = dec * run[5] + s1.y;
        nr[6] = dec * run[6] + s1.z;  nr[7] = dec * run[7] + s1.w;
        nr[8] = dec * run[8] + s2.x;  nr[9] = dec * run[9] + s2.y;
        nr[10] = dec * run[10] + s2.z; nr[11] = dec * run[11] + s2.w;
        nr[12] = dec * run[12] + s3.x; nr[13] = dec * run[13] + s3.y;
        nr[14] = dec * run[14] + s3.z; nr[15] = dec * run[15] + s3.w;
        *(float4*)(ptr + 0)  = make_float4(run[0], run[1], run[2], run[3]);
        *(float4*)(ptr + 4)  = make_float4(run[4], run[5], run[6], run[7]);
        *(float4*)(ptr + 8)  = make_float4(run[8], run[9], run[10], run[11]);
        *(float4*)(ptr + 12) = make_float4(run[12], run[13], run[14], run[15]);
#pragma unroll
        for (int i = 0; i < 16; ++i) run[i] = nr[i];
    }
}

// ---------------------------------------------------------------------------
// K3c v2 (MFMA) (unchanged)
// ---------------------------------------------------------------------------
__global__ __launch_bounds__(256)
void chunk_output_mfma(const bf16* __restrict__ Zb, bf16* __restrict__ xy,
                       const bf16* __restrict__ Cb, const bf16* __restrict__ Graw,
                       const float* __restrict__ dtb, const float* __restrict__ A_log,
                       const float* __restrict__ Dpa, const float* __restrict__ states) {
    const int sid = blockIdx.x;
    const int c = sid % NCHUNK;
    const int h = (sid / NCHUNK) % NHEADS;
    const int b = sid / (NCHUNK * NHEADS);
    const int tid = threadIdx.x;
    const int lane = tid & 63, w = tid >> 6;
    const size_t tok0 = (size_t)b * SEQLEN + (size_t)c * Q;
    const int bc = b * NCHUNK + c;
    const float Acoef = -expf(A_log[h]);

    __shared__ __align__(16) char smem[35840];
    unsigned short (*sXt)[136] = (unsigned short(*)[136])smem;
    unsigned short (*sNh)[72]  = (unsigned short(*)[72])(smem + 17408);
    unsigned short (*sNl)[72]  = (unsigned short(*)[72])(smem + 17408 + 9216);
    float (*sY)[68] = (float(*)[68])smem;
    __shared__ float slc[Q];
    __shared__ float sldn[Q];
    __shared__ float wtot[2];

    float lx = 0.f, l2dt = 0.f;
    if (tid < Q) {
        float dtv = dtb[(tok0 + tid) * NHEADS + h];
        l2dt = __logf(dtv);
        lx = dtv * Acoef;
        int ln = tid & 63;
        for (int off = 1; off < 64; off <<= 1) {
            float v = __shfl_up(lx, off, 64);
            if (ln >= off) lx += v;
        }
        if (ln == 63) wtot[tid >> 6] = lx;
    }
    __syncthreads();
    if (tid < Q) {
        if (tid >= 64) lx += wtot[0];
        slc[tid] = lx;
        sldn[tid] = lx - l2dt;
    }

    {
        int t = tid >> 1, ph = (tid & 1) * 32;
        const unsigned short* xr = (const unsigned short*)(xy + (tok0 + t) * D_INNER + h * HEADDIM + ph);
#pragma unroll
        for (int i = 0; i < 32; ++i) sXt[ph + i][t] = xr[i];
    }
    {
        const float* init = states + (size_t)sid * 4096;
        for (int i = tid; i < 1024; i += 256) {
            float4 v = ((const float4*)init)[i];
            int n = i >> 4;
            int p = (i & 15) * 4;
#pragma unroll
            for (int j2 = 0; j2 < 4; ++j2) {
                float f = (&v.x)[j2];
                bf16 hi = f2b(f);
                float lo = f - b2f(hi);
                sNh[p + j2][n] = __bfloat16_as_ushort(hi);
                sNl[p + j2][n] = __bfloat16_as_ushort(f2b(lo));
            }
        }
    }
    __syncthreads();

    const int l15 = lane & 15, qq = lane >> 4;

    int tcur[2]; float lct_mi[2], elct[2];
#pragma unroll
    for (int mi = 0; mi < 2; ++mi) {
        tcur[mi] = w * 32 + mi * 16 + l15;
        lct_mi[mi] = slc[tcur[mi]];
        elct[mi] = __expf(lct_mi[mi]);
    }

    f32x4v acc[2][4];
#pragma unroll
    for (int mi = 0; mi < 2; ++mi)
#pragma unroll
        for (int ni = 0; ni < 4; ++ni)
            acc[mi][ni] = (f32x4v){0.f, 0.f, 0.f, 0.f};

    const bf16* grow = Graw + (size_t)bc * (Q * Q);

#pragma unroll
    for (int kb = 0; kb < 4; ++kb) {
        const int s0 = kb * 32 + qq * 8;
        float4 dA = *(const float4*)(sldn + s0);
        float4 dB = *(const float4*)(sldn + s0 + 4);
        bf16x8v af[2];
#pragma unroll
        for (int mi = 0; mi < 2; ++mi) {
            int t = tcur[mi];
            float lct = lct_mi[mi];
            uint4 gv = *(const uint4*)(grow + (size_t)t * Q + s0);
            float f0 = (s0 + 0 <= t) ? bl(gv.x) * __expf(lct - dA.x) : 0.f;
            float f1 = (s0 + 1 <= t) ? bh(gv.x) * __expf(lct - dA.y) : 0.f;
            float f2 = (s0 + 2 <= t) ? bl(gv.y) * __expf(lct - dA.z) : 0.f;
            float f3 = (s0 + 3 <= t) ? bh(gv.y) * __expf(lct - dA.w) : 0.f;
            float f4 = (s0 + 4 <= t) ? bl(gv.z) * __expf(lct - dB.x) : 0.f;
            float f5 = (s0 + 5 <= t) ? bh(gv.z) * __expf(lct - dB.y) : 0.f;
            float f6 = (s0 + 6 <= t) ? bl(gv.w) * __expf(lct - dB.z) : 0.f;
            float f7 = (s0 + 7 <= t) ? bh(gv.w) * __expf(lct - dB.w) : 0.f;
            union { bf16x8v v; unsigned u[4]; } r;
            r.u[0] = pk2(f0, f1); r.u[1] = pk2(f2, f3);
            r.u[2] = pk2(f4, f5); r.u[3] = pk2(f6, f7);
            af[mi] = r.v;
        }
        bf16x8v bfr[4];
#pragma unroll
        for (int ni = 0; ni < 4; ++ni)
            bfr[ni] = *(const bf16x8v*)(&sXt[ni * 16 + l15][s0]);
#pragma unroll
        for (int mi = 0; mi < 2; ++mi)
#pragma unroll
            for (int ni = 0; ni < 4; ++ni)
                acc[mi][ni] = __builtin_amdgcn_mfma_f32_16x16x32_bf16(
                    af[mi], bfr[ni], acc[mi][ni], 0, 0, 0);
    }

#pragma unroll
    for (int half = 0; half < 2; ++half) {
        const int n0 = half * 32 + qq * 8;
        bf16x8v af[2];
#pragma unroll
        for (int mi = 0; mi < 2; ++mi) {
            uint4 cv = *(const uint4*)(Cb + (tok0 + tcur[mi]) * D_STATE + n0);
            float el = elct[mi];
            union { bf16x8v v; unsigned u[4]; } r;
            r.u[0] = pk2(bl(cv.x) * el, bh(cv.x) * el);
            r.u[1] = pk2(bl(cv.y) * el, bh(cv.y) * el);
            r.u[2] = pk2(bl(cv.z) * el, bh(cv.z) * el);
            r.u[3] = pk2(bl(cv.w) * el, bh(cv.w) * el);
            af[mi] = r.v;
        }
        bf16x8v bh_[4], bl_[4];
#pragma unroll
        for (int ni = 0; ni < 4; ++ni) {
            int p = ni * 16 + l15;
            bh_[ni] = *(const bf16x8v*)(&sNh[p][n0]);
            bl_[ni] = *(const bf16x8v*)(&sNl[p][n0]);
        }
#pragma unroll
        for (int mi = 0; mi < 2; ++mi)
#pragma unroll
            for (int ni = 0; ni < 4; ++ni) {
                acc[mi][ni] = __builtin_amdgcn_mfma_f32_16x16x32_bf16(
                    af[mi], bh_[ni], acc[mi][ni], 0, 0, 0);
                acc[mi][ni] = __builtin_amdgcn_mfma_f32_16x16x32_bf16(
                    af[mi], bl_[ni], acc[mi][ni], 0, 0, 0);
            }
    }

    __syncthreads();
#pragma unroll
    for (int mi = 0; mi < 2; ++mi) {
        int r0 = w * 32 + mi * 16 + qq * 4;
#pragma unroll
        for (int ni = 0; ni < 4; ++ni) {
            int p = ni * 16 + l15;
            f32x4v v = acc[mi][ni];
#pragma unroll
            for (int jj = 0; jj < 4; ++jj) sY[r0 + jj][p] = v[jj];
        }
    }
    __syncthreads();

    {
        const float Dh = Dpa[h];
        int t = tid >> 1;
        int p0 = (tid & 1) * 32;
        size_t off = (tok0 + t) * D_INNER + h * HEADDIM + p0;
        const uint4* xrow = (const uint4*)(xy + off);
        const uint4* zrow = (const uint4*)(Zb + off);
        uint4 outv[4];
#pragma unroll
        for (int k4 = 0; k4 < 4; ++k4) {
            uint4 xv = xrow[k4];
            uint4 zv = zrow[k4];
            const float* yr = &sY[t][p0 + k4 * 8];
            float xs[8] = {bl(xv.x), bh(xv.x), bl(xv.y), bh(xv.y),
                           bl(xv.z), bh(xv.z), bl(xv.w), bh(xv.w)};
            float zs[8] = {bl(zv.x), bh(zv.x), bl(zv.y), bh(zv.y),
                           bl(zv.z), bh(zv.z), bl(zv.w), bh(zv.w)};
            unsigned o[4];
#pragma unroll
            for (int j = 0; j < 4; ++j) {
                float y0 = yr[2 * j]     + Dh * xs[2 * j];
                float y1 = yr[2 * j + 1] + Dh * xs[2 * j + 1];
                float z0 = zs[2 * j], z1 = zs[2 * j + 1];
                y0 *= z0 / (1.f + __expf(-z0));
                y1 *= z1 / (1.f + __expf(-z1));
                o[j] = pk2(y0, y1);
            }
            outv[k4].x = o[0]; outv[k4].y = o[1]; outv[k4].z = o[2]; outv[k4].w = o[3];
        }
        uint4* orow = (uint4*)(xy + off);
#pragma unroll
        for (int k4 = 0; k4 < 4; ++k4) orow[k4] = outv[k4];
    }
}

// ---------------------------------------------------------------------------
extern "C" void kernel_launch(void* const* d_in, const int* in_sizes, int n_in,
                              void* d_out, int out_size, void* d_ws, size_t ws_size,
                              hipStream_t stream) {
    (void)in_sizes; (void)n_in; (void)out_size; (void)ws_size;
    const float* u          = (const float*)d_in[0];
    const float* in_proj_w  = (const float*)d_in[1];
    const float* conv_w     = (const float*)d_in[2];
    const float* conv_b     = (const float*)d_in[3];
    const float* norm_w     = (const float*)d_in[4];
    const float* out_proj_w = (const float*)d_in[5];
    const float* A_log      = (const float*)d_in[6];
    const float* Dp         = (const float*)d_in[7];
    const float* dt_bias    = (const float*)d_in[8];

    char* w = (char*)d_ws;
    bf16*  Zb     = (bf16*)w;     w += (size_t)NTOK * D_INNER * 2;
    bf16*  XBC    = (bf16*)w;     w += (size_t)NTOK * D_CONV_IN * 2;
    bf16*  xy     = (bf16*)w;     w += (size_t)NTOK * D_INNER * 2;
    bf16*  Bb     = (bf16*)w;     w += (size_t)NTOK * D_STATE * 2;
    bf16*  Cb     = (bf16*)w;     w += (size_t)NTOK * D_STATE * 2;
    float* dtraw  = (float*)w;    w += (size_t)NTOK * NHEADS * 4;
    float* dtb    = (float*)w;    w += (size_t)NTOK * NHEADS * 4;
    float* cdecay = (float*)w;    w += (size_t)NCHB * 4;
    bf16*  wA     = (bf16*)w;     w += (size_t)NPROJPAD * D_MODEL * 2;
    bf16*  wO     = (bf16*)w;
    float* states = (float*)XBC;
    bf16*  Graw   = (bf16*)((char*)XBC + (size_t)NCHB * 4096 * 4);
    bf16*  uB     = xy;

    { int n = NTOK * D_MODEL;
      cvt_f32_bf16<<<(n / 4 + 255) / 256, 256, 0, stream>>>(u, (unsigned short*)uB, n); }
    { int nr = D_IN_PROJ * D_MODEL, np = NPROJPAD * D_MODEL;
      cvt_pad<<<(np / 4 + 255) / 256, 256, 0, stream>>>(in_proj_w, (unsigned short*)wA, nr, np); }
    { int n = D_MODEL * D_INNER;
      cvt_f32_bf16<<<(n / 4 + 255) / 256, 256, 0, stream>>>(out_proj_w, (unsigned short*)wO, n); }

    // K1: 1D grid, XCD-swizzled inside (NX = 14 column tiles, 256 row panels)
    gemm_mfma<0, NPROJPAD / 128><<<(NPROJPAD / 128) * (NTOK / 128), 256, 0, stream>>>(
        uB, wA, D_MODEL, Zb, XBC, dtraw, nullptr);

    conv_norm_v3<<<NTOK / 8, 256, 0, stream>>>(XBC, dtraw, conv_w, conv_b, norm_w, dt_bias,
                                               xy, Bb, Cb, dtb);

    score_kernel<<<NBC, 256, 0, stream>>>(Bb, Cb, Graw);
    chunk_state_mfma<<<NCHB, 256, 0, stream>>>(xy, Bb, dtb, A_log, states, cdecay);
    state_pass_kernel<<<BATCH * NHEADS, 256, 0, stream>>>(states, cdecay);
    chunk_output_mfma<<<NCHB, 256, 0, stream>>>(Zb, xy, Cb, Graw, dtb, A_log, Dp, states);

    // K4: NX = 3 column tiles
    gemm_mfma<1, D_MODEL / 128><<<(D_MODEL / 128) * (NTOK / 128), 256, 0, stream>>>(
        xy, wO, D_INNER, nullptr, nullptr, nullptr, (float*)d_out);
}

// Round 13
// 260.163 us; speedup vs baseline: 9.9588x; 1.0312x over previous
//
#include <hip/hip_runtime.h>
#include <hip/hip_bf16.h>
#include <cstddef>

#define D_MODEL   384
#define D_IN_PROJ 1676
#define D_INNER   768
#define D_CONV_IN 896
#define ZXLD      1664
#define NPROJPAD  1792          // 14 * 128
#define NHEADS    12
#define HEADDIM   64
#define D_STATE   64
#define SEQLEN    4096
#define BATCH     8
#define NTOK      (BATCH * SEQLEN)
#define EPSV      1e-5f
#define Q         128
#define NCHUNK    (SEQLEN / Q)
#define NCHB      (BATCH * NHEADS * NCHUNK)
#define NBC       (BATCH * NCHUNK)

typedef __hip_bfloat16 bf16;
typedef __attribute__((ext_vector_type(8))) short bf16x8v;
typedef __attribute__((ext_vector_type(4))) float f32x4v;

__device__ __forceinline__ float b2f(bf16 v) { return __bfloat162float(v); }
__device__ __forceinline__ bf16  f2b(float v) { return __float2bfloat16(v); }
__device__ __forceinline__ float bl(unsigned u)  { return __uint_as_float(u << 16); }
__device__ __forceinline__ float bh(unsigned u)  { return __uint_as_float(u & 0xffff0000u); }
__device__ __forceinline__ float bu(unsigned short v) { return __uint_as_float(((unsigned)v) << 16); }
__device__ __forceinline__ unsigned pk2(float a, float b) {
    return ((unsigned)__bfloat16_as_ushort(f2b(b)) << 16) | (unsigned)__bfloat16_as_ushort(f2b(a));
}
__device__ __forceinline__ int swzf(int r) { return (r ^ (r >> 2)) & 3; }
__device__ __forceinline__ int tswz(int r, int col) {
    return r * 128 + ((((col >> 3) ^ (r & 7)) << 3) | (col & 7));
}

#define GL_LDS16(g, l) __builtin_amdgcn_global_load_lds( \
    (const __attribute__((address_space(1))) unsigned*)(g), \
    (__attribute__((address_space(3))) unsigned*)(l), 16, 0, 0)

// ---------------------------------------------------------------------------
__global__ __launch_bounds__(256)
void cvt_f32_bf16(const float* __restrict__ in, unsigned short* __restrict__ out, int n) {
    int i = (blockIdx.x * 256 + threadIdx.x) * 4;
    if (i + 3 < n) {
        float4 v = *(const float4*)(in + i);
        uint2 o; o.x = pk2(v.x, v.y); o.y = pk2(v.z, v.w);
        *(uint2*)(out + i) = o;
    }
}

__global__ __launch_bounds__(256)
void cvt_pad(const float* __restrict__ in, unsigned short* __restrict__ out,
             int n_real, int n_pad) {
    int i = (blockIdx.x * 256 + threadIdx.x) * 4;
    if (i + 3 < n_pad) {
        uint2 o;
        if (i < n_real) {
            float4 v = *(const float4*)(in + i);
            o.x = pk2(v.x, v.y); o.y = pk2(v.z, v.w);
        } else {
            o.x = 0u; o.y = 0u;
        }
        *(uint2*)(out + i) = o;
    }
}

// ---------------------------------------------------------------------------
// K1: MFMA GEMM-NT, 256x128 tile, 512 threads (8 waves, 4x2 of 64x64),
// BK=32 double-buffered, XCD-aware bijective remap.
// cols<768 -> Z bf16; <1664 -> XBC bf16; <1676 -> dtraw f32.
// ---------------------------------------------------------------------------
__global__ __launch_bounds__(512)
void gemm_in_256(const bf16* __restrict__ A, const bf16* __restrict__ Bw,
                 bf16* __restrict__ Zo, bf16* __restrict__ XBCo,
                 float* __restrict__ Do) {
    const int K = D_MODEL;
    __shared__ short As[2][256 * 32];
    __shared__ short Bs[2][128 * 32];
    const int tid = threadIdx.x;
    const int lane = tid & 63;
    const int wv = tid >> 6;          // 0..7
    const int wr = wv >> 1;           // 0..3  (row sub-tile)
    const int wc = wv & 1;            // 0..1  (col sub-tile)

    // XCD swizzle: 1792 blocks = 8 xcd x (16 panel-groups x 14 col-tiles)
    const int id = blockIdx.x;
    const int xcd = id & 7;
    const int j = id >> 3;
    const int by = xcd + 8 * (j / 14);    // 0..127
    const int bx = j % 14;                // 0..13
    const int bm = by * 256;
    const int bn = bx * 128;

    f32x4v acc[4][4];
#pragma unroll
    for (int mi = 0; mi < 4; ++mi)
#pragma unroll
        for (int ni = 0; ni < 4; ++ni)
            acc[mi][ni] = (f32x4v){0.f, 0.f, 0.f, 0.f};

    // A: 2 chunks of 8KB (512 thr x 16B); B: 1 chunk of 8KB
    int aoff[2], boff;
#pragma unroll
    for (int q = 0; q < 2; ++q) {
        int o = q * 8192 + tid * 16;
        int row = o >> 6;                 // 0..255
        int ps = (o >> 4) & 3;
        int sl = ps ^ swzf(row);
        aoff[q] = (bm + row) * K + sl * 8;
    }
    {
        int o = tid * 16;
        int row = o >> 6;                 // 0..127
        int ps = (o >> 4) & 3;
        int sl = ps ^ swzf(row);
        boff = (bn + row) * K + sl * 8;
    }

    const int l15 = lane & 15, qq = lane >> 4;
    int aidx[4], bidx[4];
#pragma unroll
    for (int i = 0; i < 4; ++i) {
        int ra = wr * 64 + i * 16 + l15;      // 0..255
        int rb = wc * 64 + i * 16 + l15;      // 0..127
        aidx[i] = ra * 32 + ((qq ^ swzf(ra)) * 8);
        bidx[i] = rb * 32 + ((qq ^ swzf(rb)) * 8);
    }

    // prologue: stage tile 0 into buffer 0
    GL_LDS16(A + (size_t)aoff[0], &As[0][tid * 8]);
    GL_LDS16(A + (size_t)aoff[1], &As[0][4096 + tid * 8]);
    GL_LDS16(Bw + (size_t)boff, &Bs[0][tid * 8]);
    __syncthreads();

    const int nt = K >> 5;   // 12
    for (int t = 0; t < nt; ++t) {
        const int cur = t & 1;
        if (t + 1 < nt) {
            const int k0 = (t + 1) << 5;
            GL_LDS16(A + (size_t)aoff[0] + k0, &As[cur ^ 1][tid * 8]);
            GL_LDS16(A + (size_t)aoff[1] + k0, &As[cur ^ 1][4096 + tid * 8]);
            GL_LDS16(Bw + (size_t)boff + k0, &Bs[cur ^ 1][tid * 8]);
        }
        bf16x8v af[4], bf[4];
#pragma unroll
        for (int i = 0; i < 4; ++i) {
            af[i] = *(const bf16x8v*)(&As[cur][aidx[i]]);
            bf[i] = *(const bf16x8v*)(&Bs[cur][bidx[i]]);
        }
#pragma unroll
        for (int mi = 0; mi < 4; ++mi)
#pragma unroll
            for (int ni = 0; ni < 4; ++ni)
                acc[mi][ni] = __builtin_amdgcn_mfma_f32_16x16x32_bf16(
                    af[mi], bf[ni], acc[mi][ni], 0, 0, 0);
        __syncthreads();
    }

    const int l4 = lane >> 4;
#pragma unroll
    for (int mi = 0; mi < 4; ++mi) {
        int rbase = bm + wr * 64 + mi * 16 + l4 * 4;
#pragma unroll
        for (int ni = 0; ni < 4; ++ni) {
            int col = bn + wc * 64 + ni * 16 + l15;
            f32x4v v = acc[mi][ni];
            if (col < D_INNER) {
#pragma unroll
                for (int jj = 0; jj < 4; ++jj)
                    Zo[(size_t)(rbase + jj) * D_INNER + col] = f2b(v[jj]);
            } else if (col < ZXLD) {
#pragma unroll
                for (int jj = 0; jj < 4; ++jj)
                    XBCo[(size_t)(rbase + jj) * D_CONV_IN + (col - D_INNER)] = f2b(v[jj]);
            } else if (col < D_IN_PROJ) {
#pragma unroll
                for (int jj = 0; jj < 4; ++jj)
                    Do[(size_t)(rbase + jj) * NHEADS + (col - ZXLD)] = v[jj];
            }
        }
    }
}

// ---------------------------------------------------------------------------
// K4: MFMA GEMM-NT 128x128, BK=32 dbuf, XCD remap (unchanged from round 12)
// ---------------------------------------------------------------------------
template<int NX>
__global__ __launch_bounds__(256)
void gemm_out_mfma(const bf16* __restrict__ A, const bf16* __restrict__ Bw, int K,
                   float* __restrict__ Co) {
    __shared__ short As[2][128 * 32];
    __shared__ short Bs[2][128 * 32];
    const int tid = threadIdx.x;
    const int lane = tid & 63;
    const int w = tid >> 6;
    const int wr = w >> 1, wc = w & 1;

    const int id = blockIdx.x;
    const int xcd = id & 7;
    const int j = id >> 3;
    const int by = xcd + 8 * (j / NX);
    const int bx = j % NX;
    const int bm = by * 128;
    const int bn = bx * 128;

    f32x4v acc[4][4];
#pragma unroll
    for (int mi = 0; mi < 4; ++mi)
#pragma unroll
        for (int ni = 0; ni < 4; ++ni)
            acc[mi][ni] = (f32x4v){0.f, 0.f, 0.f, 0.f};

    int aoff[2], boff[2];
#pragma unroll
    for (int q = 0; q < 2; ++q) {
        int o = q * 4096 + tid * 16;
        int row = o >> 6;
        int ps = (o >> 4) & 3;
        int sl = ps ^ swzf(row);
        aoff[q] = (bm + row) * K + sl * 8;
        boff[q] = (bn + row) * K + sl * 8;
    }

    const int l15 = lane & 15, qq = lane >> 4;
    int aidx[4], bidx[4];
#pragma unroll
    for (int i = 0; i < 4; ++i) {
        int ra = wr * 64 + i * 16 + l15;
        int rb = wc * 64 + i * 16 + l15;
        aidx[i] = ra * 32 + ((qq ^ swzf(ra)) * 8);
        bidx[i] = rb * 32 + ((qq ^ swzf(rb)) * 8);
    }

    GL_LDS16(A + (size_t)aoff[0], &As[0][tid * 8]);
    GL_LDS16(A + (size_t)aoff[1], &As[0][2048 + tid * 8]);
    GL_LDS16(Bw + (size_t)boff[0], &Bs[0][tid * 8]);
    GL_LDS16(Bw + (size_t)boff[1], &Bs[0][2048 + tid * 8]);
    __syncthreads();

    const int nt = K >> 5;
    for (int t = 0; t < nt; ++t) {
        const int cur = t & 1;
        if (t + 1 < nt) {
            const int k0 = (t + 1) << 5;
            GL_LDS16(A + (size_t)aoff[0] + k0, &As[cur ^ 1][tid * 8]);
            GL_LDS16(A + (size_t)aoff[1] + k0, &As[cur ^ 1][2048 + tid * 8]);
            GL_LDS16(Bw + (size_t)boff[0] + k0, &Bs[cur ^ 1][tid * 8]);
            GL_LDS16(Bw + (size_t)boff[1] + k0, &Bs[cur ^ 1][2048 + tid * 8]);
        }
        bf16x8v af[4], bf[4];
#pragma unroll
        for (int i = 0; i < 4; ++i) {
            af[i] = *(const bf16x8v*)(&As[cur][aidx[i]]);
            bf[i] = *(const bf16x8v*)(&Bs[cur][bidx[i]]);
        }
#pragma unroll
        for (int mi = 0; mi < 4; ++mi)
#pragma unroll
            for (int ni = 0; ni < 4; ++ni)
                acc[mi][ni] = __builtin_amdgcn_mfma_f32_16x16x32_bf16(
                    af[mi], bf[ni], acc[mi][ni], 0, 0, 0);
        __syncthreads();
    }

    const int l4 = lane >> 4;
#pragma unroll
    for (int mi = 0; mi < 4; ++mi) {
        int rbase = bm + wr * 64 + mi * 16 + l4 * 4;
#pragma unroll
        for (int ni = 0; ni < 4; ++ni) {
            int col = bn + wc * 64 + ni * 16 + l15;
            f32x4v v = acc[mi][ni];
#pragma unroll
            for (int jj = 0; jj < 4; ++jj)
                Co[(size_t)(rbase + jj) * D_MODEL + col] = v[jj];
        }
    }
}

// ---------------------------------------------------------------------------
// K2 v3 (unchanged)
// ---------------------------------------------------------------------------
__global__ __launch_bounds__(256)
void conv_norm_v3(const bf16* __restrict__ XBC, const float* __restrict__ dtraw,
                  const float* __restrict__ conv_w, const float* __restrict__ conv_b,
                  const float* __restrict__ norm_w, const float* __restrict__ dt_bias,
                  bf16* __restrict__ xn, bf16* __restrict__ Bb,
                  bf16* __restrict__ Cb, float* __restrict__ dtb) {
    const int tid = threadIdx.x;
    const int t0 = blockIdx.x * 8;
    const int l0 = t0 & (SEQLEN - 1);

    __shared__ float sp[8][200];
    __shared__ float sq[8][8];
    __shared__ float sscale[8];

    const int c = tid;
    const bool active = (c < 224);
    const int ch0 = c * 4;

    float acc[8][4];
    float w0[4], w1[4], w2[4], w3[4];

    if (active) {
        float4 wa = *(const float4*)(conv_w + (ch0 + 0) * 4);
        float4 wb = *(const float4*)(conv_w + (ch0 + 1) * 4);
        float4 wcc = *(const float4*)(conv_w + (ch0 + 2) * 4);
        float4 wd = *(const float4*)(conv_w + (ch0 + 3) * 4);
        w0[0] = wa.x; w1[0] = wa.y; w2[0] = wa.z; w3[0] = wa.w;
        w0[1] = wb.x; w1[1] = wb.y; w2[1] = wb.z; w3[1] = wb.w;
        w0[2] = wcc.x; w1[2] = wcc.y; w2[2] = wcc.z; w3[2] = wcc.w;
        w0[3] = wd.x; w1[3] = wd.y; w2[3] = wd.z; w3[3] = wd.w;
        float4 bv = *(const float4*)(conv_b + ch0);
#pragma unroll
        for (int t = 0; t < 8; ++t) {
            acc[t][0] = bv.x; acc[t][1] = bv.y; acc[t][2] = bv.z; acc[t][3] = bv.w;
        }
#pragma unroll
        for (int ri = 0; ri < 11; ++ri) {
            int lr = l0 - 3 + ri;
            if (lr >= 0) {
                uint2 rv = *(const uint2*)((const unsigned short*)XBC
                              + (size_t)(t0 - 3 + ri) * D_CONV_IN + ch0);
                float r0 = bl(rv.x), r1 = bh(rv.x), r2 = bl(rv.y), r3 = bh(rv.y);
#pragma unroll
                for (int t = 0; t < 8; ++t) {
                    if (t >= ri - 3 && t <= ri) {
                        const int jt = ri - t;
                        const float* wj = (jt == 0) ? w0 : (jt == 1) ? w1 : (jt == 2) ? w2 : w3;
                        acc[t][0] += r0 * wj[0];
                        acc[t][1] += r1 * wj[1];
                        acc[t][2] += r2 * wj[2];
                        acc[t][3] += r3 * wj[3];
                    }
                }
            }
        }
#pragma unroll
        for (int t = 0; t < 8; ++t) {
            float ss = 0.f;
#pragma unroll
            for (int i = 0; i < 4; ++i) {
                float v = acc[t][i];
                float s = v / (1.f + __expf(-v));
                acc[t][i] = s;
                ss += s * s;
            }
            if (c < 192) sp[t][c] = ss;
        }
    }
    __syncthreads();
    if (tid < 64) {
        int t = tid >> 3, i = tid & 7;
        float s = 0.f;
#pragma unroll
        for (int k = 0; k < 24; ++k) s += sp[t][i * 24 + k];
        sq[t][i] = s;
    }
    __syncthreads();
    if (tid < 8) {
        float tot = 0.f;
#pragma unroll
        for (int i = 0; i < 8; ++i) tot += sq[tid][i];
        sscale[tid] = rsqrtf(tot / (float)D_INNER + EPSV);
    }
    __syncthreads();

    if (c < 192) {
        float4 nv = *(const float4*)(norm_w + ch0);
#pragma unroll
        for (int t = 0; t < 8; ++t) {
            float sc = sscale[t];
            uint2 o;
            o.x = pk2(acc[t][0] * sc * nv.x, acc[t][1] * sc * nv.y);
            o.y = pk2(acc[t][2] * sc * nv.z, acc[t][3] * sc * nv.w);
            *(uint2*)(xn + (size_t)(t0 + t) * D_INNER + ch0) = o;
        }
    } else if (c < 224) {
        const int idx = ch0 - 768;
#pragma unroll
        for (int t = 0; t < 8; ++t) {
            uint2 o;
            o.x = pk2(acc[t][0], acc[t][1]);
            o.y = pk2(acc[t][2], acc[t][3]);
            bf16* base = (idx < 64) ? (Bb + (size_t)(t0 + t) * D_STATE + idx)
                                    : (Cb + (size_t)(t0 + t) * D_STATE + (idx - 64));
            *(uint2*)base = o;
        }
    }
    if (tid < 96) {
        int t = tid / 12, hh = tid % 12;
        float v = dtraw[(size_t)(t0 + t) * NHEADS + hh] + dt_bias[hh];
        float spv = (v > 20.f) ? v : log1pf(expf(v));
        dtb[(size_t)(t0 + t) * NHEADS + hh] = spv;
    }
}

// ---------------------------------------------------------------------------
// Score kernel (unchanged)
// ---------------------------------------------------------------------------
__global__ __launch_bounds__(256)
void score_kernel(const bf16* __restrict__ Bb, const bf16* __restrict__ Cb,
                  bf16* __restrict__ Graw) {
    const int bc = blockIdx.x;
    const size_t tok0 = (size_t)bc * Q;
    const int tid = threadIdx.x;
    const int lane = tid & 63, w = tid >> 6;
    const int wr = w >> 1, wc = w & 1;
    __shared__ short sC[Q * 64];
    __shared__ short sB[Q * 64];

#pragma unroll
    for (int it = 0; it < 4; ++it) {
        int j = it * 256 + tid;
        int r = j >> 3, sp = j & 7;
        int sl = sp ^ (r & 7);
        GL_LDS16(Cb + tok0 * D_STATE + r * 64 + sl * 8, sC + j * 8);
        GL_LDS16(Bb + tok0 * D_STATE + r * 64 + sl * 8, sB + j * 8);
    }
    __syncthreads();

    const int l15 = lane & 15, qq = lane >> 4;
    f32x4v acc[4][4];
#pragma unroll
    for (int mi = 0; mi < 4; ++mi)
#pragma unroll
        for (int ni = 0; ni < 4; ++ni)
            acc[mi][ni] = (f32x4v){0.f, 0.f, 0.f, 0.f};

#pragma unroll
    for (int kb = 0; kb < 2; ++kb) {
        bf16x8v af[4], bf[4];
#pragma unroll
        for (int i = 0; i < 4; ++i) {
            int ra = wr * 64 + i * 16 + l15;
            int rb = wc * 64 + i * 16 + l15;
            af[i] = *(const bf16x8v*)(sC + ra * 64 + ((kb * 4 + qq) ^ (ra & 7)) * 8);
            bf[i] = *(const bf16x8v*)(sB + rb * 64 + ((kb * 4 + qq) ^ (rb & 7)) * 8);
        }
#pragma unroll
        for (int mi = 0; mi < 4; ++mi)
#pragma unroll
            for (int ni = 0; ni < 4; ++ni)
                acc[mi][ni] = __builtin_amdgcn_mfma_f32_16x16x32_bf16(
                    af[mi], bf[ni], acc[mi][ni], 0, 0, 0);
    }

    bf16* gout = Graw + (size_t)bc * (Q * Q);
#pragma unroll
    for (int mi = 0; mi < 4; ++mi) {
        int t0 = wr * 64 + mi * 16 + qq * 4;
#pragma unroll
        for (int ni = 0; ni < 4; ++ni) {
            int s = wc * 64 + ni * 16 + l15;
            f32x4v v = acc[mi][ni];
#pragma unroll
            for (int j = 0; j < 4; ++j)
                gout[(size_t)(t0 + j) * Q + s] = f2b(v[j]);
        }
    }
}

// ---------------------------------------------------------------------------
// K3a (MFMA) (unchanged)
// ---------------------------------------------------------------------------
__global__ __launch_bounds__(256)
void chunk_state_mfma(const bf16* __restrict__ xy, const bf16* __restrict__ Bb,
                      const float* __restrict__ dtb, const float* __restrict__ A_log,
                      float* __restrict__ states, float* __restrict__ cdecay) {
    const int sid = blockIdx.x;
    const int c = sid % NCHUNK;
    const int h = (sid / NCHUNK) % NHEADS;
    const int b = sid / (NCHUNK * NHEADS);
    const int tid = threadIdx.x;
    const int lane = tid & 63, w = tid >> 6;
    const size_t tok0 = (size_t)b * SEQLEN + (size_t)c * Q;
    const float Acoef = -expf(A_log[h]);

    __shared__ __align__(16) unsigned short sBT[64 * 128];
    __shared__ __align__(16) unsigned short sXT[64 * 128];
    __shared__ float slcum[Q];
    __shared__ float sdt[Q];
    __shared__ float wtot[2];

    float lx = 0.f;
    if (tid < Q) {
        float dtv = dtb[(tok0 + tid) * NHEADS + h];
        sdt[tid] = dtv;
        lx = dtv * Acoef;
        int ln = tid & 63;
        for (int off = 1; off < 64; off <<= 1) {
            float v = __shfl_up(lx, off, 64);
            if (ln >= off) lx += v;
        }
        if (ln == 63) wtot[tid >> 6] = lx;
    }
    __syncthreads();
    if (tid < Q) {
        if (tid >= 64) lx += wtot[0];
        slcum[tid] = lx;
    }
    __syncthreads();
    const float ltot = slcum[Q - 1];

    {
        int t = tid >> 1, half = tid & 1;
        float s_t = sdt[t] * __expf(ltot - slcum[t]);
        const unsigned short* br = (const unsigned short*)(Bb + (tok0 + t) * D_STATE) + half * 32;
        const unsigned short* xr = (const unsigned short*)(xy + (tok0 + t) * D_INNER + h * HEADDIM) + half * 32;
#pragma unroll
        for (int i = 0; i < 32; ++i) {
            int r = half * 32 + i;
            sBT[tswz(r, t)] = __bfloat16_as_ushort(f2b(bu(br[i]) * s_t));
            sXT[tswz(r, t)] = xr[i];
        }
    }
    __syncthreads();

    const int l15 = lane & 15, qq = lane >> 4;
    f32x4v acc[4];
#pragma unroll
    for (int ni = 0; ni < 4; ++ni) acc[ni] = (f32x4v){0.f, 0.f, 0.f, 0.f};

#pragma unroll
    for (int kb = 0; kb < 4; ++kb) {
        const int col = kb * 32 + qq * 8;
        bf16x8v af = *(const bf16x8v*)(&sBT[tswz(w * 16 + l15, col)]);
#pragma unroll
        for (int ni = 0; ni < 4; ++ni) {
            bf16x8v bx = *(const bf16x8v*)(&sXT[tswz(ni * 16 + l15, col)]);
            acc[ni] = __builtin_amdgcn_mfma_f32_16x16x32_bf16(af, bx, acc[ni], 0, 0, 0);
        }
    }

    float* out = states + (size_t)sid * 4096;
#pragma unroll
    for (int ni = 0; ni < 4; ++ni) {
#pragma unroll
        for (int j = 0; j < 4; ++j) {
            int n = w * 16 + qq * 4 + j;
            int p = ni * 16 + l15;
            out[n * 64 + p] = acc[ni][j];
        }
    }
    if (tid == 0) cdecay[sid] = expf(ltot);
}

// ---------------------------------------------------------------------------
// K3b (unchanged)
// ---------------------------------------------------------------------------
__global__ __launch_bounds__(256)
void state_pass_kernel(float* __restrict__ states, const float* __restrict__ cdecay) {
    const int bh = blockIdx.x;
    const int tid = threadIdx.x;
    float run[16];
#pragma unroll
    for (int i = 0; i < 16; ++i) run[i] = 0.f;
    float* base = states + (size_t)bh * NCHUNK * 4096 + tid * 16;
    const float* cd = cdecay + bh * NCHUNK;
    for (int c = 0; c < NCHUNK; ++c) {
        float dec = cd[c];
        float* ptr = base + (size_t)c * 4096;
        float4 s0 = *(float4*)(ptr + 0);
        float4 s1 = *(float4*)(ptr + 4);
        float4 s2 = *(float4*)(ptr + 8);
        float4 s3 = *(float4*)(ptr + 12);
        float nr[16];
        nr[0] = dec * run[0] + s0.x;  nr[1] = dec * run[1] + s0.y;
        nr[2] = dec * run[2] + s0.z;  nr[3] = dec * run[3] + s0.w;
        nr[4] = dec * run[4] + s1.x;  nr[5] = dec * run[5] + s1.y;
        nr[6] = dec * run[6] + s1.z;  nr[7] = dec * run[7] + s1.w;
        nr[8] = dec * run[8] + s2.x;  nr[9] = dec * run[9] + s2.y;
        nr[10] = dec * run[10] + s2.z; nr[11] = dec * run[11] + s2.w;
        nr[12] = dec * run[12] + s3.x; nr[13] = dec * run[13] + s3.y;
        nr[14] = dec * run[14] + s3.z; nr[15] = dec * run[15] + s3.w;
        *(float4*)(ptr + 0)  = make_float4(run[0], run[1], run[2], run[3]);
        *(float4*)(ptr + 4)  = make_float4(run[4], run[5], run[6], run[7]);
        *(float4*)(ptr + 8)  = make_float4(run[8], run[9], run[10], run[11]);
        *(float4*)(ptr + 12) = make_float4(run[12], run[13], run[14], run[15]);
#pragma unroll
        for (int i = 0; i < 16; ++i) run[i] = nr[i];
    }
}

// ---------------------------------------------------------------------------
// K3c v2 (MFMA) (unchanged)
// ---------------------------------------------------------------------------
__global__ __launch_bounds__(256)
void chunk_output_mfma(const bf16* __restrict__ Zb, bf16* __restrict__ xy,
                       const bf16* __restrict__ Cb, const bf16* __restrict__ Graw,
                       const float* __restrict__ dtb, const float* __restrict__ A_log,
                       const float* __restrict__ Dpa, const float* __restrict__ states) {
    const int sid = blockIdx.x;
    const int c = sid % NCHUNK;
    const int h = (sid / NCHUNK) % NHEADS;
    const int b = sid / (NCHUNK * NHEADS);
    const int tid = threadIdx.x;
    const int lane = tid & 63, w = tid >> 6;
    const size_t tok0 = (size_t)b * SEQLEN + (size_t)c * Q;
    const int bc = b * NCHUNK + c;
    const float Acoef = -expf(A_log[h]);

    __shared__ __align__(16) char smem[35840];
    unsigned short (*sXt)[136] = (unsigned short(*)[136])smem;
    unsigned short (*sNh)[72]  = (unsigned short(*)[72])(smem + 17408);
    unsigned short (*sNl)[72]  = (unsigned short(*)[72])(smem + 17408 + 9216);
    float (*sY)[68] = (float(*)[68])smem;
    __shared__ float slc[Q];
    __shared__ float sldn[Q];
    __shared__ float wtot[2];

    float lx = 0.f, l2dt = 0.f;
    if (tid < Q) {
        float dtv = dtb[(tok0 + tid) * NHEADS + h];
        l2dt = __logf(dtv);
        lx = dtv * Acoef;
        int ln = tid & 63;
        for (int off = 1; off < 64; off <<= 1) {
            float v = __shfl_up(lx, off, 64);
            if (ln >= off) lx += v;
        }
        if (ln == 63) wtot[tid >> 6] = lx;
    }
    __syncthreads();
    if (tid < Q) {
        if (tid >= 64) lx += wtot[0];
        slc[tid] = lx;
        sldn[tid] = lx - l2dt;
    }

    {
        int t = tid >> 1, ph = (tid & 1) * 32;
        const unsigned short* xr = (const unsigned short*)(xy + (tok0 + t) * D_INNER + h * HEADDIM + ph);
#pragma unroll
        for (int i = 0; i < 32; ++i) sXt[ph + i][t] = xr[i];
    }
    {
        const float* init = states + (size_t)sid * 4096;
        for (int i = tid; i < 1024; i += 256) {
            float4 v = ((const float4*)init)[i];
            int n = i >> 4;
            int p = (i & 15) * 4;
#pragma unroll
            for (int j2 = 0; j2 < 4; ++j2) {
                float f = (&v.x)[j2];
                bf16 hi = f2b(f);
                float lo = f - b2f(hi);
                sNh[p + j2][n] = __bfloat16_as_ushort(hi);
                sNl[p + j2][n] = __bfloat16_as_ushort(f2b(lo));
            }
        }
    }
    __syncthreads();

    const int l15 = lane & 15, qq = lane >> 4;

    int tcur[2]; float lct_mi[2], elct[2];
#pragma unroll
    for (int mi = 0; mi < 2; ++mi) {
        tcur[mi] = w * 32 + mi * 16 + l15;
        lct_mi[mi] = slc[tcur[mi]];
        elct[mi] = __expf(lct_mi[mi]);
    }

    f32x4v acc[2][4];
#pragma unroll
    for (int mi = 0; mi < 2; ++mi)
#pragma unroll
        for (int ni = 0; ni < 4; ++ni)
            acc[mi][ni] = (f32x4v){0.f, 0.f, 0.f, 0.f};

    const bf16* grow = Graw + (size_t)bc * (Q * Q);

#pragma unroll
    for (int kb = 0; kb < 4; ++kb) {
        const int s0 = kb * 32 + qq * 8;
        float4 dA = *(const float4*)(sldn + s0);
        float4 dB = *(const float4*)(sldn + s0 + 4);
        bf16x8v af[2];
#pragma unroll
        for (int mi = 0; mi < 2; ++mi) {
            int t = tcur[mi];
            float lct = lct_mi[mi];
            uint4 gv = *(const uint4*)(grow + (size_t)t * Q + s0);
            float f0 = (s0 + 0 <= t) ? bl(gv.x) * __expf(lct - dA.x) : 0.f;
            float f1 = (s0 + 1 <= t) ? bh(gv.x) * __expf(lct - dA.y) : 0.f;
            float f2 = (s0 + 2 <= t) ? bl(gv.y) * __expf(lct - dA.z) : 0.f;
            float f3 = (s0 + 3 <= t) ? bh(gv.y) * __expf(lct - dA.w) : 0.f;
            float f4 = (s0 + 4 <= t) ? bl(gv.z) * __expf(lct - dB.x) : 0.f;
            float f5 = (s0 + 5 <= t) ? bh(gv.z) * __expf(lct - dB.y) : 0.f;
            float f6 = (s0 + 6 <= t) ? bl(gv.w) * __expf(lct - dB.z) : 0.f;
            float f7 = (s0 + 7 <= t) ? bh(gv.w) * __expf(lct - dB.w) : 0.f;
            union { bf16x8v v; unsigned u[4]; } r;
            r.u[0] = pk2(f0, f1); r.u[1] = pk2(f2, f3);
            r.u[2] = pk2(f4, f5); r.u[3] = pk2(f6, f7);
            af[mi] = r.v;
        }
        bf16x8v bfr[4];
#pragma unroll
        for (int ni = 0; ni < 4; ++ni)
            bfr[ni] = *(const bf16x8v*)(&sXt[ni * 16 + l15][s0]);
#pragma unroll
        for (int mi = 0; mi < 2; ++mi)
#pragma unroll
            for (int ni = 0; ni < 4; ++ni)
                acc[mi][ni] = __builtin_amdgcn_mfma_f32_16x16x32_bf16(
                    af[mi], bfr[ni], acc[mi][ni], 0, 0, 0);
    }

#pragma unroll
    for (int half = 0; half < 2; ++half) {
        const int n0 = half * 32 + qq * 8;
        bf16x8v af[2];
#pragma unroll
        for (int mi = 0; mi < 2; ++mi) {
            uint4 cv = *(const uint4*)(Cb + (tok0 + tcur[mi]) * D_STATE + n0);
            float el = elct[mi];
            union { bf16x8v v; unsigned u[4]; } r;
            r.u[0] = pk2(bl(cv.x) * el, bh(cv.x) * el);
            r.u[1] = pk2(bl(cv.y) * el, bh(cv.y) * el);
            r.u[2] = pk2(bl(cv.z) * el, bh(cv.z) * el);
            r.u[3] = pk2(bl(cv.w) * el, bh(cv.w) * el);
            af[mi] = r.v;
        }
        bf16x8v bh_[4], bl_[4];
#pragma unroll
        for (int ni = 0; ni < 4; ++ni) {
            int p = ni * 16 + l15;
            bh_[ni] = *(const bf16x8v*)(&sNh[p][n0]);
            bl_[ni] = *(const bf16x8v*)(&sNl[p][n0]);
        }
#pragma unroll
        for (int mi = 0; mi < 2; ++mi)
#pragma unroll
            for (int ni = 0; ni < 4; ++ni) {
                acc[mi][ni] = __builtin_amdgcn_mfma_f32_16x16x32_bf16(
                    af[mi], bh_[ni], acc[mi][ni], 0, 0, 0);
                acc[mi][ni] = __builtin_amdgcn_mfma_f32_16x16x32_bf16(
                    af[mi], bl_[ni], acc[mi][ni], 0, 0, 0);
            }
    }

    __syncthreads();
#pragma unroll
    for (int mi = 0; mi < 2; ++mi) {
        int r0 = w * 32 + mi * 16 + qq * 4;
#pragma unroll
        for (int ni = 0; ni < 4; ++ni) {
            int p = ni * 16 + l15;
            f32x4v v = acc[mi][ni];
#pragma unroll
            for (int jj = 0; jj < 4; ++jj) sY[r0 + jj][p] = v[jj];
        }
    }
    __syncthreads();

    {
        const float Dh = Dpa[h];
        int t = tid >> 1;
        int p0 = (tid & 1) * 32;
        size_t off = (tok0 + t) * D_INNER + h * HEADDIM + p0;
        const uint4* xrow = (const uint4*)(xy + off);
        const uint4* zrow = (const uint4*)(Zb + off);
        uint4 outv[4];
#pragma unroll
        for (int k4 = 0; k4 < 4; ++k4) {
            uint4 xv = xrow[k4];
            uint4 zv = zrow[k4];
            const float* yr = &sY[t][p0 + k4 * 8];
            float xs[8] = {bl(xv.x), bh(xv.x), bl(xv.y), bh(xv.y),
                           bl(xv.z), bh(xv.z), bl(xv.w), bh(xv.w)};
            float zs[8] = {bl(zv.x), bh(zv.x), bl(zv.y), bh(zv.y),
                           bl(zv.z), bh(zv.z), bl(zv.w), bh(zv.w)};
            unsigned o[4];
#pragma unroll
            for (int j = 0; j < 4; ++j) {
                float y0 = yr[2 * j]     + Dh * xs[2 * j];
                float y1 = yr[2 * j + 1] + Dh * xs[2 * j + 1];
                float z0 = zs[2 * j], z1 = zs[2 * j + 1];
                y0 *= z0 / (1.f + __expf(-z0));
                y1 *= z1 / (1.f + __expf(-z1));
                o[j] = pk2(y0, y1);
            }
            outv[k4].x = o[0]; outv[k4].y = o[1]; outv[k4].z = o[2]; outv[k4].w = o[3];
        }
        uint4* orow = (uint4*)(xy + off);
#pragma unroll
        for (int k4 = 0; k4 < 4; ++k4) orow[k4] = outv[k4];
    }
}

// ---------------------------------------------------------------------------
extern "C" void kernel_launch(void* const* d_in, const int* in_sizes, int n_in,
                              void* d_out, int out_size, void* d_ws, size_t ws_size,
                              hipStream_t stream) {
    (void)in_sizes; (void)n_in; (void)out_size; (void)ws_size;
    const float* u          = (const float*)d_in[0];
    const float* in_proj_w  = (const float*)d_in[1];
    const float* conv_w     = (const float*)d_in[2];
    const float* conv_b     = (const float*)d_in[3];
    const float* norm_w     = (const float*)d_in[4];
    const float* out_proj_w = (const float*)d_in[5];
    const float* A_log      = (const float*)d_in[6];
    const float* Dp         = (const float*)d_in[7];
    const float* dt_bias    = (const float*)d_in[8];

    char* w = (char*)d_ws;
    bf16*  Zb     = (bf16*)w;     w += (size_t)NTOK * D_INNER * 2;
    bf16*  XBC    = (bf16*)w;     w += (size_t)NTOK * D_CONV_IN * 2;
    bf16*  xy     = (bf16*)w;     w += (size_t)NTOK * D_INNER * 2;
    bf16*  Bb     = (bf16*)w;     w += (size_t)NTOK * D_STATE * 2;
    bf16*  Cb     = (bf16*)w;     w += (size_t)NTOK * D_STATE * 2;
    float* dtraw  = (float*)w;    w += (size_t)NTOK * NHEADS * 4;
    float* dtb    = (float*)w;    w += (size_t)NTOK * NHEADS * 4;
    float* cdecay = (float*)w;    w += (size_t)NCHB * 4;
    bf16*  wA     = (bf16*)w;     w += (size_t)NPROJPAD * D_MODEL * 2;
    bf16*  wO     = (bf16*)w;
    float* states = (float*)XBC;
    bf16*  Graw   = (bf16*)((char*)XBC + (size_t)NCHB * 4096 * 4);
    bf16*  uB     = xy;

    { int n = NTOK * D_MODEL;
      cvt_f32_bf16<<<(n / 4 + 255) / 256, 256, 0, stream>>>(u, (unsigned short*)uB, n); }
    { int nr = D_IN_PROJ * D_MODEL, np = NPROJPAD * D_MODEL;
      cvt_pad<<<(np / 4 + 255) / 256, 256, 0, stream>>>(in_proj_w, (unsigned short*)wA, nr, np); }
    { int n = D_MODEL * D_INNER;
      cvt_f32_bf16<<<(n / 4 + 255) / 256, 256, 0, stream>>>(out_proj_w, (unsigned short*)wO, n); }

    // K1: 256x128 tile, 512 threads, 1792 blocks (8 xcd x 16 panels x 14 cols)
    gemm_in_256<<<(NPROJPAD / 128) * (NTOK / 256), 512, 0, stream>>>(
        uB, wA, Zb, XBC, dtraw);

    conv_norm_v3<<<NTOK / 8, 256, 0, stream>>>(XBC, dtraw, conv_w, conv_b, norm_w, dt_bias,
                                               xy, Bb, Cb, dtb);

    score_kernel<<<NBC, 256, 0, stream>>>(Bb, Cb, Graw);
    chunk_state_mfma<<<NCHB, 256, 0, stream>>>(xy, Bb, dtb, A_log, states, cdecay);
    state_pass_kernel<<<BATCH * NHEADS, 256, 0, stream>>>(states, cdecay);
    chunk_output_mfma<<<NCHB, 256, 0, stream>>>(Zb, xy, Cb, Graw, dtb, A_log, Dp, states);

    // K4: 128x128, NX = 3 column tiles
    gemm_out_mfma<D_MODEL / 128><<<(D_MODEL / 128) * (NTOK / 128), 256, 0, stream>>>(
        xy, wO, D_INNER, (float*)d_out);
}